// Round 2
// baseline (3994.418 us; speedup 1.0000x reference)
//
#include <hip/hip_runtime.h>
#include <cfloat>

#define BB 8
#define NN 2048
#define KNN 20
#define NCOPY 64
#define EPSV 1e-5f
#define SLOPEV 0.2f

// ---------------- small prep kernels ----------------

__global__ void transpose0_kernel(const float* __restrict__ x, float* __restrict__ XT0) {
    int e = blockIdx.x * blockDim.x + threadIdx.x;
    if (e >= BB * NN * 3) return;
    int b = e / (NN * 3); int r = e - b * NN * 3; int n = r / 3; int c = r - n * 3;
    XT0[e] = x[((size_t)b * 3 + c) * NN + n];
}

__global__ void wprep_kernel(const float* __restrict__ W, float* __restrict__ WaT,
                             float* __restrict__ WdT, int C, int O) {
    int e = blockIdx.x * blockDim.x + threadIdx.x;
    if (e >= C * O) return;
    int c = e / O, o = e - c * O;
    float a = W[o * 2 * C + c];
    WaT[e] = a;
    WdT[e] = W[o * 2 * C + C + c] - a;
}

__global__ void w5prep_kernel(const float* __restrict__ W5, float* __restrict__ W5T) {
    int e = blockIdx.x * blockDim.x + threadIdx.x;   // 512*1024 exact
    int c = e >> 10, o = e & 1023;
    W5T[e] = W5[o * 512 + c];
}

// ---------------- per-point squared norm (matches dot-product partial order) ----

template <int C>
__global__ void xx_kernel(const float* __restrict__ XT, float* __restrict__ xx) {
    int e = blockIdx.x * blockDim.x + threadIdx.x;
    if (e >= BB * NN) return;
    const float* p = &XT[(size_t)e * C];
    float s;
    if constexpr (C % 4 == 0) {
        float s0 = 0, s1 = 0, s2 = 0, s3 = 0;
        for (int c = 0; c < C; c += 4) {
            float4 v = *(const float4*)(p + c);
            s0 += v.x * v.x; s1 += v.y * v.y; s2 += v.z * v.z; s3 += v.w * v.w;
        }
        s = (s0 + s1) + (s2 + s3);
    } else {
        s = p[0] * p[0];
        for (int c = 1; c < C; ++c) s += p[c] * p[c];
    }
    xx[e] = s;
}

// ---------------- KNN ----------------
// Mimics the reference's fp32 formula: pd = (2*inner - xx_n) - xx_m, then
// top-k of pd (largest = nearest) with lowest-index tie-break. Using the same
// cancellation-prone fp32 form keeps our pd values within reduction-order ulps
// of the numpy reference, minimizing rank-20 boundary flips.

template <int C>
__global__ __launch_bounds__(256) void knn_kernel(const float* __restrict__ XT,
                                                  const float* __restrict__ xx,
                                                  int* __restrict__ idxb) {
    __shared__ float pds[4][NN];
    __shared__ alignas(16) float ctr[4][C];
    __shared__ float xr[4];
    int blk = blockIdx.x;
    int b = blk / (NN / 4);
    int n0 = (blk - b * (NN / 4)) * 4;
    int tid = threadIdx.x;
    for (int e = tid; e < 4 * C; e += 256) {
        int r = e / C, c = e - r * C;
        ctr[r][c] = XT[((size_t)b * NN + n0 + r) * C + c];
    }
    if (tid < 4) xr[tid] = xx[(size_t)b * NN + n0 + tid];
    __syncthreads();
    for (int m = tid; m < NN; m += 256) {
        const float* col = &XT[((size_t)b * NN + m) * C];
        float xxm = xx[(size_t)b * NN + m];
        float in0, in1, in2, in3;
        if constexpr (C % 4 == 0) {
            float p0[4] = {0, 0, 0, 0}, p1[4] = {0, 0, 0, 0},
                  p2[4] = {0, 0, 0, 0}, p3[4] = {0, 0, 0, 0};
            for (int c = 0; c < C; c += 4) {
                float4 v = *(const float4*)(col + c);
                float4 a0 = *(const float4*)&ctr[0][c];
                float4 a1 = *(const float4*)&ctr[1][c];
                float4 a2 = *(const float4*)&ctr[2][c];
                float4 a3 = *(const float4*)&ctr[3][c];
                p0[0] += v.x * a0.x; p0[1] += v.y * a0.y; p0[2] += v.z * a0.z; p0[3] += v.w * a0.w;
                p1[0] += v.x * a1.x; p1[1] += v.y * a1.y; p1[2] += v.z * a1.z; p1[3] += v.w * a1.w;
                p2[0] += v.x * a2.x; p2[1] += v.y * a2.y; p2[2] += v.z * a2.z; p2[3] += v.w * a2.w;
                p3[0] += v.x * a3.x; p3[1] += v.y * a3.y; p3[2] += v.z * a3.z; p3[3] += v.w * a3.w;
            }
            in0 = (p0[0] + p0[1]) + (p0[2] + p0[3]);
            in1 = (p1[0] + p1[1]) + (p1[2] + p1[3]);
            in2 = (p2[0] + p2[1]) + (p2[2] + p2[3]);
            in3 = (p3[0] + p3[1]) + (p3[2] + p3[3]);
        } else {
            in0 = col[0] * ctr[0][0]; in1 = col[0] * ctr[1][0];
            in2 = col[0] * ctr[2][0]; in3 = col[0] * ctr[3][0];
            for (int c = 1; c < C; ++c) {
                float v = col[c];
                in0 += v * ctr[0][c]; in1 += v * ctr[1][c];
                in2 += v * ctr[2][c]; in3 += v * ctr[3][c];
            }
        }
        pds[0][m] = (2.0f * in0 - xr[0]) - xxm;
        pds[1][m] = (2.0f * in1 - xr[1]) - xxm;
        pds[2][m] = (2.0f * in2 - xr[2]) - xxm;
        pds[3][m] = (2.0f * in3 - xr[3]) - xxm;
    }
    __syncthreads();
    int w = tid >> 6, lane = tid & 63;
    int* outp = idxb + ((size_t)b * NN + n0 + w) * KNN;
    for (int it = 0; it < KNN; ++it) {
        float bv = -FLT_MAX; int bi = -1;
        #pragma unroll
        for (int j = 0; j < NN / 64; ++j) {
            int m = lane + j * 64;
            float v = pds[w][m];
            if (v > bv) { bv = v; bi = m; }
        }
        for (int off = 32; off > 0; off >>= 1) {
            float ov = __shfl_down(bv, off);
            int oi = __shfl_down(bi, off);
            if (ov > bv || (ov == bv && (unsigned)oi < (unsigned)bi)) { bv = ov; bi = oi; }
        }
        int sel = __shfl(bi, 0);
        if (lane == 0) outp[it] = sel;
        if ((sel & 63) == lane) pds[w][sel] = -FLT_MAX;   // mask out chosen
        __syncthreads();
    }
}

// ---------------- EdgeConv pass A ----------------
// y[k,o] = Wa.nbr_k + (Wb-Wa).ctr. Accumulates per-channel sum/sumsq (BN stats,
// 64-way-spread atomics) and per-(n,o) max/min over k.

template <int C, int O>
__global__ __launch_bounds__(256) void edge_passA_kernel(
    const float* __restrict__ XT, const int* __restrict__ idxb,
    const float* __restrict__ WaT, const float* __restrict__ WdT,
    float* __restrict__ ymaxb, float* __restrict__ yminb, float* __restrict__ stats) {
    constexpr int OT = O / 4;
    constexpr int G = 256 / OT;
    constexpr int KP = (KNN + G - 1) / G;
    constexpr int CP = (C % 4 == 0) ? (C + 4) : C;
    __shared__ alignas(16) float ctr[C];
    __shared__ alignas(16) float nbr[KNN][CP];
    __shared__ alignas(16) float t2[O];
    __shared__ int sidx[KNN];
    __shared__ alignas(16) float red[4][1024];
    int blk = blockIdx.x;
    int b = blk >> 11;            // N = 2048
    int tid = threadIdx.x;
    if (tid < KNN) sidx[tid] = idxb[(size_t)blk * KNN + tid];
    for (int e = tid; e < C; e += 256) ctr[e] = XT[(size_t)blk * C + e];
    __syncthreads();
    if constexpr (C % 4 == 0) {
        for (int e = tid; e < KNN * (C / 4); e += 256) {
            int k = e / (C / 4), q = e - k * (C / 4);
            *(float4*)&nbr[k][q * 4] =
                *(const float4*)&XT[((size_t)b * NN + sidx[k]) * C + q * 4];
        }
    } else {
        for (int e = tid; e < KNN * C; e += 256) {
            int k = e / C, c = e - k * C;
            nbr[k][c] = XT[((size_t)b * NN + sidx[k]) * C + c];
        }
    }
    if (tid < O) {
        float s = 0;
        for (int c = 0; c < C; ++c) s += WdT[c * O + tid] * ctr[c];
        t2[tid] = s;
    }
    __syncthreads();
    int og = tid % OT, kg = tid / OT;
    int o0 = og * 4;
    float acc[KP][4];
    #pragma unroll
    for (int j = 0; j < KP; ++j) { acc[j][0] = 0; acc[j][1] = 0; acc[j][2] = 0; acc[j][3] = 0; }
    if constexpr (C % 4 == 0) {
        for (int c = 0; c < C; c += 4) {
            float4 w0 = *(const float4*)&WaT[(c + 0) * O + o0];
            float4 w1 = *(const float4*)&WaT[(c + 1) * O + o0];
            float4 w2 = *(const float4*)&WaT[(c + 2) * O + o0];
            float4 w3 = *(const float4*)&WaT[(c + 3) * O + o0];
            #pragma unroll
            for (int j = 0; j < KP; ++j) {
                int k = kg + j * G;
                if (k < KNN) {
                    float4 nv = *(const float4*)&nbr[k][c];
                    acc[j][0] += nv.x * w0.x + nv.y * w1.x + nv.z * w2.x + nv.w * w3.x;
                    acc[j][1] += nv.x * w0.y + nv.y * w1.y + nv.z * w2.y + nv.w * w3.y;
                    acc[j][2] += nv.x * w0.z + nv.y * w1.z + nv.z * w2.z + nv.w * w3.z;
                    acc[j][3] += nv.x * w0.w + nv.y * w1.w + nv.z * w2.w + nv.w * w3.w;
                }
            }
        }
    } else {
        for (int c = 0; c < C; ++c) {
            float4 w = *(const float4*)&WaT[c * O + o0];
            #pragma unroll
            for (int j = 0; j < KP; ++j) {
                int k = kg + j * G;
                if (k < KNN) {
                    float nv = nbr[k][c];
                    acc[j][0] += nv * w.x; acc[j][1] += nv * w.y;
                    acc[j][2] += nv * w.z; acc[j][3] += nv * w.w;
                }
            }
        }
    }
    float t2a[4];
    *(float4*)t2a = *(const float4*)&t2[o0];
    float vmax[4], vmin[4], vsum[4], vsq[4];
    #pragma unroll
    for (int q = 0; q < 4; ++q) { vmax[q] = -FLT_MAX; vmin[q] = FLT_MAX; vsum[q] = 0; vsq[q] = 0; }
    #pragma unroll
    for (int j = 0; j < KP; ++j) {
        int k = kg + j * G;
        if (k < KNN) {
            #pragma unroll
            for (int q = 0; q < 4; ++q) {
                float y = acc[j][q] + t2a[q];
                vmax[q] = fmaxf(vmax[q], y); vmin[q] = fminf(vmin[q], y);
                vsum[q] += y; vsq[q] += y * y;
            }
        }
    }
    *(float4*)&red[0][kg * O + o0] = make_float4(vmax[0], vmax[1], vmax[2], vmax[3]);
    *(float4*)&red[1][kg * O + o0] = make_float4(vmin[0], vmin[1], vmin[2], vmin[3]);
    *(float4*)&red[2][kg * O + o0] = make_float4(vsum[0], vsum[1], vsum[2], vsum[3]);
    *(float4*)&red[3][kg * O + o0] = make_float4(vsq[0], vsq[1], vsq[2], vsq[3]);
    __syncthreads();
    if (tid < O) {
        float m1 = -FLT_MAX, m2 = FLT_MAX, s1 = 0, s2 = 0;
        #pragma unroll 4
        for (int g = 0; g < G; ++g) {
            m1 = fmaxf(m1, red[0][g * O + tid]);
            m2 = fminf(m2, red[1][g * O + tid]);
            s1 += red[2][g * O + tid];
            s2 += red[3][g * O + tid];
        }
        ymaxb[(size_t)blk * O + tid] = m1;
        yminb[(size_t)blk * O + tid] = m2;
        float* st = &stats[(size_t)(blk & (NCOPY - 1)) * (2 * O)];
        atomicAdd(&st[tid], s1);
        atomicAdd(&st[O + tid], s2);
    }
}

// ---------------- BN finalize + edge pass B ----------------

__global__ void finalize_stats_kernel(const float* __restrict__ stats, const float* __restrict__ gg,
                                      const float* __restrict__ bb, float* __restrict__ scsh,
                                      int O, float invM) {
    int o = blockIdx.x * blockDim.x + threadIdx.x;
    if (o >= O) return;
    float s1 = 0, s2 = 0;
    for (int cp = 0; cp < NCOPY; ++cp) {
        s1 += stats[(size_t)cp * 2 * O + o];
        s2 += stats[(size_t)cp * 2 * O + O + o];
    }
    float mean = s1 * invM;
    float var = s2 * invM - mean * mean;
    float scale = gg[o] * rsqrtf(var + EPSV);
    float shift = bb[o] - mean * scale;
    scsh[o] = scale; scsh[O + o] = shift;
}

__global__ void edge_passB_kernel(const float* __restrict__ ymaxb, const float* __restrict__ yminb,
                                  const float* __restrict__ scsh, float* __restrict__ XTout,
                                  int O, int total) {
    int e = blockIdx.x * blockDim.x + threadIdx.x;
    if (e >= total) return;
    int o = e & (O - 1);   // O is a power of two
    float sc = scsh[o], sh = scsh[O + o];
    float y = (sc >= 0.0f) ? ymaxb[e] : yminb[e];   // monotone-affine max/min trick
    float z = sc * y + sh;
    XTout[e] = (z > 0.0f) ? z : SLOPEV * z;
}

// ---------------- final 512->1024 conv + BN + leaky + max/mean ----------------

__device__ __forceinline__ void stage_cat(float (*cat)[512], const float* __restrict__ XT1,
                                          const float* __restrict__ XT2, const float* __restrict__ XT3,
                                          const float* __restrict__ XT4, int b, int n0, int tid) {
    for (int e = tid; e < 16 * 16; e += 256) { int r = e >> 4, q = e & 15;
        *(float4*)&cat[r][q * 4]       = *(const float4*)&XT1[((size_t)b * NN + n0 + r) * 64 + q * 4]; }
    for (int e = tid; e < 16 * 16; e += 256) { int r = e >> 4, q = e & 15;
        *(float4*)&cat[r][64 + q * 4]  = *(const float4*)&XT2[((size_t)b * NN + n0 + r) * 64 + q * 4]; }
    for (int e = tid; e < 16 * 32; e += 256) { int r = e >> 5, q = e & 31;
        *(float4*)&cat[r][128 + q * 4] = *(const float4*)&XT3[((size_t)b * NN + n0 + r) * 128 + q * 4]; }
    for (int e = tid; e < 16 * 64; e += 256) { int r = e >> 6, q = e & 63;
        *(float4*)&cat[r][256 + q * 4] = *(const float4*)&XT4[((size_t)b * NN + n0 + r) * 256 + q * 4]; }
}

__global__ __launch_bounds__(256) void final_passA_kernel(
    const float* __restrict__ XT1, const float* __restrict__ XT2, const float* __restrict__ XT3,
    const float* __restrict__ XT4, const float* __restrict__ W5T, float* __restrict__ stats) {
    __shared__ alignas(16) float cat[16][512];
    int blk = blockIdx.x;
    int b = blk / (NN / 16);
    int n0 = (blk - b * (NN / 16)) * 16;
    int tid = threadIdx.x;
    stage_cat(cat, XT1, XT2, XT3, XT4, b, n0, tid);
    __syncthreads();
    int o0 = tid * 4;
    float acc[16][4];
    #pragma unroll
    for (int r = 0; r < 16; ++r) { acc[r][0] = 0; acc[r][1] = 0; acc[r][2] = 0; acc[r][3] = 0; }
    for (int c = 0; c < 512; c += 4) {
        float4 w0 = *(const float4*)&W5T[(size_t)(c + 0) * 1024 + o0];
        float4 w1 = *(const float4*)&W5T[(size_t)(c + 1) * 1024 + o0];
        float4 w2 = *(const float4*)&W5T[(size_t)(c + 2) * 1024 + o0];
        float4 w3 = *(const float4*)&W5T[(size_t)(c + 3) * 1024 + o0];
        #pragma unroll
        for (int r = 0; r < 16; ++r) {
            float4 cv = *(const float4*)&cat[r][c];
            acc[r][0] += cv.x * w0.x + cv.y * w1.x + cv.z * w2.x + cv.w * w3.x;
            acc[r][1] += cv.x * w0.y + cv.y * w1.y + cv.z * w2.y + cv.w * w3.y;
            acc[r][2] += cv.x * w0.z + cv.y * w1.z + cv.z * w2.z + cv.w * w3.z;
            acc[r][3] += cv.x * w0.w + cv.y * w1.w + cv.z * w2.w + cv.w * w3.w;
        }
    }
    float* st = &stats[(size_t)(blk & (NCOPY - 1)) * 2048];
    #pragma unroll
    for (int q = 0; q < 4; ++q) {
        float s1 = 0, s2 = 0;
        #pragma unroll
        for (int r = 0; r < 16; ++r) { float y = acc[r][q]; s1 += y; s2 += y * y; }
        atomicAdd(&st[o0 + q], s1);
        atomicAdd(&st[1024 + o0 + q], s2);
    }
}

__global__ __launch_bounds__(256) void final_passB_kernel(
    const float* __restrict__ XT1, const float* __restrict__ XT2, const float* __restrict__ XT3,
    const float* __restrict__ XT4, const float* __restrict__ W5T, const float* __restrict__ scsh,
    float* __restrict__ pmax, float* __restrict__ psum) {
    __shared__ alignas(16) float cat[16][512];
    int blk = blockIdx.x;
    int b = blk / (NN / 16);
    int n0 = (blk - b * (NN / 16)) * 16;
    int tid = threadIdx.x;
    stage_cat(cat, XT1, XT2, XT3, XT4, b, n0, tid);
    __syncthreads();
    int o0 = tid * 4;
    float acc[16][4];
    #pragma unroll
    for (int r = 0; r < 16; ++r) { acc[r][0] = 0; acc[r][1] = 0; acc[r][2] = 0; acc[r][3] = 0; }
    for (int c = 0; c < 512; c += 4) {
        float4 w0 = *(const float4*)&W5T[(size_t)(c + 0) * 1024 + o0];
        float4 w1 = *(const float4*)&W5T[(size_t)(c + 1) * 1024 + o0];
        float4 w2 = *(const float4*)&W5T[(size_t)(c + 2) * 1024 + o0];
        float4 w3 = *(const float4*)&W5T[(size_t)(c + 3) * 1024 + o0];
        #pragma unroll
        for (int r = 0; r < 16; ++r) {
            float4 cv = *(const float4*)&cat[r][c];
            acc[r][0] += cv.x * w0.x + cv.y * w1.x + cv.z * w2.x + cv.w * w3.x;
            acc[r][1] += cv.x * w0.y + cv.y * w1.y + cv.z * w2.y + cv.w * w3.y;
            acc[r][2] += cv.x * w0.z + cv.y * w1.z + cv.z * w2.z + cv.w * w3.z;
            acc[r][3] += cv.x * w0.w + cv.y * w1.w + cv.z * w2.w + cv.w * w3.w;
        }
    }
    #pragma unroll
    for (int q = 0; q < 4; ++q) {
        float scq = scsh[o0 + q], shq = scsh[1024 + o0 + q];
        float mx = -FLT_MAX, sm = 0;
        #pragma unroll
        for (int r = 0; r < 16; ++r) {
            float z = scq * acc[r][q] + shq;
            float l = (z > 0.0f) ? z : SLOPEV * z;
            mx = fmaxf(mx, l); sm += l;
        }
        pmax[(size_t)blk * 1024 + o0 + q] = mx;
        psum[(size_t)blk * 1024 + o0 + q] = sm;
    }
}

__global__ void final_passC_kernel(const float* __restrict__ pmax, const float* __restrict__ psum,
                                   float* __restrict__ out) {
    int e = blockIdx.x * blockDim.x + threadIdx.x;
    if (e >= BB * 1024) return;
    int b = e >> 10, o = e & 1023;
    float mx = -FLT_MAX, sm = 0;
    for (int j = 0; j < NN / 16; ++j) {
        size_t p = ((size_t)(b * (NN / 16) + j)) * 1024 + o;
        mx = fmaxf(mx, pmax[p]);
        sm += psum[p];
    }
    out[b * 2048 + o] = mx;
    out[b * 2048 + 1024 + o] = sm * (1.0f / NN);
}

// ---------------- launch ----------------

extern "C" void kernel_launch(void* const* d_in, const int* in_sizes, int n_in,
                              void* d_out, int out_size, void* d_ws, size_t ws_size,
                              hipStream_t stream) {
    const float* x  = (const float*)d_in[0];
    const float* W1 = (const float*)d_in[1];
    const float* W2 = (const float*)d_in[2];
    const float* W3 = (const float*)d_in[3];
    const float* W4 = (const float*)d_in[4];
    const float* W5 = (const float*)d_in[5];
    const float* g1 = (const float*)d_in[6];  const float* b1 = (const float*)d_in[7];
    const float* g2 = (const float*)d_in[8];  const float* b2 = (const float*)d_in[9];
    const float* g3 = (const float*)d_in[10]; const float* b3 = (const float*)d_in[11];
    const float* g4 = (const float*)d_in[12]; const float* b4 = (const float*)d_in[13];
    const float* g5 = (const float*)d_in[14]; const float* b5 = (const float*)d_in[15];

    float* ws = (float*)d_ws;
    size_t off = 0;
    float* XT0 = ws + off; off += (size_t)BB * NN * 3;
    float* XT1 = ws + off; off += (size_t)BB * NN * 64;
    float* XT2 = ws + off; off += (size_t)BB * NN * 64;
    float* XT3 = ws + off; off += (size_t)BB * NN * 128;
    float* XT4 = ws + off; off += (size_t)BB * NN * 256;
    float* ymax = ws + off; off += (size_t)BB * NN * 256;
    float* ymin = ws + off; off += (size_t)BB * NN * 256;
    int*   idxb = (int*)(ws + off); off += (size_t)BB * NN * KNN;
    float* xxb = ws + off; off += (size_t)BB * NN;
    float* WaT = ws + off; off += 128 * 256;
    float* WdT = ws + off; off += 128 * 256;
    float* W5T = ws + off; off += 512 * 1024;
    float* st1 = ws + off; off += NCOPY * 2 * 64;
    float* st2 = ws + off; off += NCOPY * 2 * 64;
    float* st3 = ws + off; off += NCOPY * 2 * 128;
    float* st4 = ws + off; off += NCOPY * 2 * 256;
    float* st5 = ws + off; off += NCOPY * 2 * 1024;
    float* sc1 = ws + off; off += 2 * 64;
    float* sc2 = ws + off; off += 2 * 64;
    float* sc3 = ws + off; off += 2 * 128;
    float* sc4 = ws + off; off += 2 * 256;
    float* sc5 = ws + off; off += 2 * 1024;
    float* pmax = ymax;   // reuse (edge buffers dead by final pass B)
    float* psum = ymin;

    // zero all BN-stat accumulators (ws is poisoned 0xAA before every call)
    hipMemsetAsync(st1, 0, (size_t)NCOPY * 2 * (64 + 64 + 128 + 256 + 1024) * sizeof(float), stream);

    transpose0_kernel<<<(BB * NN * 3 + 255) / 256, 256, 0, stream>>>(x, XT0);

    // layer 1: C=3 -> O=64
    wprep_kernel<<<(3 * 64 + 255) / 256, 256, 0, stream>>>(W1, WaT, WdT, 3, 64);
    xx_kernel<3><<<BB * NN / 256, 256, 0, stream>>>(XT0, xxb);
    knn_kernel<3><<<BB * NN / 4, 256, 0, stream>>>(XT0, xxb, idxb);
    edge_passA_kernel<3, 64><<<BB * NN, 256, 0, stream>>>(XT0, idxb, WaT, WdT, ymax, ymin, st1);
    finalize_stats_kernel<<<1, 64, 0, stream>>>(st1, g1, b1, sc1, 64, 1.0f / ((float)BB * NN * KNN));
    edge_passB_kernel<<<BB * NN * 64 / 256, 256, 0, stream>>>(ymax, ymin, sc1, XT1, 64, BB * NN * 64);

    // layer 2: C=64 -> O=64
    wprep_kernel<<<(64 * 64 + 255) / 256, 256, 0, stream>>>(W2, WaT, WdT, 64, 64);
    xx_kernel<64><<<BB * NN / 256, 256, 0, stream>>>(XT1, xxb);
    knn_kernel<64><<<BB * NN / 4, 256, 0, stream>>>(XT1, xxb, idxb);
    edge_passA_kernel<64, 64><<<BB * NN, 256, 0, stream>>>(XT1, idxb, WaT, WdT, ymax, ymin, st2);
    finalize_stats_kernel<<<1, 64, 0, stream>>>(st2, g2, b2, sc2, 64, 1.0f / ((float)BB * NN * KNN));
    edge_passB_kernel<<<BB * NN * 64 / 256, 256, 0, stream>>>(ymax, ymin, sc2, XT2, 64, BB * NN * 64);

    // layer 3: C=64 -> O=128
    wprep_kernel<<<(64 * 128 + 255) / 256, 256, 0, stream>>>(W3, WaT, WdT, 64, 128);
    xx_kernel<64><<<BB * NN / 256, 256, 0, stream>>>(XT2, xxb);
    knn_kernel<64><<<BB * NN / 4, 256, 0, stream>>>(XT2, xxb, idxb);
    edge_passA_kernel<64, 128><<<BB * NN, 256, 0, stream>>>(XT2, idxb, WaT, WdT, ymax, ymin, st3);
    finalize_stats_kernel<<<1, 128, 0, stream>>>(st3, g3, b3, sc3, 128, 1.0f / ((float)BB * NN * KNN));
    edge_passB_kernel<<<BB * NN * 128 / 256, 256, 0, stream>>>(ymax, ymin, sc3, XT3, 128, BB * NN * 128);

    // layer 4: C=128 -> O=256
    wprep_kernel<<<(128 * 256 + 255) / 256, 256, 0, stream>>>(W4, WaT, WdT, 128, 256);
    xx_kernel<128><<<BB * NN / 256, 256, 0, stream>>>(XT3, xxb);
    knn_kernel<128><<<BB * NN / 4, 256, 0, stream>>>(XT3, xxb, idxb);
    edge_passA_kernel<128, 256><<<BB * NN, 256, 0, stream>>>(XT3, idxb, WaT, WdT, ymax, ymin, st4);
    finalize_stats_kernel<<<1, 256, 0, stream>>>(st4, g4, b4, sc4, 256, 1.0f / ((float)BB * NN * KNN));
    edge_passB_kernel<<<BB * NN * 256 / 256, 256, 0, stream>>>(ymax, ymin, sc4, XT4, 256, BB * NN * 256);

    // final: 512 -> 1024, BN over (B,N), leaky, max+mean over N
    w5prep_kernel<<<512 * 1024 / 256, 256, 0, stream>>>(W5, W5T);
    final_passA_kernel<<<BB * NN / 16, 256, 0, stream>>>(XT1, XT2, XT3, XT4, W5T, st5);
    finalize_stats_kernel<<<4, 256, 0, stream>>>(st5, g5, b5, sc5, 1024, 1.0f / ((float)BB * NN));
    final_passB_kernel<<<BB * NN / 16, 256, 0, stream>>>(XT1, XT2, XT3, XT4, W5T, sc5, pmax, psum);
    final_passC_kernel<<<(BB * 1024 + 255) / 256, 256, 0, stream>>>(pmax, psum, (float*)d_out);

    (void)in_sizes; (void)n_in; (void)out_size; (void)ws_size;
}

// Round 3
// 3161.178 us; speedup vs baseline: 1.2636x; 1.2636x over previous
//
#include <hip/hip_runtime.h>
#include <cfloat>

#define BB 8
#define NN 2048
#define KNN 20
#define NCOPY 64
#define EPSV 1e-5f
#define SLOPEV 0.2f

// ---------------- small prep kernels ----------------

__global__ void transpose0_kernel(const float* __restrict__ x, float* __restrict__ XT0) {
    int e = blockIdx.x * blockDim.x + threadIdx.x;
    if (e >= BB * NN * 3) return;
    int b = e / (NN * 3); int r = e - b * NN * 3; int n = r / 3; int c = r - n * 3;
    XT0[e] = x[((size_t)b * 3 + c) * NN + n];
}

__global__ void wprep_kernel(const float* __restrict__ W, float* __restrict__ WaT,
                             float* __restrict__ WdT, int C, int O) {
    int e = blockIdx.x * blockDim.x + threadIdx.x;
    if (e >= C * O) return;
    int c = e / O, o = e - c * O;
    float a = W[o * 2 * C + c];
    WaT[e] = a;
    WdT[e] = W[o * 2 * C + C + c] - a;
}

__global__ void w5prep_kernel(const float* __restrict__ W5, float* __restrict__ W5T) {
    int e = blockIdx.x * blockDim.x + threadIdx.x;   // 512*1024 exact
    int c = e >> 10, o = e & 1023;
    W5T[e] = W5[o * 512 + c];
}

// ---------------- per-point squared norm (matches dot-product partial order) ----

template <int C>
__global__ void xx_kernel(const float* __restrict__ XT, float* __restrict__ xx) {
    int e = blockIdx.x * blockDim.x + threadIdx.x;
    if (e >= BB * NN) return;
    const float* p = &XT[(size_t)e * C];
    float s;
    if constexpr (C % 4 == 0) {
        float s0 = 0, s1 = 0, s2 = 0, s3 = 0;
        for (int c = 0; c < C; c += 4) {
            float4 v = *(const float4*)(p + c);
            s0 += v.x * v.x; s1 += v.y * v.y; s2 += v.z * v.z; s3 += v.w * v.w;
        }
        s = (s0 + s1) + (s2 + s3);
    } else {
        s = p[0] * p[0];
        for (int c = 1; c < C; ++c) s += p[c] * p[c];
    }
    xx[e] = s;
}

// ---------------- KNN v2 ----------------
// Block = 4 query rows, one wave per row. Phase 1: coalesced distance GEMV from
// channel-major XC (lane <-> m-quad, float4 loads); pd = (2*inner - xx_n) - xx_m
// replicates the reference's fp32 cancellation form. Phase 2: barrier-free
// selection — pd in wave-private LDS + per-lane register top-2 cache; 20x
// shfl_xor argmax (tie -> lowest index) with lazy owner rescans.

template <int C>
__global__ __launch_bounds__(256) void knn2_kernel(
    const float* __restrict__ XC,   // [B][C][N] channel-major
    const float* __restrict__ XT,   // [B][N][C] point-major (centers)
    const float* __restrict__ xx,   // [B][N]
    int* __restrict__ idxb) {
    __shared__ float pds[4][NN];
    __shared__ float ctr[4][(C < 4) ? 4 : C];
    __shared__ float xr[4];
    int blk = blockIdx.x;
    int b = blk >> 9;                // 512 blocks per batch
    int n0 = (blk & 511) * 4;
    int tid = threadIdx.x;
    int w = tid >> 6, lane = tid & 63;
    for (int e = tid; e < 4 * C; e += 256) {
        int r = e / C, c = e - r * C;
        ctr[r][c] = XT[((size_t)b * NN + n0 + r) * C + c];
    }
    if (tid < 4) xr[tid] = xx[(size_t)b * NN + n0 + tid];
    __syncthreads();

    const float* xcb = XC + (size_t)b * C * NN + 4 * lane;
    float4 aL[8];
    #pragma unroll
    for (int j = 0; j < 8; ++j) aL[j] = make_float4(0.f, 0.f, 0.f, 0.f);
    if constexpr (C >= 8) {
        float4 aH[8];
        #pragma unroll
        for (int j = 0; j < 8; ++j) aH[j] = make_float4(0.f, 0.f, 0.f, 0.f);
        for (int c = 0; c < C / 2; ++c) {
            float s = ctr[w][c];
            const float* p = xcb + (size_t)c * NN;
            #pragma unroll
            for (int j = 0; j < 8; ++j) {
                float4 v = *(const float4*)(p + j * 256);
                aL[j].x += v.x * s; aL[j].y += v.y * s; aL[j].z += v.z * s; aL[j].w += v.w * s;
            }
        }
        for (int c = C / 2; c < C; ++c) {
            float s = ctr[w][c];
            const float* p = xcb + (size_t)c * NN;
            #pragma unroll
            for (int j = 0; j < 8; ++j) {
                float4 v = *(const float4*)(p + j * 256);
                aH[j].x += v.x * s; aH[j].y += v.y * s; aH[j].z += v.z * s; aH[j].w += v.w * s;
            }
        }
        #pragma unroll
        for (int j = 0; j < 8; ++j) {
            aL[j].x += aH[j].x; aL[j].y += aH[j].y; aL[j].z += aH[j].z; aL[j].w += aH[j].w;
        }
    } else {
        for (int c = 0; c < C; ++c) {
            float s = ctr[w][c];
            const float* p = xcb + (size_t)c * NN;
            #pragma unroll
            for (int j = 0; j < 8; ++j) {
                float4 v = *(const float4*)(p + j * 256);
                aL[j].x += v.x * s; aL[j].y += v.y * s; aL[j].z += v.z * s; aL[j].w += v.w * s;
            }
        }
    }

    float xrn = xr[w];
    float v1 = -FLT_MAX, v2 = -FLT_MAX;
    int i1 = 0x7FFFFFFF, i2 = 0x7FFFFFFF;
    #define UPD(val, mm) do { \
        float _v = (val); int _m = (mm); \
        bool _b1 = (_v > v1) || (_v == v1 && _m < i1); \
        bool _b2 = (_v > v2) || (_v == v2 && _m < i2); \
        if (_b1) { v2 = v1; i2 = i1; v1 = _v; i1 = _m; } \
        else if (_b2) { v2 = _v; i2 = _m; } \
    } while (0)
    #pragma unroll
    for (int j = 0; j < 8; ++j) {
        int m0 = 4 * lane + 256 * j;
        float4 xm = *(const float4*)&xx[(size_t)b * NN + m0];
        float4 pd;
        pd.x = (2.0f * aL[j].x - xrn) - xm.x;
        pd.y = (2.0f * aL[j].y - xrn) - xm.y;
        pd.z = (2.0f * aL[j].z - xrn) - xm.z;
        pd.w = (2.0f * aL[j].w - xrn) - xm.w;
        *(float4*)&pds[w][m0] = pd;
        UPD(pd.x, m0); UPD(pd.y, m0 + 1); UPD(pd.z, m0 + 2); UPD(pd.w, m0 + 3);
    }
    // No barrier: pds[w] is wave-private from here on.
    int* outp = idxb + ((size_t)b * NN + n0 + w) * KNN;
    bool needscan = false;
    for (int it = 0; it < KNN; ++it) {
        float bv = v1; int bi = i1;
        #pragma unroll
        for (int off = 1; off < 64; off <<= 1) {
            float ov = __shfl_xor(bv, off);
            int oi = __shfl_xor(bi, off);
            if (ov > bv || (ov == bv && oi < bi)) { bv = ov; bi = oi; }
        }
        if (lane == 0) outp[it] = bi;
        if (i1 == bi) {                 // owner (m-sets disjoint across lanes)
            pds[w][bi] = -FLT_MAX;
            if (needscan) {
                v1 = -FLT_MAX; v2 = -FLT_MAX; i1 = 0x7FFFFFFF; i2 = 0x7FFFFFFF;
                #pragma unroll
                for (int j = 0; j < 8; ++j) {
                    int m0 = 4 * lane + 256 * j;
                    float4 pv = *(const float4*)&pds[w][m0];
                    UPD(pv.x, m0); UPD(pv.y, m0 + 1); UPD(pv.z, m0 + 2); UPD(pv.w, m0 + 3);
                }
                needscan = false;
            } else {
                v1 = v2; i1 = i2; needscan = true;
            }
        }
    }
    #undef UPD
}

// ---------------- EdgeConv pass A ----------------
// y[k,o] = Wa.nbr_k + (Wb-Wa).ctr. Accumulates per-channel sum/sumsq (BN stats,
// 64-way-spread atomics) and per-(n,o) max/min over k.

template <int C, int O>
__global__ __launch_bounds__(256) void edge_passA_kernel(
    const float* __restrict__ XT, const int* __restrict__ idxb,
    const float* __restrict__ WaT, const float* __restrict__ WdT,
    float* __restrict__ ymaxb, float* __restrict__ yminb, float* __restrict__ stats) {
    constexpr int OT = O / 4;
    constexpr int G = 256 / OT;
    constexpr int KP = (KNN + G - 1) / G;
    constexpr int CP = (C % 4 == 0) ? (C + 4) : C;
    __shared__ alignas(16) float ctr[C];
    __shared__ alignas(16) float nbr[KNN][CP];
    __shared__ alignas(16) float t2[O];
    __shared__ int sidx[KNN];
    __shared__ alignas(16) float red[4][1024];
    int blk = blockIdx.x;
    int b = blk >> 11;            // N = 2048
    int tid = threadIdx.x;
    if (tid < KNN) sidx[tid] = idxb[(size_t)blk * KNN + tid];
    for (int e = tid; e < C; e += 256) ctr[e] = XT[(size_t)blk * C + e];
    __syncthreads();
    if constexpr (C % 4 == 0) {
        for (int e = tid; e < KNN * (C / 4); e += 256) {
            int k = e / (C / 4), q = e - k * (C / 4);
            *(float4*)&nbr[k][q * 4] =
                *(const float4*)&XT[((size_t)b * NN + sidx[k]) * C + q * 4];
        }
    } else {
        for (int e = tid; e < KNN * C; e += 256) {
            int k = e / C, c = e - k * C;
            nbr[k][c] = XT[((size_t)b * NN + sidx[k]) * C + c];
        }
    }
    if (tid < O) {
        float s = 0;
        for (int c = 0; c < C; ++c) s += WdT[c * O + tid] * ctr[c];
        t2[tid] = s;
    }
    __syncthreads();
    int og = tid % OT, kg = tid / OT;
    int o0 = og * 4;
    float acc[KP][4];
    #pragma unroll
    for (int j = 0; j < KP; ++j) { acc[j][0] = 0; acc[j][1] = 0; acc[j][2] = 0; acc[j][3] = 0; }
    if constexpr (C % 4 == 0) {
        for (int c = 0; c < C; c += 4) {
            float4 w0 = *(const float4*)&WaT[(c + 0) * O + o0];
            float4 w1 = *(const float4*)&WaT[(c + 1) * O + o0];
            float4 w2 = *(const float4*)&WaT[(c + 2) * O + o0];
            float4 w3 = *(const float4*)&WaT[(c + 3) * O + o0];
            #pragma unroll
            for (int j = 0; j < KP; ++j) {
                int k = kg + j * G;
                if (k < KNN) {
                    float4 nv = *(const float4*)&nbr[k][c];
                    acc[j][0] += nv.x * w0.x + nv.y * w1.x + nv.z * w2.x + nv.w * w3.x;
                    acc[j][1] += nv.x * w0.y + nv.y * w1.y + nv.z * w2.y + nv.w * w3.y;
                    acc[j][2] += nv.x * w0.z + nv.y * w1.z + nv.z * w2.z + nv.w * w3.z;
                    acc[j][3] += nv.x * w0.w + nv.y * w1.w + nv.z * w2.w + nv.w * w3.w;
                }
            }
        }
    } else {
        for (int c = 0; c < C; ++c) {
            float4 w = *(const float4*)&WaT[c * O + o0];
            #pragma unroll
            for (int j = 0; j < KP; ++j) {
                int k = kg + j * G;
                if (k < KNN) {
                    float nv = nbr[k][c];
                    acc[j][0] += nv * w.x; acc[j][1] += nv * w.y;
                    acc[j][2] += nv * w.z; acc[j][3] += nv * w.w;
                }
            }
        }
    }
    float t2a[4];
    *(float4*)t2a = *(const float4*)&t2[o0];
    float vmax[4], vmin[4], vsum[4], vsq[4];
    #pragma unroll
    for (int q = 0; q < 4; ++q) { vmax[q] = -FLT_MAX; vmin[q] = FLT_MAX; vsum[q] = 0; vsq[q] = 0; }
    #pragma unroll
    for (int j = 0; j < KP; ++j) {
        int k = kg + j * G;
        if (k < KNN) {
            #pragma unroll
            for (int q = 0; q < 4; ++q) {
                float y = acc[j][q] + t2a[q];
                vmax[q] = fmaxf(vmax[q], y); vmin[q] = fminf(vmin[q], y);
                vsum[q] += y; vsq[q] += y * y;
            }
        }
    }
    *(float4*)&red[0][kg * O + o0] = make_float4(vmax[0], vmax[1], vmax[2], vmax[3]);
    *(float4*)&red[1][kg * O + o0] = make_float4(vmin[0], vmin[1], vmin[2], vmin[3]);
    *(float4*)&red[2][kg * O + o0] = make_float4(vsum[0], vsum[1], vsum[2], vsum[3]);
    *(float4*)&red[3][kg * O + o0] = make_float4(vsq[0], vsq[1], vsq[2], vsq[3]);
    __syncthreads();
    if (tid < O) {
        float m1 = -FLT_MAX, m2 = FLT_MAX, s1 = 0, s2 = 0;
        #pragma unroll 4
        for (int g = 0; g < G; ++g) {
            m1 = fmaxf(m1, red[0][g * O + tid]);
            m2 = fminf(m2, red[1][g * O + tid]);
            s1 += red[2][g * O + tid];
            s2 += red[3][g * O + tid];
        }
        ymaxb[(size_t)blk * O + tid] = m1;
        yminb[(size_t)blk * O + tid] = m2;
        float* st = &stats[(size_t)(blk & (NCOPY - 1)) * (2 * O)];
        atomicAdd(&st[tid], s1);
        atomicAdd(&st[O + tid], s2);
    }
}

// ---------------- BN finalize + edge pass B ----------------

__global__ void finalize_stats_kernel(const float* __restrict__ stats, const float* __restrict__ gg,
                                      const float* __restrict__ bb, float* __restrict__ scsh,
                                      int O, float invM) {
    int o = blockIdx.x * blockDim.x + threadIdx.x;
    if (o >= O) return;
    float s1 = 0, s2 = 0;
    for (int cp = 0; cp < NCOPY; ++cp) {
        s1 += stats[(size_t)cp * 2 * O + o];
        s2 += stats[(size_t)cp * 2 * O + O + o];
    }
    float mean = s1 * invM;
    float var = s2 * invM - mean * mean;
    float scale = gg[o] * rsqrtf(var + EPSV);
    float shift = bb[o] - mean * scale;
    scsh[o] = scale; scsh[O + o] = shift;
}

// Writes point-major XT; optionally also channel-major XC (for next layer's knn).
__global__ void edge_passB_kernel(const float* __restrict__ ymaxb, const float* __restrict__ yminb,
                                  const float* __restrict__ scsh, float* __restrict__ XTout,
                                  float* __restrict__ XCout, int O, int total) {
    int e = blockIdx.x * blockDim.x + threadIdx.x;
    if (e >= total) return;
    int o = e & (O - 1);   // O is a power of two
    float sc = scsh[o], sh = scsh[O + o];
    float y = (sc >= 0.0f) ? ymaxb[e] : yminb[e];   // monotone-affine max/min trick
    float z = sc * y + sh;
    float r = (z > 0.0f) ? z : SLOPEV * z;
    XTout[e] = r;
    if (XCout) {
        int n = (e / O) & (NN - 1);
        int bb_ = e / (O * NN);
        XCout[((size_t)bb_ * O + o) * NN + n] = r;
    }
}

// ---------------- final 512->1024 conv + BN + leaky + max/mean ----------------

__device__ __forceinline__ void stage_cat(float (*cat)[512], const float* __restrict__ XT1,
                                          const float* __restrict__ XT2, const float* __restrict__ XT3,
                                          const float* __restrict__ XT4, int b, int n0, int tid) {
    for (int e = tid; e < 16 * 16; e += 256) { int r = e >> 4, q = e & 15;
        *(float4*)&cat[r][q * 4]       = *(const float4*)&XT1[((size_t)b * NN + n0 + r) * 64 + q * 4]; }
    for (int e = tid; e < 16 * 16; e += 256) { int r = e >> 4, q = e & 15;
        *(float4*)&cat[r][64 + q * 4]  = *(const float4*)&XT2[((size_t)b * NN + n0 + r) * 64 + q * 4]; }
    for (int e = tid; e < 16 * 32; e += 256) { int r = e >> 5, q = e & 31;
        *(float4*)&cat[r][128 + q * 4] = *(const float4*)&XT3[((size_t)b * NN + n0 + r) * 128 + q * 4]; }
    for (int e = tid; e < 16 * 64; e += 256) { int r = e >> 6, q = e & 63;
        *(float4*)&cat[r][256 + q * 4] = *(const float4*)&XT4[((size_t)b * NN + n0 + r) * 256 + q * 4]; }
}

__global__ __launch_bounds__(256) void final_passA_kernel(
    const float* __restrict__ XT1, const float* __restrict__ XT2, const float* __restrict__ XT3,
    const float* __restrict__ XT4, const float* __restrict__ W5T, float* __restrict__ stats) {
    __shared__ alignas(16) float cat[16][512];
    int blk = blockIdx.x;
    int b = blk / (NN / 16);
    int n0 = (blk - b * (NN / 16)) * 16;
    int tid = threadIdx.x;
    stage_cat(cat, XT1, XT2, XT3, XT4, b, n0, tid);
    __syncthreads();
    int o0 = tid * 4;
    float acc[16][4];
    #pragma unroll
    for (int r = 0; r < 16; ++r) { acc[r][0] = 0; acc[r][1] = 0; acc[r][2] = 0; acc[r][3] = 0; }
    for (int c = 0; c < 512; c += 4) {
        float4 w0 = *(const float4*)&W5T[(size_t)(c + 0) * 1024 + o0];
        float4 w1 = *(const float4*)&W5T[(size_t)(c + 1) * 1024 + o0];
        float4 w2 = *(const float4*)&W5T[(size_t)(c + 2) * 1024 + o0];
        float4 w3 = *(const float4*)&W5T[(size_t)(c + 3) * 1024 + o0];
        #pragma unroll
        for (int r = 0; r < 16; ++r) {
            float4 cv = *(const float4*)&cat[r][c];
            acc[r][0] += cv.x * w0.x + cv.y * w1.x + cv.z * w2.x + cv.w * w3.x;
            acc[r][1] += cv.x * w0.y + cv.y * w1.y + cv.z * w2.y + cv.w * w3.y;
            acc[r][2] += cv.x * w0.z + cv.y * w1.z + cv.z * w2.z + cv.w * w3.z;
            acc[r][3] += cv.x * w0.w + cv.y * w1.w + cv.z * w2.w + cv.w * w3.w;
        }
    }
    float* st = &stats[(size_t)(blk & (NCOPY - 1)) * 2048];
    #pragma unroll
    for (int q = 0; q < 4; ++q) {
        float s1 = 0, s2 = 0;
        #pragma unroll
        for (int r = 0; r < 16; ++r) { float y = acc[r][q]; s1 += y; s2 += y * y; }
        atomicAdd(&st[o0 + q], s1);
        atomicAdd(&st[1024 + o0 + q], s2);
    }
}

__global__ __launch_bounds__(256) void final_passB_kernel(
    const float* __restrict__ XT1, const float* __restrict__ XT2, const float* __restrict__ XT3,
    const float* __restrict__ XT4, const float* __restrict__ W5T, const float* __restrict__ scsh,
    float* __restrict__ pmax, float* __restrict__ psum) {
    __shared__ alignas(16) float cat[16][512];
    int blk = blockIdx.x;
    int b = blk / (NN / 16);
    int n0 = (blk - b * (NN / 16)) * 16;
    int tid = threadIdx.x;
    stage_cat(cat, XT1, XT2, XT3, XT4, b, n0, tid);
    __syncthreads();
    int o0 = tid * 4;
    float acc[16][4];
    #pragma unroll
    for (int r = 0; r < 16; ++r) { acc[r][0] = 0; acc[r][1] = 0; acc[r][2] = 0; acc[r][3] = 0; }
    for (int c = 0; c < 512; c += 4) {
        float4 w0 = *(const float4*)&W5T[(size_t)(c + 0) * 1024 + o0];
        float4 w1 = *(const float4*)&W5T[(size_t)(c + 1) * 1024 + o0];
        float4 w2 = *(const float4*)&W5T[(size_t)(c + 2) * 1024 + o0];
        float4 w3 = *(const float4*)&W5T[(size_t)(c + 3) * 1024 + o0];
        #pragma unroll
        for (int r = 0; r < 16; ++r) {
            float4 cv = *(const float4*)&cat[r][c];
            acc[r][0] += cv.x * w0.x + cv.y * w1.x + cv.z * w2.x + cv.w * w3.x;
            acc[r][1] += cv.x * w0.y + cv.y * w1.y + cv.z * w2.y + cv.w * w3.y;
            acc[r][2] += cv.x * w0.z + cv.y * w1.z + cv.z * w2.z + cv.w * w3.z;
            acc[r][3] += cv.x * w0.w + cv.y * w1.w + cv.z * w2.w + cv.w * w3.w;
        }
    }
    #pragma unroll
    for (int q = 0; q < 4; ++q) {
        float scq = scsh[o0 + q], shq = scsh[1024 + o0 + q];
        float mx = -FLT_MAX, sm = 0;
        #pragma unroll
        for (int r = 0; r < 16; ++r) {
            float z = scq * acc[r][q] + shq;
            float l = (z > 0.0f) ? z : SLOPEV * z;
            mx = fmaxf(mx, l); sm += l;
        }
        pmax[(size_t)blk * 1024 + o0 + q] = mx;
        psum[(size_t)blk * 1024 + o0 + q] = sm;
    }
}

__global__ void final_passC_kernel(const float* __restrict__ pmax, const float* __restrict__ psum,
                                   float* __restrict__ out) {
    int e = blockIdx.x * blockDim.x + threadIdx.x;
    if (e >= BB * 1024) return;
    int b = e >> 10, o = e & 1023;
    float mx = -FLT_MAX, sm = 0;
    for (int j = 0; j < NN / 16; ++j) {
        size_t p = ((size_t)(b * (NN / 16) + j)) * 1024 + o;
        mx = fmaxf(mx, pmax[p]);
        sm += psum[p];
    }
    out[b * 2048 + o] = mx;
    out[b * 2048 + 1024 + o] = sm * (1.0f / NN);
}

// ---------------- launch ----------------

extern "C" void kernel_launch(void* const* d_in, const int* in_sizes, int n_in,
                              void* d_out, int out_size, void* d_ws, size_t ws_size,
                              hipStream_t stream) {
    const float* x  = (const float*)d_in[0];
    const float* W1 = (const float*)d_in[1];
    const float* W2 = (const float*)d_in[2];
    const float* W3 = (const float*)d_in[3];
    const float* W4 = (const float*)d_in[4];
    const float* W5 = (const float*)d_in[5];
    const float* g1 = (const float*)d_in[6];  const float* b1 = (const float*)d_in[7];
    const float* g2 = (const float*)d_in[8];  const float* b2 = (const float*)d_in[9];
    const float* g3 = (const float*)d_in[10]; const float* b3 = (const float*)d_in[11];
    const float* g4 = (const float*)d_in[12]; const float* b4 = (const float*)d_in[13];
    const float* g5 = (const float*)d_in[14]; const float* b5 = (const float*)d_in[15];

    float* ws = (float*)d_ws;
    size_t off = 0;
    float* XT0 = ws + off; off += (size_t)BB * NN * 3;
    float* XT1 = ws + off; off += (size_t)BB * NN * 64;
    float* XT2 = ws + off; off += (size_t)BB * NN * 64;
    float* XT3 = ws + off; off += (size_t)BB * NN * 128;
    float* XT4 = ws + off; off += (size_t)BB * NN * 256;
    float* XC1 = ws + off; off += (size_t)BB * NN * 64;
    float* XC2 = ws + off; off += (size_t)BB * NN * 64;
    float* XC3 = ws + off; off += (size_t)BB * NN * 128;
    float* ymax = ws + off; off += (size_t)BB * NN * 256;
    float* ymin = ws + off; off += (size_t)BB * NN * 256;
    int*   idxb = (int*)(ws + off); off += (size_t)BB * NN * KNN;
    float* xxb = ws + off; off += (size_t)BB * NN;
    float* WaT = ws + off; off += 128 * 256;
    float* WdT = ws + off; off += 128 * 256;
    float* W5T = ws + off; off += 512 * 1024;
    float* st1 = ws + off; off += NCOPY * 2 * 64;
    float* st2 = ws + off; off += NCOPY * 2 * 64;
    float* st3 = ws + off; off += NCOPY * 2 * 128;
    float* st4 = ws + off; off += NCOPY * 2 * 256;
    float* st5 = ws + off; off += NCOPY * 2 * 1024;
    float* sc1 = ws + off; off += 2 * 64;
    float* sc2 = ws + off; off += 2 * 64;
    float* sc3 = ws + off; off += 2 * 128;
    float* sc4 = ws + off; off += 2 * 256;
    float* sc5 = ws + off; off += 2 * 1024;
    float* pmax = ymax;   // reuse (edge buffers dead by final pass B)
    float* psum = ymin;

    // zero all BN-stat accumulators (ws is poisoned 0xAA before every call)
    hipMemsetAsync(st1, 0, (size_t)NCOPY * 2 * (64 + 64 + 128 + 256 + 1024) * sizeof(float), stream);

    transpose0_kernel<<<(BB * NN * 3 + 255) / 256, 256, 0, stream>>>(x, XT0);

    // layer 1: C=3 -> O=64   (x itself is the channel-major XC0)
    wprep_kernel<<<(3 * 64 + 255) / 256, 256, 0, stream>>>(W1, WaT, WdT, 3, 64);
    xx_kernel<3><<<BB * NN / 256, 256, 0, stream>>>(XT0, xxb);
    knn2_kernel<3><<<BB * NN / 4, 256, 0, stream>>>(x, XT0, xxb, idxb);
    edge_passA_kernel<3, 64><<<BB * NN, 256, 0, stream>>>(XT0, idxb, WaT, WdT, ymax, ymin, st1);
    finalize_stats_kernel<<<1, 64, 0, stream>>>(st1, g1, b1, sc1, 64, 1.0f / ((float)BB * NN * KNN));
    edge_passB_kernel<<<BB * NN * 64 / 256, 256, 0, stream>>>(ymax, ymin, sc1, XT1, XC1, 64, BB * NN * 64);

    // layer 2: C=64 -> O=64
    wprep_kernel<<<(64 * 64 + 255) / 256, 256, 0, stream>>>(W2, WaT, WdT, 64, 64);
    xx_kernel<64><<<BB * NN / 256, 256, 0, stream>>>(XT1, xxb);
    knn2_kernel<64><<<BB * NN / 4, 256, 0, stream>>>(XC1, XT1, xxb, idxb);
    edge_passA_kernel<64, 64><<<BB * NN, 256, 0, stream>>>(XT1, idxb, WaT, WdT, ymax, ymin, st2);
    finalize_stats_kernel<<<1, 64, 0, stream>>>(st2, g2, b2, sc2, 64, 1.0f / ((float)BB * NN * KNN));
    edge_passB_kernel<<<BB * NN * 64 / 256, 256, 0, stream>>>(ymax, ymin, sc2, XT2, XC2, 64, BB * NN * 64);

    // layer 3: C=64 -> O=128
    wprep_kernel<<<(64 * 128 + 255) / 256, 256, 0, stream>>>(W3, WaT, WdT, 64, 128);
    xx_kernel<64><<<BB * NN / 256, 256, 0, stream>>>(XT2, xxb);
    knn2_kernel<64><<<BB * NN / 4, 256, 0, stream>>>(XC2, XT2, xxb, idxb);
    edge_passA_kernel<64, 128><<<BB * NN, 256, 0, stream>>>(XT2, idxb, WaT, WdT, ymax, ymin, st3);
    finalize_stats_kernel<<<1, 128, 0, stream>>>(st3, g3, b3, sc3, 128, 1.0f / ((float)BB * NN * KNN));
    edge_passB_kernel<<<BB * NN * 128 / 256, 256, 0, stream>>>(ymax, ymin, sc3, XT3, XC3, 128, BB * NN * 128);

    // layer 4: C=128 -> O=256
    wprep_kernel<<<(128 * 256 + 255) / 256, 256, 0, stream>>>(W4, WaT, WdT, 128, 256);
    xx_kernel<128><<<BB * NN / 256, 256, 0, stream>>>(XT3, xxb);
    knn2_kernel<128><<<BB * NN / 4, 256, 0, stream>>>(XC3, XT3, xxb, idxb);
    edge_passA_kernel<128, 256><<<BB * NN, 256, 0, stream>>>(XT3, idxb, WaT, WdT, ymax, ymin, st4);
    finalize_stats_kernel<<<1, 256, 0, stream>>>(st4, g4, b4, sc4, 256, 1.0f / ((float)BB * NN * KNN));
    edge_passB_kernel<<<BB * NN * 256 / 256, 256, 0, stream>>>(ymax, ymin, sc4, XT4, nullptr, 256, BB * NN * 256);

    // final: 512 -> 1024, BN over (B,N), leaky, max+mean over N
    w5prep_kernel<<<512 * 1024 / 256, 256, 0, stream>>>(W5, W5T);
    final_passA_kernel<<<BB * NN / 16, 256, 0, stream>>>(XT1, XT2, XT3, XT4, W5T, st5);
    finalize_stats_kernel<<<4, 256, 0, stream>>>(st5, g5, b5, sc5, 1024, 1.0f / ((float)BB * NN));
    final_passB_kernel<<<BB * NN / 16, 256, 0, stream>>>(XT1, XT2, XT3, XT4, W5T, sc5, pmax, psum);
    final_passC_kernel<<<(BB * 1024 + 255) / 256, 256, 0, stream>>>(pmax, psum, (float*)d_out);

    (void)in_sizes; (void)n_in; (void)out_size; (void)ws_size;
}

// Round 4
// 2501.827 us; speedup vs baseline: 1.5966x; 1.2635x over previous
//
#include <hip/hip_runtime.h>
#include <cfloat>

#define BB 8
#define NN 2048
#define KNN 20
#define NCOPY 64
#define EPSV 1e-5f
#define SLOPEV 0.2f

// ---------------- small prep kernels ----------------

__global__ void transpose0_kernel(const float* __restrict__ x, float* __restrict__ XT0) {
    int e = blockIdx.x * blockDim.x + threadIdx.x;
    if (e >= BB * NN * 3) return;
    int b = e / (NN * 3); int r = e - b * NN * 3; int n = r / 3; int c = r - n * 3;
    XT0[e] = x[((size_t)b * 3 + c) * NN + n];
}

__global__ void wprep_kernel(const float* __restrict__ W, float* __restrict__ WaT,
                             float* __restrict__ WdT, int C, int O) {
    int e = blockIdx.x * blockDim.x + threadIdx.x;
    if (e >= C * O) return;
    int c = e / O, o = e - c * O;
    float a = W[o * 2 * C + c];
    WaT[e] = a;
    WdT[e] = W[o * 2 * C + C + c] - a;
}

__global__ void w5prep_kernel(const float* __restrict__ W5, float* __restrict__ W5T) {
    int e = blockIdx.x * blockDim.x + threadIdx.x;   // 512*1024 exact
    int c = e >> 10, o = e & 1023;
    W5T[e] = W5[o * 512 + c];
}

// ---------------- per-point squared norm (matches dot-product partial order) ----

template <int C>
__global__ void xx_kernel(const float* __restrict__ XT, float* __restrict__ xx) {
    int e = blockIdx.x * blockDim.x + threadIdx.x;
    if (e >= BB * NN) return;
    const float* p = &XT[(size_t)e * C];
    float s;
    if constexpr (C % 4 == 0) {
        float s0 = 0, s1 = 0, s2 = 0, s3 = 0;
        for (int c = 0; c < C; c += 4) {
            float4 v = *(const float4*)(p + c);
            s0 += v.x * v.x; s1 += v.y * v.y; s2 += v.z * v.z; s3 += v.w * v.w;
        }
        s = (s0 + s1) + (s2 + s3);
    } else {
        s = p[0] * p[0];
        for (int c = 1; c < C; ++c) s += p[c] * p[c];
    }
    xx[e] = s;
}

// ---------------- KNN v3 ----------------
// Block = 8 query rows; 4 waves own disjoint 512-wide m-ranges (2 half-passes
// of 256 m). pd tile in 64 KB LDS; XC slice read once per block (8x traffic
// cut vs knn2). Inner product uses 4 interleaved channel-class partials
// combined (P0+P1)+(P2+P3) — the round-2 structure that matched np (0.03).
// pd = (2*inner - xx_n) - xx_m. Selection: wave -> 2 rows sequentially, lazy
// top-2 register cache + 6-level shfl_xor argmax, lowest-index ties.

#define UPD(val, mm) do { \
    float _v = (val); int _m = (mm); \
    bool _b1 = (_v > v1) || (_v == v1 && _m < i1); \
    bool _b2 = (_v > v2) || (_v == v2 && _m < i2); \
    if (_b1) { v2 = v1; i2 = i1; v1 = _v; i1 = _m; } \
    else if (_b2) { v2 = _v; i2 = _m; } \
} while (0)

template <int C>
__global__ __launch_bounds__(256) void knn3_kernel(
    const float* __restrict__ XC,   // [B][C][N] channel-major
    const float* __restrict__ XT,   // [B][N][C] point-major (centers)
    const float* __restrict__ xx,   // [B][N]
    int* __restrict__ idxb) {
    __shared__ float pds[8][NN];    // exactly 64 KB
    int blk = blockIdx.x;
    int b = blk >> 8;               // 256 blocks per batch (N/8)
    int n0 = (blk & 255) * 8;
    int tid = threadIdx.x;
    int w = tid >> 6, lane = tid & 63;
    const size_t baseN = (size_t)b * NN;
    const float* xt0 = XT + (baseN + n0) * C;

    float xr[8];
    #pragma unroll
    for (int r = 0; r < 8; ++r) xr[r] = xx[baseN + n0 + r];

    #pragma unroll
    for (int h = 0; h < 2; ++h) {
        int m0 = w * 512 + h * 256 + 4 * lane;
        const float* xcb = XC + (size_t)b * C * NN + m0;
        float4 xxm = *(const float4*)&xx[baseN + m0];
        if constexpr (C % 4 == 0) {
            float4 P0[8], P1[8], P2[8], P3[8];
            #pragma unroll
            for (int r = 0; r < 8; ++r) {
                P0[r] = make_float4(0.f, 0.f, 0.f, 0.f); P1[r] = P0[r];
                P2[r] = P0[r]; P3[r] = P0[r];
            }
            for (int cq = 0; cq < C / 4; ++cq) {
                float4 v0 = *(const float4*)(xcb + (size_t)(4 * cq + 0) * NN);
                float4 v1 = *(const float4*)(xcb + (size_t)(4 * cq + 1) * NN);
                float4 v2 = *(const float4*)(xcb + (size_t)(4 * cq + 2) * NN);
                float4 v3 = *(const float4*)(xcb + (size_t)(4 * cq + 3) * NN);
                #pragma unroll
                for (int r = 0; r < 8; ++r) {
                    float4 s = *(const float4*)(xt0 + r * C + 4 * cq);
                    P0[r].x += v0.x * s.x; P0[r].y += v0.y * s.x; P0[r].z += v0.z * s.x; P0[r].w += v0.w * s.x;
                    P1[r].x += v1.x * s.y; P1[r].y += v1.y * s.y; P1[r].z += v1.z * s.y; P1[r].w += v1.w * s.y;
                    P2[r].x += v2.x * s.z; P2[r].y += v2.y * s.z; P2[r].z += v2.z * s.z; P2[r].w += v2.w * s.z;
                    P3[r].x += v3.x * s.w; P3[r].y += v3.y * s.w; P3[r].z += v3.z * s.w; P3[r].w += v3.w * s.w;
                }
            }
            #pragma unroll
            for (int r = 0; r < 8; ++r) {
                float4 inn, pd;
                inn.x = (P0[r].x + P1[r].x) + (P2[r].x + P3[r].x);
                inn.y = (P0[r].y + P1[r].y) + (P2[r].y + P3[r].y);
                inn.z = (P0[r].z + P1[r].z) + (P2[r].z + P3[r].z);
                inn.w = (P0[r].w + P1[r].w) + (P2[r].w + P3[r].w);
                pd.x = (2.0f * inn.x - xr[r]) - xxm.x;
                pd.y = (2.0f * inn.y - xr[r]) - xxm.y;
                pd.z = (2.0f * inn.z - xr[r]) - xxm.z;
                pd.w = (2.0f * inn.w - xr[r]) - xxm.w;
                *(float4*)&pds[r][m0] = pd;
            }
        } else {
            float4 P[8];
            #pragma unroll
            for (int r = 0; r < 8; ++r) P[r] = make_float4(0.f, 0.f, 0.f, 0.f);
            for (int c = 0; c < C; ++c) {
                float4 v = *(const float4*)(xcb + (size_t)c * NN);
                #pragma unroll
                for (int r = 0; r < 8; ++r) {
                    float s = xt0[r * C + c];
                    P[r].x += v.x * s; P[r].y += v.y * s; P[r].z += v.z * s; P[r].w += v.w * s;
                }
            }
            #pragma unroll
            for (int r = 0; r < 8; ++r) {
                float4 pd;
                pd.x = (2.0f * P[r].x - xr[r]) - xxm.x;
                pd.y = (2.0f * P[r].y - xr[r]) - xxm.y;
                pd.z = (2.0f * P[r].z - xr[r]) - xxm.z;
                pd.w = (2.0f * P[r].w - xr[r]) - xxm.w;
                *(float4*)&pds[r][m0] = pd;
            }
        }
    }
    __syncthreads();

    // selection: wave w handles rows 2w, 2w+1 (pds rows are block-shared, but
    // after the barrier each row is touched by exactly one wave).
    for (int rr = 0; rr < 2; ++rr) {
        int r = 2 * w + rr;
        float v1 = -FLT_MAX, v2 = -FLT_MAX;
        int i1 = 0x7FFFFFFF, i2 = 0x7FFFFFFF;
        #pragma unroll
        for (int j = 0; j < 8; ++j) {
            int m0 = 4 * lane + 256 * j;
            float4 pv = *(const float4*)&pds[r][m0];
            UPD(pv.x, m0); UPD(pv.y, m0 + 1); UPD(pv.z, m0 + 2); UPD(pv.w, m0 + 3);
        }
        int* outp = idxb + (baseN + n0 + r) * KNN;
        bool needscan = false;
        for (int it = 0; it < KNN; ++it) {
            float bv = v1; int bi = i1;
            #pragma unroll
            for (int off = 1; off < 64; off <<= 1) {
                float ov = __shfl_xor(bv, off);
                int oi = __shfl_xor(bi, off);
                if (ov > bv || (ov == bv && oi < bi)) { bv = ov; bi = oi; }
            }
            if (lane == 0) outp[it] = bi;
            if (i1 == bi) {                 // owner (m-sets disjoint across lanes)
                pds[r][bi] = -FLT_MAX;
                if (needscan) {
                    v1 = -FLT_MAX; v2 = -FLT_MAX; i1 = 0x7FFFFFFF; i2 = 0x7FFFFFFF;
                    #pragma unroll
                    for (int j = 0; j < 8; ++j) {
                        int m0 = 4 * lane + 256 * j;
                        float4 pv = *(const float4*)&pds[r][m0];
                        UPD(pv.x, m0); UPD(pv.y, m0 + 1); UPD(pv.z, m0 + 2); UPD(pv.w, m0 + 3);
                    }
                    needscan = false;
                } else {
                    v1 = v2; i1 = i2; needscan = true;
                }
            }
        }
    }
}
#undef UPD

// ---------------- EdgeConv pass A ----------------
// y[k,o] = Wa.nbr_k + (Wb-Wa).ctr. Accumulates per-channel sum/sumsq (BN stats,
// 64-way-spread atomics) and per-(n,o) max/min over k.

template <int C, int O>
__global__ __launch_bounds__(256) void edge_passA_kernel(
    const float* __restrict__ XT, const int* __restrict__ idxb,
    const float* __restrict__ WaT, const float* __restrict__ WdT,
    float* __restrict__ ymaxb, float* __restrict__ yminb, float* __restrict__ stats) {
    constexpr int OT = O / 4;
    constexpr int G = 256 / OT;
    constexpr int KP = (KNN + G - 1) / G;
    constexpr int CP = (C % 4 == 0) ? (C + 4) : C;
    __shared__ alignas(16) float ctr[C];
    __shared__ alignas(16) float nbr[KNN][CP];
    __shared__ alignas(16) float t2[O];
    __shared__ int sidx[KNN];
    __shared__ alignas(16) float red[4][1024];
    int blk = blockIdx.x;
    int b = blk >> 11;            // N = 2048
    int tid = threadIdx.x;
    if (tid < KNN) sidx[tid] = idxb[(size_t)blk * KNN + tid];
    for (int e = tid; e < C; e += 256) ctr[e] = XT[(size_t)blk * C + e];
    __syncthreads();
    if constexpr (C % 4 == 0) {
        for (int e = tid; e < KNN * (C / 4); e += 256) {
            int k = e / (C / 4), q = e - k * (C / 4);
            *(float4*)&nbr[k][q * 4] =
                *(const float4*)&XT[((size_t)b * NN + sidx[k]) * C + q * 4];
        }
    } else {
        for (int e = tid; e < KNN * C; e += 256) {
            int k = e / C, c = e - k * C;
            nbr[k][c] = XT[((size_t)b * NN + sidx[k]) * C + c];
        }
    }
    if (tid < O) {
        float s = 0;
        for (int c = 0; c < C; ++c) s += WdT[c * O + tid] * ctr[c];
        t2[tid] = s;
    }
    __syncthreads();
    int og = tid % OT, kg = tid / OT;
    int o0 = og * 4;
    float acc[KP][4];
    #pragma unroll
    for (int j = 0; j < KP; ++j) { acc[j][0] = 0; acc[j][1] = 0; acc[j][2] = 0; acc[j][3] = 0; }
    if constexpr (C % 4 == 0) {
        for (int c = 0; c < C; c += 4) {
            float4 w0 = *(const float4*)&WaT[(c + 0) * O + o0];
            float4 w1 = *(const float4*)&WaT[(c + 1) * O + o0];
            float4 w2 = *(const float4*)&WaT[(c + 2) * O + o0];
            float4 w3 = *(const float4*)&WaT[(c + 3) * O + o0];
            #pragma unroll
            for (int j = 0; j < KP; ++j) {
                int k = kg + j * G;
                if (k < KNN) {
                    float4 nv = *(const float4*)&nbr[k][c];
                    acc[j][0] += nv.x * w0.x + nv.y * w1.x + nv.z * w2.x + nv.w * w3.x;
                    acc[j][1] += nv.x * w0.y + nv.y * w1.y + nv.z * w2.y + nv.w * w3.y;
                    acc[j][2] += nv.x * w0.z + nv.y * w1.z + nv.z * w2.z + nv.w * w3.z;
                    acc[j][3] += nv.x * w0.w + nv.y * w1.w + nv.z * w2.w + nv.w * w3.w;
                }
            }
        }
    } else {
        for (int c = 0; c < C; ++c) {
            float4 w = *(const float4*)&WaT[c * O + o0];
            #pragma unroll
            for (int j = 0; j < KP; ++j) {
                int k = kg + j * G;
                if (k < KNN) {
                    float nv = nbr[k][c];
                    acc[j][0] += nv * w.x; acc[j][1] += nv * w.y;
                    acc[j][2] += nv * w.z; acc[j][3] += nv * w.w;
                }
            }
        }
    }
    float t2a[4];
    *(float4*)t2a = *(const float4*)&t2[o0];
    float vmax[4], vmin[4], vsum[4], vsq[4];
    #pragma unroll
    for (int q = 0; q < 4; ++q) { vmax[q] = -FLT_MAX; vmin[q] = FLT_MAX; vsum[q] = 0; vsq[q] = 0; }
    #pragma unroll
    for (int j = 0; j < KP; ++j) {
        int k = kg + j * G;
        if (k < KNN) {
            #pragma unroll
            for (int q = 0; q < 4; ++q) {
                float y = acc[j][q] + t2a[q];
                vmax[q] = fmaxf(vmax[q], y); vmin[q] = fminf(vmin[q], y);
                vsum[q] += y; vsq[q] += y * y;
            }
        }
    }
    *(float4*)&red[0][kg * O + o0] = make_float4(vmax[0], vmax[1], vmax[2], vmax[3]);
    *(float4*)&red[1][kg * O + o0] = make_float4(vmin[0], vmin[1], vmin[2], vmin[3]);
    *(float4*)&red[2][kg * O + o0] = make_float4(vsum[0], vsum[1], vsum[2], vsum[3]);
    *(float4*)&red[3][kg * O + o0] = make_float4(vsq[0], vsq[1], vsq[2], vsq[3]);
    __syncthreads();
    if (tid < O) {
        float m1 = -FLT_MAX, m2 = FLT_MAX, s1 = 0, s2 = 0;
        #pragma unroll 4
        for (int g = 0; g < G; ++g) {
            m1 = fmaxf(m1, red[0][g * O + tid]);
            m2 = fminf(m2, red[1][g * O + tid]);
            s1 += red[2][g * O + tid];
            s2 += red[3][g * O + tid];
        }
        ymaxb[(size_t)blk * O + tid] = m1;
        yminb[(size_t)blk * O + tid] = m2;
        float* st = &stats[(size_t)(blk & (NCOPY - 1)) * (2 * O)];
        atomicAdd(&st[tid], s1);
        atomicAdd(&st[O + tid], s2);
    }
}

// ---------------- BN finalize + edge pass B ----------------

__global__ void finalize_stats_kernel(const float* __restrict__ stats, const float* __restrict__ gg,
                                      const float* __restrict__ bb, float* __restrict__ scsh,
                                      int O, float invM) {
    int o = blockIdx.x * blockDim.x + threadIdx.x;
    if (o >= O) return;
    float s1 = 0, s2 = 0;
    for (int cp = 0; cp < NCOPY; ++cp) {
        s1 += stats[(size_t)cp * 2 * O + o];
        s2 += stats[(size_t)cp * 2 * O + O + o];
    }
    float mean = s1 * invM;
    float var = s2 * invM - mean * mean;
    float scale = gg[o] * rsqrtf(var + EPSV);
    float shift = bb[o] - mean * scale;
    scsh[o] = scale; scsh[O + o] = shift;
}

// Writes point-major XT; optionally also channel-major XC (for next layer's knn).
__global__ void edge_passB_kernel(const float* __restrict__ ymaxb, const float* __restrict__ yminb,
                                  const float* __restrict__ scsh, float* __restrict__ XTout,
                                  float* __restrict__ XCout, int O, int total) {
    int e = blockIdx.x * blockDim.x + threadIdx.x;
    if (e >= total) return;
    int o = e & (O - 1);   // O is a power of two
    float sc = scsh[o], sh = scsh[O + o];
    float y = (sc >= 0.0f) ? ymaxb[e] : yminb[e];   // monotone-affine max/min trick
    float z = sc * y + sh;
    float r = (z > 0.0f) ? z : SLOPEV * z;
    XTout[e] = r;
    if (XCout) {
        int n = (e / O) & (NN - 1);
        int bb_ = e / (O * NN);
        XCout[((size_t)bb_ * O + o) * NN + n] = r;
    }
}

// ---------------- final 512->1024 conv + BN + leaky + max/mean ----------------

__device__ __forceinline__ void stage_cat(float (*cat)[512], const float* __restrict__ XT1,
                                          const float* __restrict__ XT2, const float* __restrict__ XT3,
                                          const float* __restrict__ XT4, int b, int n0, int tid) {
    for (int e = tid; e < 16 * 16; e += 256) { int r = e >> 4, q = e & 15;
        *(float4*)&cat[r][q * 4]       = *(const float4*)&XT1[((size_t)b * NN + n0 + r) * 64 + q * 4]; }
    for (int e = tid; e < 16 * 16; e += 256) { int r = e >> 4, q = e & 15;
        *(float4*)&cat[r][64 + q * 4]  = *(const float4*)&XT2[((size_t)b * NN + n0 + r) * 64 + q * 4]; }
    for (int e = tid; e < 16 * 32; e += 256) { int r = e >> 5, q = e & 31;
        *(float4*)&cat[r][128 + q * 4] = *(const float4*)&XT3[((size_t)b * NN + n0 + r) * 128 + q * 4]; }
    for (int e = tid; e < 16 * 64; e += 256) { int r = e >> 6, q = e & 63;
        *(float4*)&cat[r][256 + q * 4] = *(const float4*)&XT4[((size_t)b * NN + n0 + r) * 256 + q * 4]; }
}

__global__ __launch_bounds__(256) void final_passA_kernel(
    const float* __restrict__ XT1, const float* __restrict__ XT2, const float* __restrict__ XT3,
    const float* __restrict__ XT4, const float* __restrict__ W5T, float* __restrict__ stats) {
    __shared__ alignas(16) float cat[16][512];
    int blk = blockIdx.x;
    int b = blk / (NN / 16);
    int n0 = (blk - b * (NN / 16)) * 16;
    int tid = threadIdx.x;
    stage_cat(cat, XT1, XT2, XT3, XT4, b, n0, tid);
    __syncthreads();
    int o0 = tid * 4;
    float acc[16][4];
    #pragma unroll
    for (int r = 0; r < 16; ++r) { acc[r][0] = 0; acc[r][1] = 0; acc[r][2] = 0; acc[r][3] = 0; }
    for (int c = 0; c < 512; c += 4) {
        float4 w0 = *(const float4*)&W5T[(size_t)(c + 0) * 1024 + o0];
        float4 w1 = *(const float4*)&W5T[(size_t)(c + 1) * 1024 + o0];
        float4 w2 = *(const float4*)&W5T[(size_t)(c + 2) * 1024 + o0];
        float4 w3 = *(const float4*)&W5T[(size_t)(c + 3) * 1024 + o0];
        #pragma unroll
        for (int r = 0; r < 16; ++r) {
            float4 cv = *(const float4*)&cat[r][c];
            acc[r][0] += cv.x * w0.x + cv.y * w1.x + cv.z * w2.x + cv.w * w3.x;
            acc[r][1] += cv.x * w0.y + cv.y * w1.y + cv.z * w2.y + cv.w * w3.y;
            acc[r][2] += cv.x * w0.z + cv.y * w1.z + cv.z * w2.z + cv.w * w3.z;
            acc[r][3] += cv.x * w0.w + cv.y * w1.w + cv.z * w2.w + cv.w * w3.w;
        }
    }
    float* st = &stats[(size_t)(blk & (NCOPY - 1)) * 2048];
    #pragma unroll
    for (int q = 0; q < 4; ++q) {
        float s1 = 0, s2 = 0;
        #pragma unroll
        for (int r = 0; r < 16; ++r) { float y = acc[r][q]; s1 += y; s2 += y * y; }
        atomicAdd(&st[o0 + q], s1);
        atomicAdd(&st[1024 + o0 + q], s2);
    }
}

__global__ __launch_bounds__(256) void final_passB_kernel(
    const float* __restrict__ XT1, const float* __restrict__ XT2, const float* __restrict__ XT3,
    const float* __restrict__ XT4, const float* __restrict__ W5T, const float* __restrict__ scsh,
    float* __restrict__ pmax, float* __restrict__ psum) {
    __shared__ alignas(16) float cat[16][512];
    int blk = blockIdx.x;
    int b = blk / (NN / 16);
    int n0 = (blk - b * (NN / 16)) * 16;
    int tid = threadIdx.x;
    stage_cat(cat, XT1, XT2, XT3, XT4, b, n0, tid);
    __syncthreads();
    int o0 = tid * 4;
    float acc[16][4];
    #pragma unroll
    for (int r = 0; r < 16; ++r) { acc[r][0] = 0; acc[r][1] = 0; acc[r][2] = 0; acc[r][3] = 0; }
    for (int c = 0; c < 512; c += 4) {
        float4 w0 = *(const float4*)&W5T[(size_t)(c + 0) * 1024 + o0];
        float4 w1 = *(const float4*)&W5T[(size_t)(c + 1) * 1024 + o0];
        float4 w2 = *(const float4*)&W5T[(size_t)(c + 2) * 1024 + o0];
        float4 w3 = *(const float4*)&W5T[(size_t)(c + 3) * 1024 + o0];
        #pragma unroll
        for (int r = 0; r < 16; ++r) {
            float4 cv = *(const float4*)&cat[r][c];
            acc[r][0] += cv.x * w0.x + cv.y * w1.x + cv.z * w2.x + cv.w * w3.x;
            acc[r][1] += cv.x * w0.y + cv.y * w1.y + cv.z * w2.y + cv.w * w3.y;
            acc[r][2] += cv.x * w0.z + cv.y * w1.z + cv.z * w2.z + cv.w * w3.z;
            acc[r][3] += cv.x * w0.w + cv.y * w1.w + cv.z * w2.w + cv.w * w3.w;
        }
    }
    #pragma unroll
    for (int q = 0; q < 4; ++q) {
        float scq = scsh[o0 + q], shq = scsh[1024 + o0 + q];
        float mx = -FLT_MAX, sm = 0;
        #pragma unroll
        for (int r = 0; r < 16; ++r) {
            float z = scq * acc[r][q] + shq;
            float l = (z > 0.0f) ? z : SLOPEV * z;
            mx = fmaxf(mx, l); sm += l;
        }
        pmax[(size_t)blk * 1024 + o0 + q] = mx;
        psum[(size_t)blk * 1024 + o0 + q] = sm;
    }
}

__global__ void final_passC_kernel(const float* __restrict__ pmax, const float* __restrict__ psum,
                                   float* __restrict__ out) {
    int e = blockIdx.x * blockDim.x + threadIdx.x;
    if (e >= BB * 1024) return;
    int b = e >> 10, o = e & 1023;
    float mx = -FLT_MAX, sm = 0;
    for (int j = 0; j < NN / 16; ++j) {
        size_t p = ((size_t)(b * (NN / 16) + j)) * 1024 + o;
        mx = fmaxf(mx, pmax[p]);
        sm += psum[p];
    }
    out[b * 2048 + o] = mx;
    out[b * 2048 + 1024 + o] = sm * (1.0f / NN);
}

// ---------------- launch ----------------

extern "C" void kernel_launch(void* const* d_in, const int* in_sizes, int n_in,
                              void* d_out, int out_size, void* d_ws, size_t ws_size,
                              hipStream_t stream) {
    const float* x  = (const float*)d_in[0];
    const float* W1 = (const float*)d_in[1];
    const float* W2 = (const float*)d_in[2];
    const float* W3 = (const float*)d_in[3];
    const float* W4 = (const float*)d_in[4];
    const float* W5 = (const float*)d_in[5];
    const float* g1 = (const float*)d_in[6];  const float* b1 = (const float*)d_in[7];
    const float* g2 = (const float*)d_in[8];  const float* b2 = (const float*)d_in[9];
    const float* g3 = (const float*)d_in[10]; const float* b3 = (const float*)d_in[11];
    const float* g4 = (const float*)d_in[12]; const float* b4 = (const float*)d_in[13];
    const float* g5 = (const float*)d_in[14]; const float* b5 = (const float*)d_in[15];

    float* ws = (float*)d_ws;
    size_t off = 0;
    float* XT0 = ws + off; off += (size_t)BB * NN * 3;
    float* XT1 = ws + off; off += (size_t)BB * NN * 64;
    float* XT2 = ws + off; off += (size_t)BB * NN * 64;
    float* XT3 = ws + off; off += (size_t)BB * NN * 128;
    float* XT4 = ws + off; off += (size_t)BB * NN * 256;
    float* XC1 = ws + off; off += (size_t)BB * NN * 64;
    float* XC2 = ws + off; off += (size_t)BB * NN * 64;
    float* XC3 = ws + off; off += (size_t)BB * NN * 128;
    float* ymax = ws + off; off += (size_t)BB * NN * 256;
    float* ymin = ws + off; off += (size_t)BB * NN * 256;
    int*   idxb = (int*)(ws + off); off += (size_t)BB * NN * KNN;
    float* xxb = ws + off; off += (size_t)BB * NN;
    float* WaT = ws + off; off += 128 * 256;
    float* WdT = ws + off; off += 128 * 256;
    float* W5T = ws + off; off += 512 * 1024;
    float* st1 = ws + off; off += NCOPY * 2 * 64;
    float* st2 = ws + off; off += NCOPY * 2 * 64;
    float* st3 = ws + off; off += NCOPY * 2 * 128;
    float* st4 = ws + off; off += NCOPY * 2 * 256;
    float* st5 = ws + off; off += NCOPY * 2 * 1024;
    float* sc1 = ws + off; off += 2 * 64;
    float* sc2 = ws + off; off += 2 * 64;
    float* sc3 = ws + off; off += 2 * 128;
    float* sc4 = ws + off; off += 2 * 256;
    float* sc5 = ws + off; off += 2 * 1024;
    float* pmax = ymax;   // reuse (edge buffers dead by final pass B)
    float* psum = ymin;

    // zero all BN-stat accumulators (ws is poisoned 0xAA before every call)
    hipMemsetAsync(st1, 0, (size_t)NCOPY * 2 * (64 + 64 + 128 + 256 + 1024) * sizeof(float), stream);

    transpose0_kernel<<<(BB * NN * 3 + 255) / 256, 256, 0, stream>>>(x, XT0);

    // layer 1: C=3 -> O=64   (x itself is the channel-major XC0)
    wprep_kernel<<<(3 * 64 + 255) / 256, 256, 0, stream>>>(W1, WaT, WdT, 3, 64);
    xx_kernel<3><<<BB * NN / 256, 256, 0, stream>>>(XT0, xxb);
    knn3_kernel<3><<<BB * NN / 8, 256, 0, stream>>>(x, XT0, xxb, idxb);
    edge_passA_kernel<3, 64><<<BB * NN, 256, 0, stream>>>(XT0, idxb, WaT, WdT, ymax, ymin, st1);
    finalize_stats_kernel<<<1, 64, 0, stream>>>(st1, g1, b1, sc1, 64, 1.0f / ((float)BB * NN * KNN));
    edge_passB_kernel<<<BB * NN * 64 / 256, 256, 0, stream>>>(ymax, ymin, sc1, XT1, XC1, 64, BB * NN * 64);

    // layer 2: C=64 -> O=64
    wprep_kernel<<<(64 * 64 + 255) / 256, 256, 0, stream>>>(W2, WaT, WdT, 64, 64);
    xx_kernel<64><<<BB * NN / 256, 256, 0, stream>>>(XT1, xxb);
    knn3_kernel<64><<<BB * NN / 8, 256, 0, stream>>>(XC1, XT1, xxb, idxb);
    edge_passA_kernel<64, 64><<<BB * NN, 256, 0, stream>>>(XT1, idxb, WaT, WdT, ymax, ymin, st2);
    finalize_stats_kernel<<<1, 64, 0, stream>>>(st2, g2, b2, sc2, 64, 1.0f / ((float)BB * NN * KNN));
    edge_passB_kernel<<<BB * NN * 64 / 256, 256, 0, stream>>>(ymax, ymin, sc2, XT2, XC2, 64, BB * NN * 64);

    // layer 3: C=64 -> O=128
    wprep_kernel<<<(64 * 128 + 255) / 256, 256, 0, stream>>>(W3, WaT, WdT, 64, 128);
    xx_kernel<64><<<BB * NN / 256, 256, 0, stream>>>(XT2, xxb);
    knn3_kernel<64><<<BB * NN / 8, 256, 0, stream>>>(XC2, XT2, xxb, idxb);
    edge_passA_kernel<64, 128><<<BB * NN, 256, 0, stream>>>(XT2, idxb, WaT, WdT, ymax, ymin, st3);
    finalize_stats_kernel<<<1, 128, 0, stream>>>(st3, g3, b3, sc3, 128, 1.0f / ((float)BB * NN * KNN));
    edge_passB_kernel<<<BB * NN * 128 / 256, 256, 0, stream>>>(ymax, ymin, sc3, XT3, XC3, 128, BB * NN * 128);

    // layer 4: C=128 -> O=256
    wprep_kernel<<<(128 * 256 + 255) / 256, 256, 0, stream>>>(W4, WaT, WdT, 128, 256);
    xx_kernel<128><<<BB * NN / 256, 256, 0, stream>>>(XT3, xxb);
    knn3_kernel<128><<<BB * NN / 8, 256, 0, stream>>>(XC3, XT3, xxb, idxb);
    edge_passA_kernel<128, 256><<<BB * NN, 256, 0, stream>>>(XT3, idxb, WaT, WdT, ymax, ymin, st4);
    finalize_stats_kernel<<<1, 256, 0, stream>>>(st4, g4, b4, sc4, 256, 1.0f / ((float)BB * NN * KNN));
    edge_passB_kernel<<<BB * NN * 256 / 256, 256, 0, stream>>>(ymax, ymin, sc4, XT4, nullptr, 256, BB * NN * 256);

    // final: 512 -> 1024, BN over (B,N), leaky, max+mean over N
    w5prep_kernel<<<512 * 1024 / 256, 256, 0, stream>>>(W5, W5T);
    final_passA_kernel<<<BB * NN / 16, 256, 0, stream>>>(XT1, XT2, XT3, XT4, W5T, st5);
    finalize_stats_kernel<<<4, 256, 0, stream>>>(st5, g5, b5, sc5, 1024, 1.0f / ((float)BB * NN));
    final_passB_kernel<<<BB * NN / 16, 256, 0, stream>>>(XT1, XT2, XT3, XT4, W5T, sc5, pmax, psum);
    final_passC_kernel<<<(BB * 1024 + 255) / 256, 256, 0, stream>>>(pmax, psum, (float*)d_out);

    (void)in_sizes; (void)n_in; (void)out_size; (void)ws_size;
}

// Round 5
// 2002.561 us; speedup vs baseline: 1.9947x; 1.2493x over previous
//
#include <hip/hip_runtime.h>
#include <cfloat>

#define BB 8
#define NN 2048
#define KNN 20
#define NCOPY 64
#define EPSV 1e-5f
#define SLOPEV 0.2f

typedef short bf16x8 __attribute__((ext_vector_type(8)));   // 8 bf16 (4 VGPRs)
typedef float f32x4 __attribute__((ext_vector_type(4)));

__device__ __forceinline__ unsigned short f2b(float f) {
    unsigned u = __builtin_bit_cast(unsigned, f);
    unsigned r = (u + 0x7FFFu + ((u >> 16) & 1u)) >> 16;   // RNE
    return (unsigned short)r;
}
__device__ __forceinline__ short4 f2b4(float4 v) {
    short4 r;
    r.x = (short)f2b(v.x); r.y = (short)f2b(v.y);
    r.z = (short)f2b(v.z); r.w = (short)f2b(v.w);
    return r;
}

// ---------------- small prep kernels ----------------

__global__ void transpose0_kernel(const float* __restrict__ x, float* __restrict__ XT0) {
    int e = blockIdx.x * blockDim.x + threadIdx.x;
    if (e >= BB * NN * 3) return;
    int b = e / (NN * 3); int r = e - b * NN * 3; int n = r / 3; int c = r - n * 3;
    XT0[e] = x[((size_t)b * 3 + c) * NN + n];
}

__global__ void wprep_kernel(const float* __restrict__ W, float* __restrict__ WaT,
                             float* __restrict__ WdT, int C, int O) {
    int e = blockIdx.x * blockDim.x + threadIdx.x;
    if (e >= C * O) return;
    int c = e / O, o = e - c * O;
    float a = W[o * 2 * C + c];
    WaT[e] = a;
    WdT[e] = W[o * 2 * C + C + c] - a;
}

// W4 [256][256] -> Wa bf16 [o=256][c=128], Wd bf16 [o=256][c=128]
__global__ void wprep4b_kernel(const float* __restrict__ W, short* __restrict__ Wab,
                               short* __restrict__ Wdb) {
    int e = blockIdx.x * 256 + threadIdx.x;   // 32768 exact
    int o = e >> 7, c = e & 127;
    float a = W[o * 256 + c];
    Wab[e] = (short)f2b(a);
    Wdb[e] = (short)f2b(W[o * 256 + 128 + c] - a);
}

__global__ void w5b_kernel(const float* __restrict__ W5, short* __restrict__ W5b) {
    int e = blockIdx.x * 256 + threadIdx.x;   // 1024*512 exact, same [o][c] layout
    W5b[e] = (short)f2b(W5[e]);
}

// ---------------- per-point squared norm (matches dot-product partial order) ----

template <int C>
__global__ void xx_kernel(const float* __restrict__ XT, float* __restrict__ xx) {
    int e = blockIdx.x * blockDim.x + threadIdx.x;
    if (e >= BB * NN) return;
    const float* p = &XT[(size_t)e * C];
    float s;
    if constexpr (C % 4 == 0) {
        float s0 = 0, s1 = 0, s2 = 0, s3 = 0;
        for (int c = 0; c < C; c += 4) {
            float4 v = *(const float4*)(p + c);
            s0 += v.x * v.x; s1 += v.y * v.y; s2 += v.z * v.z; s3 += v.w * v.w;
        }
        s = (s0 + s1) + (s2 + s3);
    } else {
        s = p[0] * p[0];
        for (int c = 1; c < C; ++c) s += p[c] * p[c];
    }
    xx[e] = s;
}

// ---------------- KNN v3 (unchanged from R4: correct, 0.03 absmax) ----------------

#define UPD(val, mm) do { \
    float _v = (val); int _m = (mm); \
    bool _b1 = (_v > v1) || (_v == v1 && _m < i1); \
    bool _b2 = (_v > v2) || (_v == v2 && _m < i2); \
    if (_b1) { v2 = v1; i2 = i1; v1 = _v; i1 = _m; } \
    else if (_b2) { v2 = _v; i2 = _m; } \
} while (0)

template <int C>
__global__ __launch_bounds__(256) void knn3_kernel(
    const float* __restrict__ XC,   // [B][C][N] channel-major
    const float* __restrict__ XT,   // [B][N][C] point-major (centers)
    const float* __restrict__ xx,   // [B][N]
    int* __restrict__ idxb) {
    __shared__ float pds[8][NN];    // exactly 64 KB
    int blk = blockIdx.x;
    int b = blk >> 8;               // 256 blocks per batch (N/8)
    int n0 = (blk & 255) * 8;
    int tid = threadIdx.x;
    int w = tid >> 6, lane = tid & 63;
    const size_t baseN = (size_t)b * NN;
    const float* xt0 = XT + (baseN + n0) * C;

    float xr[8];
    #pragma unroll
    for (int r = 0; r < 8; ++r) xr[r] = xx[baseN + n0 + r];

    #pragma unroll
    for (int h = 0; h < 2; ++h) {
        int m0 = w * 512 + h * 256 + 4 * lane;
        const float* xcb = XC + (size_t)b * C * NN + m0;
        float4 xxm = *(const float4*)&xx[baseN + m0];
        if constexpr (C % 4 == 0) {
            float4 P0[8], P1[8], P2[8], P3[8];
            #pragma unroll
            for (int r = 0; r < 8; ++r) {
                P0[r] = make_float4(0.f, 0.f, 0.f, 0.f); P1[r] = P0[r];
                P2[r] = P0[r]; P3[r] = P0[r];
            }
            for (int cq = 0; cq < C / 4; ++cq) {
                float4 v0 = *(const float4*)(xcb + (size_t)(4 * cq + 0) * NN);
                float4 v1 = *(const float4*)(xcb + (size_t)(4 * cq + 1) * NN);
                float4 v2 = *(const float4*)(xcb + (size_t)(4 * cq + 2) * NN);
                float4 v3 = *(const float4*)(xcb + (size_t)(4 * cq + 3) * NN);
                #pragma unroll
                for (int r = 0; r < 8; ++r) {
                    float4 s = *(const float4*)(xt0 + r * C + 4 * cq);
                    P0[r].x += v0.x * s.x; P0[r].y += v0.y * s.x; P0[r].z += v0.z * s.x; P0[r].w += v0.w * s.x;
                    P1[r].x += v1.x * s.y; P1[r].y += v1.y * s.y; P1[r].z += v1.z * s.y; P1[r].w += v1.w * s.y;
                    P2[r].x += v2.x * s.z; P2[r].y += v2.y * s.z; P2[r].z += v2.z * s.z; P2[r].w += v2.w * s.z;
                    P3[r].x += v3.x * s.w; P3[r].y += v3.y * s.w; P3[r].z += v3.z * s.w; P3[r].w += v3.w * s.w;
                }
            }
            #pragma unroll
            for (int r = 0; r < 8; ++r) {
                float4 inn, pd;
                inn.x = (P0[r].x + P1[r].x) + (P2[r].x + P3[r].x);
                inn.y = (P0[r].y + P1[r].y) + (P2[r].y + P3[r].y);
                inn.z = (P0[r].z + P1[r].z) + (P2[r].z + P3[r].z);
                inn.w = (P0[r].w + P1[r].w) + (P2[r].w + P3[r].w);
                pd.x = (2.0f * inn.x - xr[r]) - xxm.x;
                pd.y = (2.0f * inn.y - xr[r]) - xxm.y;
                pd.z = (2.0f * inn.z - xr[r]) - xxm.z;
                pd.w = (2.0f * inn.w - xr[r]) - xxm.w;
                *(float4*)&pds[r][m0] = pd;
            }
        } else {
            float4 P[8];
            #pragma unroll
            for (int r = 0; r < 8; ++r) P[r] = make_float4(0.f, 0.f, 0.f, 0.f);
            for (int c = 0; c < C; ++c) {
                float4 v = *(const float4*)(xcb + (size_t)c * NN);
                #pragma unroll
                for (int r = 0; r < 8; ++r) {
                    float s = xt0[r * C + c];
                    P[r].x += v.x * s; P[r].y += v.y * s; P[r].z += v.z * s; P[r].w += v.w * s;
                }
            }
            #pragma unroll
            for (int r = 0; r < 8; ++r) {
                float4 pd;
                pd.x = (2.0f * P[r].x - xr[r]) - xxm.x;
                pd.y = (2.0f * P[r].y - xr[r]) - xxm.y;
                pd.z = (2.0f * P[r].z - xr[r]) - xxm.z;
                pd.w = (2.0f * P[r].w - xr[r]) - xxm.w;
                *(float4*)&pds[r][m0] = pd;
            }
        }
    }
    __syncthreads();

    for (int rr = 0; rr < 2; ++rr) {
        int r = 2 * w + rr;
        float v1 = -FLT_MAX, v2 = -FLT_MAX;
        int i1 = 0x7FFFFFFF, i2 = 0x7FFFFFFF;
        #pragma unroll
        for (int j = 0; j < 8; ++j) {
            int m0 = 4 * lane + 256 * j;
            float4 pv = *(const float4*)&pds[r][m0];
            UPD(pv.x, m0); UPD(pv.y, m0 + 1); UPD(pv.z, m0 + 2); UPD(pv.w, m0 + 3);
        }
        int* outp = idxb + (baseN + n0 + r) * KNN;
        bool needscan = false;
        for (int it = 0; it < KNN; ++it) {
            float bv = v1; int bi = i1;
            #pragma unroll
            for (int off = 1; off < 64; off <<= 1) {
                float ov = __shfl_xor(bv, off);
                int oi = __shfl_xor(bi, off);
                if (ov > bv || (ov == bv && oi < bi)) { bv = ov; bi = oi; }
            }
            if (lane == 0) outp[it] = bi;
            if (i1 == bi) {
                pds[r][bi] = -FLT_MAX;
                if (needscan) {
                    v1 = -FLT_MAX; v2 = -FLT_MAX; i1 = 0x7FFFFFFF; i2 = 0x7FFFFFFF;
                    #pragma unroll
                    for (int j = 0; j < 8; ++j) {
                        int m0 = 4 * lane + 256 * j;
                        float4 pv = *(const float4*)&pds[r][m0];
                        UPD(pv.x, m0); UPD(pv.y, m0 + 1); UPD(pv.z, m0 + 2); UPD(pv.w, m0 + 3);
                    }
                    needscan = false;
                } else {
                    v1 = v2; i1 = i2; needscan = true;
                }
            }
        }
    }
}
#undef UPD

// ---------------- EdgeConv pass A (fp32, layers 1-3 only: feeds KNN, must stay exact) ----

template <int C, int O>
__global__ __launch_bounds__(256) void edge_passA_kernel(
    const float* __restrict__ XT, const int* __restrict__ idxb,
    const float* __restrict__ WaT, const float* __restrict__ WdT,
    float* __restrict__ ymaxb, float* __restrict__ yminb, float* __restrict__ stats) {
    constexpr int OT = O / 4;
    constexpr int G = 256 / OT;
    constexpr int KP = (KNN + G - 1) / G;
    constexpr int CP = (C % 4 == 0) ? (C + 4) : C;
    __shared__ alignas(16) float ctr[C];
    __shared__ alignas(16) float nbr[KNN][CP];
    __shared__ alignas(16) float t2[O];
    __shared__ int sidx[KNN];
    __shared__ alignas(16) float red[4][1024];
    int blk = blockIdx.x;
    int b = blk >> 11;            // N = 2048
    int tid = threadIdx.x;
    if (tid < KNN) sidx[tid] = idxb[(size_t)blk * KNN + tid];
    for (int e = tid; e < C; e += 256) ctr[e] = XT[(size_t)blk * C + e];
    __syncthreads();
    if constexpr (C % 4 == 0) {
        for (int e = tid; e < KNN * (C / 4); e += 256) {
            int k = e / (C / 4), q = e - k * (C / 4);
            *(float4*)&nbr[k][q * 4] =
                *(const float4*)&XT[((size_t)b * NN + sidx[k]) * C + q * 4];
        }
    } else {
        for (int e = tid; e < KNN * C; e += 256) {
            int k = e / C, c = e - k * C;
            nbr[k][c] = XT[((size_t)b * NN + sidx[k]) * C + c];
        }
    }
    if (tid < O) {
        float s = 0;
        for (int c = 0; c < C; ++c) s += WdT[c * O + tid] * ctr[c];
        t2[tid] = s;
    }
    __syncthreads();
    int og = tid % OT, kg = tid / OT;
    int o0 = og * 4;
    float acc[KP][4];
    #pragma unroll
    for (int j = 0; j < KP; ++j) { acc[j][0] = 0; acc[j][1] = 0; acc[j][2] = 0; acc[j][3] = 0; }
    if constexpr (C % 4 == 0) {
        for (int c = 0; c < C; c += 4) {
            float4 w0 = *(const float4*)&WaT[(c + 0) * O + o0];
            float4 w1 = *(const float4*)&WaT[(c + 1) * O + o0];
            float4 w2 = *(const float4*)&WaT[(c + 2) * O + o0];
            float4 w3 = *(const float4*)&WaT[(c + 3) * O + o0];
            #pragma unroll
            for (int j = 0; j < KP; ++j) {
                int k = kg + j * G;
                if (k < KNN) {
                    float4 nv = *(const float4*)&nbr[k][c];
                    acc[j][0] += nv.x * w0.x + nv.y * w1.x + nv.z * w2.x + nv.w * w3.x;
                    acc[j][1] += nv.x * w0.y + nv.y * w1.y + nv.z * w2.y + nv.w * w3.y;
                    acc[j][2] += nv.x * w0.z + nv.y * w1.z + nv.z * w2.z + nv.w * w3.z;
                    acc[j][3] += nv.x * w0.w + nv.y * w1.w + nv.z * w2.w + nv.w * w3.w;
                }
            }
        }
    } else {
        for (int c = 0; c < C; ++c) {
            float4 w = *(const float4*)&WaT[c * O + o0];
            #pragma unroll
            for (int j = 0; j < KP; ++j) {
                int k = kg + j * G;
                if (k < KNN) {
                    float nv = nbr[k][c];
                    acc[j][0] += nv * w.x; acc[j][1] += nv * w.y;
                    acc[j][2] += nv * w.z; acc[j][3] += nv * w.w;
                }
            }
        }
    }
    float t2a[4];
    *(float4*)t2a = *(const float4*)&t2[o0];
    float vmax[4], vmin[4], vsum[4], vsq[4];
    #pragma unroll
    for (int q = 0; q < 4; ++q) { vmax[q] = -FLT_MAX; vmin[q] = FLT_MAX; vsum[q] = 0; vsq[q] = 0; }
    #pragma unroll
    for (int j = 0; j < KP; ++j) {
        int k = kg + j * G;
        if (k < KNN) {
            #pragma unroll
            for (int q = 0; q < 4; ++q) {
                float y = acc[j][q] + t2a[q];
                vmax[q] = fmaxf(vmax[q], y); vmin[q] = fminf(vmin[q], y);
                vsum[q] += y; vsq[q] += y * y;
            }
        }
    }
    *(float4*)&red[0][kg * O + o0] = make_float4(vmax[0], vmax[1], vmax[2], vmax[3]);
    *(float4*)&red[1][kg * O + o0] = make_float4(vmin[0], vmin[1], vmin[2], vmin[3]);
    *(float4*)&red[2][kg * O + o0] = make_float4(vsum[0], vsum[1], vsum[2], vsum[3]);
    *(float4*)&red[3][kg * O + o0] = make_float4(vsq[0], vsq[1], vsq[2], vsq[3]);
    __syncthreads();
    if (tid < O) {
        float m1 = -FLT_MAX, m2 = FLT_MAX, s1 = 0, s2 = 0;
        #pragma unroll 4
        for (int g = 0; g < G; ++g) {
            m1 = fmaxf(m1, red[0][g * O + tid]);
            m2 = fminf(m2, red[1][g * O + tid]);
            s1 += red[2][g * O + tid];
            s2 += red[3][g * O + tid];
        }
        ymaxb[(size_t)blk * O + tid] = m1;
        yminb[(size_t)blk * O + tid] = m2;
        float* st = &stats[(size_t)(blk & (NCOPY - 1)) * (2 * O)];
        atomicAdd(&st[tid], s1);
        atomicAdd(&st[O + tid], s2);
    }
}

// ---------------- T2 = XT3 . Wd (bf16 MFMA), all points ----------------
// M=16 points/block, N=256, K=128. D layout: col=lane&15, row=quad*4+reg.

__global__ __launch_bounds__(256) void t2_mfma_kernel(
    const float* __restrict__ XT3, const short* __restrict__ Wdb, float* __restrict__ T2) {
    __shared__ alignas(16) short A[16][136];
    int blk = blockIdx.x;           // BB*NN/16 = 1024
    int tid = threadIdx.x, w = tid >> 6, lane = tid & 63;
    int n0g = blk * 16;
    for (int ch = tid; ch < 512; ch += 256) {
        int r = ch >> 5, c4 = (ch & 31) << 2;
        float4 v = *(const float4*)&XT3[((size_t)n0g + r) * 128 + c4];
        *(short4*)&A[r][c4] = f2b4(v);
    }
    __syncthreads();
    int arow = lane & 15, aq = lane >> 4;
    bf16x8 af[4];
    #pragma unroll
    for (int ks = 0; ks < 4; ++ks)
        af[ks] = *(const bf16x8*)&A[arow][ks * 32 + aq * 8];
    for (int t = 0; t < 4; ++t) {
        int nt = w * 4 + t;
        f32x4 acc = {0.f, 0.f, 0.f, 0.f};
        const short* bp = Wdb + (size_t)(nt * 16 + arow) * 128 + aq * 8;
        #pragma unroll
        for (int ks = 0; ks < 4; ++ks)
            acc = __builtin_amdgcn_mfma_f32_16x16x32_bf16(af[ks], *(const bf16x8*)(bp + ks * 32), acc, 0, 0, 0);
        #pragma unroll
        for (int r = 0; r < 4; ++r)
            T2[((size_t)n0g + aq * 4 + r) * 256 + nt * 16 + arow] = acc[r];
    }
}

// ---------------- EdgeConv layer 4 (bf16 MFMA) ----------------
// Block = 4 waves = 4 points. Per point: A = 20 nbr rows (pad 32, zero) x K=128
// bf16 in LDS; y = A.Wa^T + t2 via 2 m-tiles x 16 n-tiles x 4 k-steps MFMA.
// Epilogue: max/min/sum/sumsq over k (rows) via reg + cross-quad shuffles.

__global__ __launch_bounds__(256) void edge4_mfma_kernel(
    const float* __restrict__ XT, const int* __restrict__ idxb,
    const short* __restrict__ Wab, const float* __restrict__ T2,
    float* __restrict__ ymaxb, float* __restrict__ yminb, float* __restrict__ stats) {
    __shared__ alignas(16) short A[4][32][136];
    int blk = blockIdx.x;           // BB*NN/4 = 4096
    int tid = threadIdx.x, w = tid >> 6, lane = tid & 63;
    int p = blk * 4 + w;            // global point id
    int b = p >> 11;
    size_t baseC = (size_t)b * NN;
    const int* idxp = idxb + (size_t)p * KNN;
    for (int ch = lane; ch < 20 * 32; ch += 64) {
        int k = ch >> 5, c4 = (ch & 31) << 2;
        int idx = idxp[k];
        float4 v = *(const float4*)&XT[(baseC + idx) * 128 + c4];
        *(short4*)&A[w][k][c4] = f2b4(v);
    }
    for (int ch = lane; ch < 12 * 34; ch += 64) {
        int k = 20 + ch / 34, c4 = (ch % 34) << 2;
        *(short4*)&A[w][k][c4] = make_short4(0, 0, 0, 0);
    }
    __syncthreads();
    int arow = lane & 15, aq = lane >> 4;
    bf16x8 af0[4], af1[4];
    #pragma unroll
    for (int ks = 0; ks < 4; ++ks) {
        af0[ks] = *(const bf16x8*)&A[w][arow][ks * 32 + aq * 8];
        af1[ks] = *(const bf16x8*)&A[w][16 + arow][ks * 32 + aq * 8];
    }
    const float* t2p = T2 + (size_t)p * 256;
    float* st = stats + (size_t)(p & (NCOPY - 1)) * 512;
    for (int nt = 0; nt < 16; ++nt) {
        f32x4 acc0 = {0.f, 0.f, 0.f, 0.f}, acc1 = {0.f, 0.f, 0.f, 0.f};
        const short* bp = Wab + (size_t)(nt * 16 + arow) * 128 + aq * 8;
        #pragma unroll
        for (int ks = 0; ks < 4; ++ks) {
            bf16x8 bf = *(const bf16x8*)(bp + ks * 32);
            acc0 = __builtin_amdgcn_mfma_f32_16x16x32_bf16(af0[ks], bf, acc0, 0, 0, 0);
            acc1 = __builtin_amdgcn_mfma_f32_16x16x32_bf16(af1[ks], bf, acc1, 0, 0, 0);
        }
        float t2v = t2p[nt * 16 + arow];
        float lmax = -FLT_MAX, lmin = FLT_MAX, ls = 0.f, lsq = 0.f;
        #pragma unroll
        for (int r = 0; r < 4; ++r) {   // rows aq*4+r in 0..15, all valid k
            float y = acc0[r] + t2v;
            lmax = fmaxf(lmax, y); lmin = fminf(lmin, y); ls += y; lsq += y * y;
        }
        if (aq == 0) {                  // acc1 rows 16..19 valid only in quad 0
            #pragma unroll
            for (int r = 0; r < 4; ++r) {
                float y = acc1[r] + t2v;
                lmax = fmaxf(lmax, y); lmin = fminf(lmin, y); ls += y; lsq += y * y;
            }
        }
        #pragma unroll
        for (int off = 16; off < 64; off <<= 1) {
            lmax = fmaxf(lmax, __shfl_xor(lmax, off));
            lmin = fminf(lmin, __shfl_xor(lmin, off));
            ls += __shfl_xor(ls, off);
            lsq += __shfl_xor(lsq, off);
        }
        if (lane < 16) {
            ymaxb[(size_t)p * 256 + nt * 16 + lane] = lmax;
            yminb[(size_t)p * 256 + nt * 16 + lane] = lmin;
            atomicAdd(&st[nt * 16 + lane], ls);
            atomicAdd(&st[256 + nt * 16 + lane], lsq);
        }
    }
}

// ---------------- BN finalize + edge pass B ----------------

__global__ void finalize_stats_kernel(const float* __restrict__ stats, const float* __restrict__ gg,
                                      const float* __restrict__ bb, float* __restrict__ scsh,
                                      int O, float invM) {
    int o = blockIdx.x * blockDim.x + threadIdx.x;
    if (o >= O) return;
    float s1 = 0, s2 = 0;
    for (int cp = 0; cp < NCOPY; ++cp) {
        s1 += stats[(size_t)cp * 2 * O + o];
        s2 += stats[(size_t)cp * 2 * O + O + o];
    }
    float mean = s1 * invM;
    float var = s2 * invM - mean * mean;
    float scale = gg[o] * rsqrtf(var + EPSV);
    float shift = bb[o] - mean * scale;
    scsh[o] = scale; scsh[O + o] = shift;
}

__global__ void edge_passB_kernel(const float* __restrict__ ymaxb, const float* __restrict__ yminb,
                                  const float* __restrict__ scsh, float* __restrict__ XTout,
                                  float* __restrict__ XCout, int O, int total) {
    int e = blockIdx.x * blockDim.x + threadIdx.x;
    if (e >= total) return;
    int o = e & (O - 1);
    float sc = scsh[o], sh = scsh[O + o];
    float y = (sc >= 0.0f) ? ymaxb[e] : yminb[e];   // monotone-affine max/min trick
    float z = sc * y + sh;
    float r = (z > 0.0f) ? z : SLOPEV * z;
    XTout[e] = r;
    if (XCout) {
        int n = (e / O) & (NN - 1);
        int bb_ = e / (O * NN);
        XCout[((size_t)bb_ * O + o) * NN + n] = r;
    }
}

// ---------------- final 512->1024 (bf16 MFMA) ----------------
// Block = 32 points (2 m-tiles), 4 waves x 16 n-tiles, K=512 (16 k-steps).

__device__ __forceinline__ void stage_cat_b(short (*A)[520], const float* __restrict__ XT1,
                                            const float* __restrict__ XT2, const float* __restrict__ XT3,
                                            const float* __restrict__ XT4, int n0g, int tid) {
    for (int ch = tid; ch < 32 * 16; ch += 256) { int r = ch >> 4, c4 = (ch & 15) << 2;
        *(short4*)&A[r][c4]       = f2b4(*(const float4*)&XT1[((size_t)n0g + r) * 64 + c4]); }
    for (int ch = tid; ch < 32 * 16; ch += 256) { int r = ch >> 4, c4 = (ch & 15) << 2;
        *(short4*)&A[r][64 + c4]  = f2b4(*(const float4*)&XT2[((size_t)n0g + r) * 64 + c4]); }
    for (int ch = tid; ch < 32 * 32; ch += 256) { int r = ch >> 5, c4 = (ch & 31) << 2;
        *(short4*)&A[r][128 + c4] = f2b4(*(const float4*)&XT3[((size_t)n0g + r) * 128 + c4]); }
    for (int ch = tid; ch < 32 * 64; ch += 256) { int r = ch >> 6, c4 = (ch & 63) << 2;
        *(short4*)&A[r][256 + c4] = f2b4(*(const float4*)&XT4[((size_t)n0g + r) * 256 + c4]); }
}

__global__ __launch_bounds__(256) void final_mfmaA_kernel(
    const float* __restrict__ XT1, const float* __restrict__ XT2, const float* __restrict__ XT3,
    const float* __restrict__ XT4, const short* __restrict__ W5b, float* __restrict__ stats) {
    __shared__ alignas(16) short A[32][520];
    int blk = blockIdx.x;           // BB*NN/32 = 512
    int tid = threadIdx.x, w = tid >> 6, lane = tid & 63;
    int n0g = blk * 32;
    stage_cat_b(A, XT1, XT2, XT3, XT4, n0g, tid);
    __syncthreads();
    int arow = lane & 15, aq = lane >> 4;
    float* st = stats + (size_t)(blk & (NCOPY - 1)) * 2048;
    for (int mt = 0; mt < 2; ++mt) {
        bf16x8 af[16];
        #pragma unroll
        for (int ks = 0; ks < 16; ++ks)
            af[ks] = *(const bf16x8*)&A[mt * 16 + arow][ks * 32 + aq * 8];
        for (int t = 0; t < 16; ++t) {
            int nt = w * 16 + t;
            f32x4 acc = {0.f, 0.f, 0.f, 0.f};
            const short* bp = W5b + (size_t)(nt * 16 + arow) * 512 + aq * 8;
            #pragma unroll
            for (int ks = 0; ks < 16; ++ks)
                acc = __builtin_amdgcn_mfma_f32_16x16x32_bf16(af[ks], *(const bf16x8*)(bp + ks * 32), acc, 0, 0, 0);
            float ls = (acc[0] + acc[1]) + (acc[2] + acc[3]);
            float lsq = (acc[0] * acc[0] + acc[1] * acc[1]) + (acc[2] * acc[2] + acc[3] * acc[3]);
            ls += __shfl_xor(ls, 16); ls += __shfl_xor(ls, 32);
            lsq += __shfl_xor(lsq, 16); lsq += __shfl_xor(lsq, 32);
            if (lane < 16) {
                atomicAdd(&st[nt * 16 + lane], ls);
                atomicAdd(&st[1024 + nt * 16 + lane], lsq);
            }
        }
    }
}

__global__ __launch_bounds__(256) void final_mfmaB_kernel(
    const float* __restrict__ XT1, const float* __restrict__ XT2, const float* __restrict__ XT3,
    const float* __restrict__ XT4, const short* __restrict__ W5b, const float* __restrict__ scsh,
    float* __restrict__ pmax, float* __restrict__ psum) {
    __shared__ alignas(16) short A[32][520];
    int blk = blockIdx.x;           // 512
    int tid = threadIdx.x, w = tid >> 6, lane = tid & 63;
    int n0g = blk * 32;
    stage_cat_b(A, XT1, XT2, XT3, XT4, n0g, tid);
    __syncthreads();
    int arow = lane & 15, aq = lane >> 4;
    for (int mt = 0; mt < 2; ++mt) {
        bf16x8 af[16];
        #pragma unroll
        for (int ks = 0; ks < 16; ++ks)
            af[ks] = *(const bf16x8*)&A[mt * 16 + arow][ks * 32 + aq * 8];
        for (int t = 0; t < 16; ++t) {
            int nt = w * 16 + t;
            f32x4 acc = {0.f, 0.f, 0.f, 0.f};
            const short* bp = W5b + (size_t)(nt * 16 + arow) * 512 + aq * 8;
            #pragma unroll
            for (int ks = 0; ks < 16; ++ks)
                acc = __builtin_amdgcn_mfma_f32_16x16x32_bf16(af[ks], *(const bf16x8*)(bp + ks * 32), acc, 0, 0, 0);
            int o = nt * 16 + arow;
            float sc = scsh[o], sh = scsh[1024 + o];
            float lmax = -FLT_MAX, lsm = 0.f;
            #pragma unroll
            for (int r = 0; r < 4; ++r) {
                float z = fmaf(sc, acc[r], sh);
                float l = (z > 0.0f) ? z : SLOPEV * z;
                lmax = fmaxf(lmax, l); lsm += l;
            }
            lmax = fmaxf(lmax, __shfl_xor(lmax, 16));
            lmax = fmaxf(lmax, __shfl_xor(lmax, 32));
            lsm += __shfl_xor(lsm, 16); lsm += __shfl_xor(lsm, 32);
            if (lane < 16) {
                pmax[(size_t)(blk * 2 + mt) * 1024 + o] = lmax;
                psum[(size_t)(blk * 2 + mt) * 1024 + o] = lsm;
            }
        }
    }
}

__global__ void final_passC_kernel(const float* __restrict__ pmax, const float* __restrict__ psum,
                                   float* __restrict__ out) {
    int e = blockIdx.x * blockDim.x + threadIdx.x;
    if (e >= BB * 1024) return;
    int b = e >> 10, o = e & 1023;
    float mx = -FLT_MAX, sm = 0;
    for (int j = 0; j < NN / 16; ++j) {
        size_t p = ((size_t)(b * (NN / 16) + j)) * 1024 + o;
        mx = fmaxf(mx, pmax[p]);
        sm += psum[p];
    }
    out[b * 2048 + o] = mx;
    out[b * 2048 + 1024 + o] = sm * (1.0f / NN);
}

// ---------------- launch ----------------

extern "C" void kernel_launch(void* const* d_in, const int* in_sizes, int n_in,
                              void* d_out, int out_size, void* d_ws, size_t ws_size,
                              hipStream_t stream) {
    const float* x  = (const float*)d_in[0];
    const float* W1 = (const float*)d_in[1];
    const float* W2 = (const float*)d_in[2];
    const float* W3 = (const float*)d_in[3];
    const float* W4 = (const float*)d_in[4];
    const float* W5 = (const float*)d_in[5];
    const float* g1 = (const float*)d_in[6];  const float* b1 = (const float*)d_in[7];
    const float* g2 = (const float*)d_in[8];  const float* b2 = (const float*)d_in[9];
    const float* g3 = (const float*)d_in[10]; const float* b3 = (const float*)d_in[11];
    const float* g4 = (const float*)d_in[12]; const float* b4 = (const float*)d_in[13];
    const float* g5 = (const float*)d_in[14]; const float* b5 = (const float*)d_in[15];

    float* ws = (float*)d_ws;
    size_t off = 0;
    float* XT0 = ws + off; off += (size_t)BB * NN * 3;
    float* XT1 = ws + off; off += (size_t)BB * NN * 64;
    float* XT2 = ws + off; off += (size_t)BB * NN * 64;
    float* XT3 = ws + off; off += (size_t)BB * NN * 128;
    float* XT4 = ws + off; off += (size_t)BB * NN * 256;
    float* XC1 = ws + off; off += (size_t)BB * NN * 64;
    float* XC2 = ws + off; off += (size_t)BB * NN * 64;
    float* XC3 = ws + off; off += (size_t)BB * NN * 128;
    float* ymax = ws + off; off += (size_t)BB * NN * 256;
    float* ymin = ws + off; off += (size_t)BB * NN * 256;
    int*   idxb = (int*)(ws + off); off += (size_t)BB * NN * KNN;
    float* xxb = ws + off; off += (size_t)BB * NN;
    float* WaT = ws + off; off += 128 * 256;
    float* WdT = ws + off; off += 128 * 256;
    short* Wa4b = (short*)(ws + off); off += 256 * 128 / 2;
    short* Wd4b = (short*)(ws + off); off += 256 * 128 / 2;
    short* W5b  = (short*)(ws + off); off += 1024 * 512 / 2;
    float* st1 = ws + off; off += NCOPY * 2 * 64;
    float* st2 = ws + off; off += NCOPY * 2 * 64;
    float* st3 = ws + off; off += NCOPY * 2 * 128;
    float* st4 = ws + off; off += NCOPY * 2 * 256;
    float* st5 = ws + off; off += NCOPY * 2 * 1024;
    float* sc1 = ws + off; off += 2 * 64;
    float* sc2 = ws + off; off += 2 * 64;
    float* sc3 = ws + off; off += 2 * 128;
    float* sc4 = ws + off; off += 2 * 256;
    float* sc5 = ws + off; off += 2 * 1024;
    float* T2 = XC1;      // alias: XC1+XC2+XC3 = 8*2048*256 floats, dead after layer-4 knn
    float* pmax = ymax;   // reuse (edge buffers dead by final pass B)
    float* psum = ymin;

    hipMemsetAsync(st1, 0, (size_t)NCOPY * 2 * (64 + 64 + 128 + 256 + 1024) * sizeof(float), stream);

    transpose0_kernel<<<(BB * NN * 3 + 255) / 256, 256, 0, stream>>>(x, XT0);

    // layer 1: C=3 -> O=64   (x itself is the channel-major XC0)
    wprep_kernel<<<(3 * 64 + 255) / 256, 256, 0, stream>>>(W1, WaT, WdT, 3, 64);
    xx_kernel<3><<<BB * NN / 256, 256, 0, stream>>>(XT0, xxb);
    knn3_kernel<3><<<BB * NN / 8, 256, 0, stream>>>(x, XT0, xxb, idxb);
    edge_passA_kernel<3, 64><<<BB * NN, 256, 0, stream>>>(XT0, idxb, WaT, WdT, ymax, ymin, st1);
    finalize_stats_kernel<<<1, 64, 0, stream>>>(st1, g1, b1, sc1, 64, 1.0f / ((float)BB * NN * KNN));
    edge_passB_kernel<<<BB * NN * 64 / 256, 256, 0, stream>>>(ymax, ymin, sc1, XT1, XC1, 64, BB * NN * 64);

    // layer 2: C=64 -> O=64
    wprep_kernel<<<(64 * 64 + 255) / 256, 256, 0, stream>>>(W2, WaT, WdT, 64, 64);
    xx_kernel<64><<<BB * NN / 256, 256, 0, stream>>>(XT1, xxb);
    knn3_kernel<64><<<BB * NN / 8, 256, 0, stream>>>(XC1, XT1, xxb, idxb);
    edge_passA_kernel<64, 64><<<BB * NN, 256, 0, stream>>>(XT1, idxb, WaT, WdT, ymax, ymin, st2);
    finalize_stats_kernel<<<1, 64, 0, stream>>>(st2, g2, b2, sc2, 64, 1.0f / ((float)BB * NN * KNN));
    edge_passB_kernel<<<BB * NN * 64 / 256, 256, 0, stream>>>(ymax, ymin, sc2, XT2, XC2, 64, BB * NN * 64);

    // layer 3: C=64 -> O=128
    wprep_kernel<<<(64 * 128 + 255) / 256, 256, 0, stream>>>(W3, WaT, WdT, 64, 128);
    xx_kernel<64><<<BB * NN / 256, 256, 0, stream>>>(XT2, xxb);
    knn3_kernel<64><<<BB * NN / 8, 256, 0, stream>>>(XC2, XT2, xxb, idxb);
    edge_passA_kernel<64, 128><<<BB * NN, 256, 0, stream>>>(XT2, idxb, WaT, WdT, ymax, ymin, st3);
    finalize_stats_kernel<<<1, 128, 0, stream>>>(st3, g3, b3, sc3, 128, 1.0f / ((float)BB * NN * KNN));
    edge_passB_kernel<<<BB * NN * 128 / 256, 256, 0, stream>>>(ymax, ymin, sc3, XT3, XC3, 128, BB * NN * 128);

    // layer 4: C=128 -> O=256 (bf16 MFMA; output never feeds KNN)
    wprep4b_kernel<<<256 * 128 / 256, 256, 0, stream>>>(W4, Wa4b, Wd4b);
    xx_kernel<128><<<BB * NN / 256, 256, 0, stream>>>(XT3, xxb);
    knn3_kernel<128><<<BB * NN / 8, 256, 0, stream>>>(XC3, XT3, xxb, idxb);
    t2_mfma_kernel<<<BB * NN / 16, 256, 0, stream>>>(XT3, Wd4b, T2);   // overwrites XC1..3
    edge4_mfma_kernel<<<BB * NN / 4, 256, 0, stream>>>(XT3, idxb, Wa4b, T2, ymax, ymin, st4);
    finalize_stats_kernel<<<1, 256, 0, stream>>>(st4, g4, b4, sc4, 256, 1.0f / ((float)BB * NN * KNN));
    edge_passB_kernel<<<BB * NN * 256 / 256, 256, 0, stream>>>(ymax, ymin, sc4, XT4, nullptr, 256, BB * NN * 256);

    // final: 512 -> 1024 (bf16 MFMA), BN over (B,N), leaky, max+mean over N
    w5b_kernel<<<1024 * 512 / 256, 256, 0, stream>>>(W5, W5b);
    final_mfmaA_kernel<<<BB * NN / 32, 256, 0, stream>>>(XT1, XT2, XT3, XT4, W5b, st5);
    finalize_stats_kernel<<<4, 256, 0, stream>>>(st5, g5, b5, sc5, 1024, 1.0f / ((float)BB * NN));
    final_mfmaB_kernel<<<BB * NN / 32, 256, 0, stream>>>(XT1, XT2, XT3, XT4, W5b, sc5, pmax, psum);
    final_passC_kernel<<<(BB * 1024 + 255) / 256, 256, 0, stream>>>(pmax, psum, (float*)d_out);

    (void)in_sizes; (void)n_in; (void)out_size; (void)ws_size;
}

// Round 6
// 1939.093 us; speedup vs baseline: 2.0599x; 1.0327x over previous
//
#include <hip/hip_runtime.h>
#include <cfloat>

#define BB 8
#define NN 2048
#define KNN 20
#define NCOPY 64
#define EPSV 1e-5f
#define SLOPEV 0.2f

typedef short bf16x8 __attribute__((ext_vector_type(8)));   // 8 bf16 (4 VGPRs)
typedef float f32x4 __attribute__((ext_vector_type(4)));

__device__ __forceinline__ unsigned short f2b(float f) {
    unsigned u = __builtin_bit_cast(unsigned, f);
    unsigned r = (u + 0x7FFFu + ((u >> 16) & 1u)) >> 16;   // RNE
    return (unsigned short)r;
}
__device__ __forceinline__ short4 f2b4(float4 v) {
    short4 r;
    r.x = (short)f2b(v.x); r.y = (short)f2b(v.y);
    r.z = (short)f2b(v.z); r.w = (short)f2b(v.w);
    return r;
}

// ---------------- small prep kernels ----------------

__global__ void transpose0_kernel(const float* __restrict__ x, float* __restrict__ XT0) {
    int e = blockIdx.x * blockDim.x + threadIdx.x;
    if (e >= BB * NN * 3) return;
    int b = e / (NN * 3); int r = e - b * NN * 3; int n = r / 3; int c = r - n * 3;
    XT0[e] = x[((size_t)b * 3 + c) * NN + n];
}

__global__ void wprep_kernel(const float* __restrict__ W, float* __restrict__ WaT,
                             float* __restrict__ WdT, int C, int O) {
    int e = blockIdx.x * blockDim.x + threadIdx.x;
    if (e >= C * O) return;
    int c = e / O, o = e - c * O;
    float a = W[o * 2 * C + c];
    WaT[e] = a;
    WdT[e] = W[o * 2 * C + C + c] - a;
}

// W4 [256][256] -> Wa bf16 [o=256][c=128], Wd bf16 [o=256][c=128]
__global__ void wprep4b_kernel(const float* __restrict__ W, short* __restrict__ Wab,
                               short* __restrict__ Wdb) {
    int e = blockIdx.x * 256 + threadIdx.x;   // 32768 exact
    int o = e >> 7, c = e & 127;
    float a = W[o * 256 + c];
    Wab[e] = (short)f2b(a);
    Wdb[e] = (short)f2b(W[o * 256 + 128 + c] - a);
}

__global__ void w5b_kernel(const float* __restrict__ W5, short* __restrict__ W5b) {
    int e = blockIdx.x * 256 + threadIdx.x;   // 1024*512 exact, same [o][c] layout
    W5b[e] = (short)f2b(W5[e]);
}

// ---------------- per-point squared norm (matches dot-product partial order) ----

template <int C>
__global__ void xx_kernel(const float* __restrict__ XT, float* __restrict__ xx) {
    int e = blockIdx.x * blockDim.x + threadIdx.x;
    if (e >= BB * NN) return;
    const float* p = &XT[(size_t)e * C];
    float s;
    if constexpr (C % 4 == 0) {
        float s0 = 0, s1 = 0, s2 = 0, s3 = 0;
        for (int c = 0; c < C; c += 4) {
            float4 v = *(const float4*)(p + c);
            s0 += v.x * v.x; s1 += v.y * v.y; s2 += v.z * v.z; s3 += v.w * v.w;
        }
        s = (s0 + s1) + (s2 + s3);
    } else {
        s = p[0] * p[0];
        for (int c = 1; c < C; ++c) s += p[c] * p[c];
    }
    xx[e] = s;
}

// ---------------- KNN v4: tiled distance GEMM + register selection ----------------
// pd = (2*inner - xx_n) - xx_m, inner accumulated as 4 interleaved c%4-class
// partials combined (P0+P1)+(P2+P3) — bit-identical to the verified knn3
// structure (absmax 0.03 baseline). Selection: pd row in 32 VGPRs/lane +
// 32-bit removal mask; lazy top-2 + 6-level shfl_xor argmax, lowest-index ties.

template <int C>
__global__ __launch_bounds__(256) void knn_dist_kernel(
    const float* __restrict__ XC,   // [B][C][N]
    const float* __restrict__ XT,   // [B][N][C]
    const float* __restrict__ xx,   // [B][N]
    float* __restrict__ pd2,        // [2][N][N]
    int b0) {
    constexpr int BK = 16;
    __shared__ float As[BK][68];    // [c][n] (transposed on store)
    __shared__ alignas(16) float Bs[BK][64];   // [c][m]
    int mt = blockIdx.x, nt = blockIdx.y, bz = blockIdx.z;
    int b = b0 + bz;
    int n0 = nt * 64, m0 = mt * 64;
    int tid = threadIdx.x;
    int tn = tid >> 4, tm = tid & 15;
    float P[4][4][4];
    #pragma unroll
    for (int cl = 0; cl < 4; ++cl)
        #pragma unroll
        for (int i = 0; i < 4; ++i)
            #pragma unroll
            for (int j = 0; j < 4; ++j) P[cl][i][j] = 0.f;

    int arow = tid >> 2, acq = tid & 3;
    int brow = tid >> 4, bmq = tid & 15;
    for (int kb = 0; kb < C / BK; ++kb) {
        if (kb) __syncthreads();
        float4 av = *(const float4*)&XT[((size_t)b * NN + n0 + arow) * C + kb * BK + acq * 4];
        As[acq * 4 + 0][arow] = av.x; As[acq * 4 + 1][arow] = av.y;
        As[acq * 4 + 2][arow] = av.z; As[acq * 4 + 3][arow] = av.w;
        *(float4*)&Bs[brow][bmq * 4] =
            *(const float4*)&XC[((size_t)b * C + kb * BK + brow) * NN + m0 + bmq * 4];
        __syncthreads();
        #pragma unroll
        for (int c = 0; c < BK; ++c) {
            float4 a = *(const float4*)&As[c][tn * 4];
            float4 bv = *(const float4*)&Bs[c][tm * 4];
            constexpr int dummy = 0; (void)dummy;
            int cl = c & 3;
            P[cl][0][0] += a.x * bv.x; P[cl][0][1] += a.x * bv.y; P[cl][0][2] += a.x * bv.z; P[cl][0][3] += a.x * bv.w;
            P[cl][1][0] += a.y * bv.x; P[cl][1][1] += a.y * bv.y; P[cl][1][2] += a.y * bv.z; P[cl][1][3] += a.y * bv.w;
            P[cl][2][0] += a.z * bv.x; P[cl][2][1] += a.z * bv.y; P[cl][2][2] += a.z * bv.z; P[cl][2][3] += a.z * bv.w;
            P[cl][3][0] += a.w * bv.x; P[cl][3][1] += a.w * bv.y; P[cl][3][2] += a.w * bv.z; P[cl][3][3] += a.w * bv.w;
        }
    }
    float4 xm = *(const float4*)&xx[(size_t)b * NN + m0 + tm * 4];
    #pragma unroll
    for (int i = 0; i < 4; ++i) {
        float xrn = xx[(size_t)b * NN + n0 + tn * 4 + i];
        float4 pd;
        float in0 = (P[0][i][0] + P[1][i][0]) + (P[2][i][0] + P[3][i][0]);
        float in1 = (P[0][i][1] + P[1][i][1]) + (P[2][i][1] + P[3][i][1]);
        float in2 = (P[0][i][2] + P[1][i][2]) + (P[2][i][2] + P[3][i][2]);
        float in3 = (P[0][i][3] + P[1][i][3]) + (P[2][i][3] + P[3][i][3]);
        pd.x = (2.0f * in0 - xrn) - xm.x;
        pd.y = (2.0f * in1 - xrn) - xm.y;
        pd.z = (2.0f * in2 - xrn) - xm.z;
        pd.w = (2.0f * in3 - xrn) - xm.w;
        *(float4*)&pd2[((size_t)bz * NN + n0 + tn * 4 + i) * NN + m0 + tm * 4] = pd;
    }
}

#define UPD(val, mm) do { \
    float _v = (val); int _m = (mm); \
    bool _b1 = (_v > v1) || (_v == v1 && _m < i1); \
    bool _b2 = (_v > v2) || (_v == v2 && _m < i2); \
    if (_b1) { v2 = v1; i2 = i1; v1 = _v; i1 = _m; } \
    else if (_b2) { v2 = _v; i2 = _m; } \
} while (0)

__device__ __forceinline__ void sel20_reg(float4* pv, int lane, int* outp) {
    unsigned rm = 0;
    float v1 = -FLT_MAX, v2 = -FLT_MAX;
    int i1 = 0x7FFFFFFF, i2 = 0x7FFFFFFF;
    #pragma unroll
    for (int j = 0; j < 8; ++j) {
        int m0 = 4 * lane + 256 * j;
        UPD(pv[j].x, m0); UPD(pv[j].y, m0 + 1); UPD(pv[j].z, m0 + 2); UPD(pv[j].w, m0 + 3);
    }
    bool needscan = false;
    for (int it = 0; it < KNN; ++it) {
        float bv = v1; int bi = i1;
        #pragma unroll
        for (int off = 1; off < 64; off <<= 1) {
            float ov = __shfl_xor(bv, off);
            int oi = __shfl_xor(bi, off);
            if (ov > bv || (ov == bv && oi < bi)) { bv = ov; bi = oi; }
        }
        if (lane == 0) outp[it] = bi;
        if (i1 == bi) {                 // owner (m-sets disjoint across lanes)
            int loc = bi - 4 * lane;
            rm |= 1u << (4 * (loc >> 8) + (loc & 3));
            if (needscan) {
                v1 = -FLT_MAX; v2 = -FLT_MAX; i1 = 0x7FFFFFFF; i2 = 0x7FFFFFFF;
                #pragma unroll
                for (int j = 0; j < 8; ++j) {
                    int m0 = 4 * lane + 256 * j;
                    if (!(rm & (1u << (4 * j + 0)))) UPD(pv[j].x, m0);
                    if (!(rm & (1u << (4 * j + 1)))) UPD(pv[j].y, m0 + 1);
                    if (!(rm & (1u << (4 * j + 2)))) UPD(pv[j].z, m0 + 2);
                    if (!(rm & (1u << (4 * j + 3)))) UPD(pv[j].w, m0 + 3);
                }
                needscan = false;
            } else {
                v1 = v2; i1 = i2; needscan = true;
            }
        }
    }
}

__global__ __launch_bounds__(256) void knn_sel_kernel(
    const float* __restrict__ pd2, int* __restrict__ idxb, int b0) {
    int tid = threadIdx.x, w = tid >> 6, lane = tid & 63;
    int rg = blockIdx.x * 4 + w;          // 0..4095 (2 batches)
    int bz = rg >> 11, n = rg & (NN - 1);
    const float* row = pd2 + ((size_t)bz * NN + n) * NN;
    float4 pv[8];
    #pragma unroll
    for (int j = 0; j < 8; ++j) pv[j] = *(const float4*)&row[4 * lane + 256 * j];
    int* outp = idxb + ((size_t)(b0 + bz) * NN + n) * KNN;
    sel20_reg(pv, lane, outp);
}

// Layer-1 (C=3) fused: pd computed inline in registers, same selection.
__global__ __launch_bounds__(256) void knn_c3_kernel(
    const float* __restrict__ XC,   // x: [B][3][N]
    const float* __restrict__ XT,   // XT0: [B][N][3]
    const float* __restrict__ xx, int* __restrict__ idxb) {
    int tid = threadIdx.x, w = tid >> 6, lane = tid & 63;
    int rg = blockIdx.x * 4 + w;          // 0..16383
    int b = rg >> 11, n = rg & (NN - 1);
    const float* xt0 = XT + ((size_t)b * NN + n) * 3;
    float s0 = xt0[0], s1 = xt0[1], s2 = xt0[2];
    float xrn = xx[(size_t)b * NN + n];
    float4 pv[8];
    #pragma unroll
    for (int j = 0; j < 8; ++j) {
        int m0 = 4 * lane + 256 * j;
        float4 v0 = *(const float4*)&XC[((size_t)b * 3 + 0) * NN + m0];
        float4 v1 = *(const float4*)&XC[((size_t)b * 3 + 1) * NN + m0];
        float4 v2 = *(const float4*)&XC[((size_t)b * 3 + 2) * NN + m0];
        float4 xm = *(const float4*)&xx[(size_t)b * NN + m0];
        float4 in;
        in.x = v0.x * s0; in.x += v1.x * s1; in.x += v2.x * s2;
        in.y = v0.y * s0; in.y += v1.y * s1; in.y += v2.y * s2;
        in.z = v0.z * s0; in.z += v1.z * s1; in.z += v2.z * s2;
        in.w = v0.w * s0; in.w += v1.w * s1; in.w += v2.w * s2;
        pv[j].x = (2.0f * in.x - xrn) - xm.x;
        pv[j].y = (2.0f * in.y - xrn) - xm.y;
        pv[j].z = (2.0f * in.z - xrn) - xm.z;
        pv[j].w = (2.0f * in.w - xrn) - xm.w;
    }
    int* outp = idxb + ((size_t)b * NN + n) * KNN;
    sel20_reg(pv, lane, outp);
}
#undef UPD

// ---------------- EdgeConv pass A (fp32, layers 1-3 only: feeds KNN, must stay exact) ----

template <int C, int O>
__global__ __launch_bounds__(256) void edge_passA_kernel(
    const float* __restrict__ XT, const int* __restrict__ idxb,
    const float* __restrict__ WaT, const float* __restrict__ WdT,
    float* __restrict__ ymaxb, float* __restrict__ yminb, float* __restrict__ stats) {
    constexpr int OT = O / 4;
    constexpr int G = 256 / OT;
    constexpr int KP = (KNN + G - 1) / G;
    constexpr int CP = (C % 4 == 0) ? (C + 4) : C;
    __shared__ alignas(16) float ctr[C];
    __shared__ alignas(16) float nbr[KNN][CP];
    __shared__ alignas(16) float t2[O];
    __shared__ int sidx[KNN];
    __shared__ alignas(16) float red[4][1024];
    int blk = blockIdx.x;
    int b = blk >> 11;            // N = 2048
    int tid = threadIdx.x;
    if (tid < KNN) sidx[tid] = idxb[(size_t)blk * KNN + tid];
    for (int e = tid; e < C; e += 256) ctr[e] = XT[(size_t)blk * C + e];
    __syncthreads();
    if constexpr (C % 4 == 0) {
        for (int e = tid; e < KNN * (C / 4); e += 256) {
            int k = e / (C / 4), q = e - k * (C / 4);
            *(float4*)&nbr[k][q * 4] =
                *(const float4*)&XT[((size_t)b * NN + sidx[k]) * C + q * 4];
        }
    } else {
        for (int e = tid; e < KNN * C; e += 256) {
            int k = e / C, c = e - k * C;
            nbr[k][c] = XT[((size_t)b * NN + sidx[k]) * C + c];
        }
    }
    if (tid < O) {
        float s = 0;
        for (int c = 0; c < C; ++c) s += WdT[c * O + tid] * ctr[c];
        t2[tid] = s;
    }
    __syncthreads();
    int og = tid % OT, kg = tid / OT;
    int o0 = og * 4;
    float acc[KP][4];
    #pragma unroll
    for (int j = 0; j < KP; ++j) { acc[j][0] = 0; acc[j][1] = 0; acc[j][2] = 0; acc[j][3] = 0; }
    if constexpr (C % 4 == 0) {
        for (int c = 0; c < C; c += 4) {
            float4 w0 = *(const float4*)&WaT[(c + 0) * O + o0];
            float4 w1 = *(const float4*)&WaT[(c + 1) * O + o0];
            float4 w2 = *(const float4*)&WaT[(c + 2) * O + o0];
            float4 w3 = *(const float4*)&WaT[(c + 3) * O + o0];
            #pragma unroll
            for (int j = 0; j < KP; ++j) {
                int k = kg + j * G;
                if (k < KNN) {
                    float4 nv = *(const float4*)&nbr[k][c];
                    acc[j][0] += nv.x * w0.x + nv.y * w1.x + nv.z * w2.x + nv.w * w3.x;
                    acc[j][1] += nv.x * w0.y + nv.y * w1.y + nv.z * w2.y + nv.w * w3.y;
                    acc[j][2] += nv.x * w0.z + nv.y * w1.z + nv.z * w2.z + nv.w * w3.z;
                    acc[j][3] += nv.x * w0.w + nv.y * w1.w + nv.z * w2.w + nv.w * w3.w;
                }
            }
        }
    } else {
        for (int c = 0; c < C; ++c) {
            float4 w = *(const float4*)&WaT[c * O + o0];
            #pragma unroll
            for (int j = 0; j < KP; ++j) {
                int k = kg + j * G;
                if (k < KNN) {
                    float nv = nbr[k][c];
                    acc[j][0] += nv * w.x; acc[j][1] += nv * w.y;
                    acc[j][2] += nv * w.z; acc[j][3] += nv * w.w;
                }
            }
        }
    }
    float t2a[4];
    *(float4*)t2a = *(const float4*)&t2[o0];
    float vmax[4], vmin[4], vsum[4], vsq[4];
    #pragma unroll
    for (int q = 0; q < 4; ++q) { vmax[q] = -FLT_MAX; vmin[q] = FLT_MAX; vsum[q] = 0; vsq[q] = 0; }
    #pragma unroll
    for (int j = 0; j < KP; ++j) {
        int k = kg + j * G;
        if (k < KNN) {
            #pragma unroll
            for (int q = 0; q < 4; ++q) {
                float y = acc[j][q] + t2a[q];
                vmax[q] = fmaxf(vmax[q], y); vmin[q] = fminf(vmin[q], y);
                vsum[q] += y; vsq[q] += y * y;
            }
        }
    }
    *(float4*)&red[0][kg * O + o0] = make_float4(vmax[0], vmax[1], vmax[2], vmax[3]);
    *(float4*)&red[1][kg * O + o0] = make_float4(vmin[0], vmin[1], vmin[2], vmin[3]);
    *(float4*)&red[2][kg * O + o0] = make_float4(vsum[0], vsum[1], vsum[2], vsum[3]);
    *(float4*)&red[3][kg * O + o0] = make_float4(vsq[0], vsq[1], vsq[2], vsq[3]);
    __syncthreads();
    if (tid < O) {
        float m1 = -FLT_MAX, m2 = FLT_MAX, s1 = 0, s2 = 0;
        #pragma unroll 4
        for (int g = 0; g < G; ++g) {
            m1 = fmaxf(m1, red[0][g * O + tid]);
            m2 = fminf(m2, red[1][g * O + tid]);
            s1 += red[2][g * O + tid];
            s2 += red[3][g * O + tid];
        }
        ymaxb[(size_t)blk * O + tid] = m1;
        yminb[(size_t)blk * O + tid] = m2;
        float* st = &stats[(size_t)(blk & (NCOPY - 1)) * (2 * O)];
        atomicAdd(&st[tid], s1);
        atomicAdd(&st[O + tid], s2);
    }
}

// ---------------- T2 = XT3 . Wd (bf16 MFMA), all points ----------------

__global__ __launch_bounds__(256) void t2_mfma_kernel(
    const float* __restrict__ XT3, const short* __restrict__ Wdb, float* __restrict__ T2) {
    __shared__ alignas(16) short A[16][136];
    int blk = blockIdx.x;           // BB*NN/16 = 1024
    int tid = threadIdx.x, w = tid >> 6, lane = tid & 63;
    int n0g = blk * 16;
    for (int ch = tid; ch < 512; ch += 256) {
        int r = ch >> 5, c4 = (ch & 31) << 2;
        float4 v = *(const float4*)&XT3[((size_t)n0g + r) * 128 + c4];
        *(short4*)&A[r][c4] = f2b4(v);
    }
    __syncthreads();
    int arow = lane & 15, aq = lane >> 4;
    bf16x8 af[4];
    #pragma unroll
    for (int ks = 0; ks < 4; ++ks)
        af[ks] = *(const bf16x8*)&A[arow][ks * 32 + aq * 8];
    for (int t = 0; t < 4; ++t) {
        int nt = w * 4 + t;
        f32x4 acc = {0.f, 0.f, 0.f, 0.f};
        const short* bp = Wdb + (size_t)(nt * 16 + arow) * 128 + aq * 8;
        #pragma unroll
        for (int ks = 0; ks < 4; ++ks)
            acc = __builtin_amdgcn_mfma_f32_16x16x32_bf16(af[ks], *(const bf16x8*)(bp + ks * 32), acc, 0, 0, 0);
        #pragma unroll
        for (int r = 0; r < 4; ++r)
            T2[((size_t)n0g + aq * 4 + r) * 256 + nt * 16 + arow] = acc[r];
    }
}

// ---------------- EdgeConv layer 4 (bf16 MFMA) ----------------

__global__ __launch_bounds__(256) void edge4_mfma_kernel(
    const float* __restrict__ XT, const int* __restrict__ idxb,
    const short* __restrict__ Wab, const float* __restrict__ T2,
    float* __restrict__ ymaxb, float* __restrict__ yminb, float* __restrict__ stats) {
    __shared__ alignas(16) short A[4][32][136];
    int blk = blockIdx.x;           // BB*NN/4 = 4096
    int tid = threadIdx.x, w = tid >> 6, lane = tid & 63;
    int p = blk * 4 + w;            // global point id
    int b = p >> 11;
    size_t baseC = (size_t)b * NN;
    const int* idxp = idxb + (size_t)p * KNN;
    for (int ch = lane; ch < 20 * 32; ch += 64) {
        int k = ch >> 5, c4 = (ch & 31) << 2;
        int idx = idxp[k];
        float4 v = *(const float4*)&XT[(baseC + idx) * 128 + c4];
        *(short4*)&A[w][k][c4] = f2b4(v);
    }
    for (int ch = lane; ch < 12 * 34; ch += 64) {
        int k = 20 + ch / 34, c4 = (ch % 34) << 2;
        *(short4*)&A[w][k][c4] = make_short4(0, 0, 0, 0);
    }
    __syncthreads();
    int arow = lane & 15, aq = lane >> 4;
    bf16x8 af0[4], af1[4];
    #pragma unroll
    for (int ks = 0; ks < 4; ++ks) {
        af0[ks] = *(const bf16x8*)&A[w][arow][ks * 32 + aq * 8];
        af1[ks] = *(const bf16x8*)&A[w][16 + arow][ks * 32 + aq * 8];
    }
    const float* t2p = T2 + (size_t)p * 256;
    float* st = stats + (size_t)(p & (NCOPY - 1)) * 512;
    for (int nt = 0; nt < 16; ++nt) {
        f32x4 acc0 = {0.f, 0.f, 0.f, 0.f}, acc1 = {0.f, 0.f, 0.f, 0.f};
        const short* bp = Wab + (size_t)(nt * 16 + arow) * 128 + aq * 8;
        #pragma unroll
        for (int ks = 0; ks < 4; ++ks) {
            bf16x8 bf = *(const bf16x8*)(bp + ks * 32);
            acc0 = __builtin_amdgcn_mfma_f32_16x16x32_bf16(af0[ks], bf, acc0, 0, 0, 0);
            acc1 = __builtin_amdgcn_mfma_f32_16x16x32_bf16(af1[ks], bf, acc1, 0, 0, 0);
        }
        float t2v = t2p[nt * 16 + arow];
        float lmax = -FLT_MAX, lmin = FLT_MAX, ls = 0.f, lsq = 0.f;
        #pragma unroll
        for (int r = 0; r < 4; ++r) {
            float y = acc0[r] + t2v;
            lmax = fmaxf(lmax, y); lmin = fminf(lmin, y); ls += y; lsq += y * y;
        }
        if (aq == 0) {
            #pragma unroll
            for (int r = 0; r < 4; ++r) {
                float y = acc1[r] + t2v;
                lmax = fmaxf(lmax, y); lmin = fminf(lmin, y); ls += y; lsq += y * y;
            }
        }
        #pragma unroll
        for (int off = 16; off < 64; off <<= 1) {
            lmax = fmaxf(lmax, __shfl_xor(lmax, off));
            lmin = fminf(lmin, __shfl_xor(lmin, off));
            ls += __shfl_xor(ls, off);
            lsq += __shfl_xor(lsq, off);
        }
        if (lane < 16) {
            ymaxb[(size_t)p * 256 + nt * 16 + lane] = lmax;
            yminb[(size_t)p * 256 + nt * 16 + lane] = lmin;
            atomicAdd(&st[nt * 16 + lane], ls);
            atomicAdd(&st[256 + nt * 16 + lane], lsq);
        }
    }
}

// ---------------- BN finalize + edge pass B ----------------

__global__ void finalize_stats_kernel(const float* __restrict__ stats, const float* __restrict__ gg,
                                      const float* __restrict__ bb, float* __restrict__ scsh,
                                      int O, float invM) {
    int o = blockIdx.x * blockDim.x + threadIdx.x;
    if (o >= O) return;
    float s1 = 0, s2 = 0;
    for (int cp = 0; cp < NCOPY; ++cp) {
        s1 += stats[(size_t)cp * 2 * O + o];
        s2 += stats[(size_t)cp * 2 * O + O + o];
    }
    float mean = s1 * invM;
    float var = s2 * invM - mean * mean;
    float scale = gg[o] * rsqrtf(var + EPSV);
    float shift = bb[o] - mean * scale;
    scsh[o] = scale; scsh[O + o] = shift;
}

__global__ void edge_passB_kernel(const float* __restrict__ ymaxb, const float* __restrict__ yminb,
                                  const float* __restrict__ scsh, float* __restrict__ XTout,
                                  float* __restrict__ XCout, int O, int total) {
    int e = blockIdx.x * blockDim.x + threadIdx.x;
    if (e >= total) return;
    int o = e & (O - 1);
    float sc = scsh[o], sh = scsh[O + o];
    float y = (sc >= 0.0f) ? ymaxb[e] : yminb[e];   // monotone-affine max/min trick
    float z = sc * y + sh;
    float r = (z > 0.0f) ? z : SLOPEV * z;
    XTout[e] = r;
    if (XCout) {
        int n = (e / O) & (NN - 1);
        int bb_ = e / (O * NN);
        XCout[((size_t)bb_ * O + o) * NN + n] = r;
    }
}

// ---------------- final 512->1024 (bf16 MFMA) ----------------

__device__ __forceinline__ void stage_cat_b(short (*A)[520], const float* __restrict__ XT1,
                                            const float* __restrict__ XT2, const float* __restrict__ XT3,
                                            const float* __restrict__ XT4, int n0g, int tid) {
    for (int ch = tid; ch < 32 * 16; ch += 256) { int r = ch >> 4, c4 = (ch & 15) << 2;
        *(short4*)&A[r][c4]       = f2b4(*(const float4*)&XT1[((size_t)n0g + r) * 64 + c4]); }
    for (int ch = tid; ch < 32 * 16; ch += 256) { int r = ch >> 4, c4 = (ch & 15) << 2;
        *(short4*)&A[r][64 + c4]  = f2b4(*(const float4*)&XT2[((size_t)n0g + r) * 64 + c4]); }
    for (int ch = tid; ch < 32 * 32; ch += 256) { int r = ch >> 5, c4 = (ch & 31) << 2;
        *(short4*)&A[r][128 + c4] = f2b4(*(const float4*)&XT3[((size_t)n0g + r) * 128 + c4]); }
    for (int ch = tid; ch < 32 * 64; ch += 256) { int r = ch >> 6, c4 = (ch & 63) << 2;
        *(short4*)&A[r][256 + c4] = f2b4(*(const float4*)&XT4[((size_t)n0g + r) * 256 + c4]); }
}

__global__ __launch_bounds__(256) void final_mfmaA_kernel(
    const float* __restrict__ XT1, const float* __restrict__ XT2, const float* __restrict__ XT3,
    const float* __restrict__ XT4, const short* __restrict__ W5b, float* __restrict__ stats) {
    __shared__ alignas(16) short A[32][520];
    int blk = blockIdx.x;           // BB*NN/32 = 512
    int tid = threadIdx.x, w = tid >> 6, lane = tid & 63;
    int n0g = blk * 32;
    stage_cat_b(A, XT1, XT2, XT3, XT4, n0g, tid);
    __syncthreads();
    int arow = lane & 15, aq = lane >> 4;
    float* st = stats + (size_t)(blk & (NCOPY - 1)) * 2048;
    for (int mt = 0; mt < 2; ++mt) {
        bf16x8 af[16];
        #pragma unroll
        for (int ks = 0; ks < 16; ++ks)
            af[ks] = *(const bf16x8*)&A[mt * 16 + arow][ks * 32 + aq * 8];
        for (int t = 0; t < 16; ++t) {
            int nt = w * 16 + t;
            f32x4 acc = {0.f, 0.f, 0.f, 0.f};
            const short* bp = W5b + (size_t)(nt * 16 + arow) * 512 + aq * 8;
            #pragma unroll
            for (int ks = 0; ks < 16; ++ks)
                acc = __builtin_amdgcn_mfma_f32_16x16x32_bf16(af[ks], *(const bf16x8*)(bp + ks * 32), acc, 0, 0, 0);
            float ls = (acc[0] + acc[1]) + (acc[2] + acc[3]);
            float lsq = (acc[0] * acc[0] + acc[1] * acc[1]) + (acc[2] * acc[2] + acc[3] * acc[3]);
            ls += __shfl_xor(ls, 16); ls += __shfl_xor(ls, 32);
            lsq += __shfl_xor(lsq, 16); lsq += __shfl_xor(lsq, 32);
            if (lane < 16) {
                atomicAdd(&st[nt * 16 + lane], ls);
                atomicAdd(&st[1024 + nt * 16 + lane], lsq);
            }
        }
    }
}

__global__ __launch_bounds__(256) void final_mfmaB_kernel(
    const float* __restrict__ XT1, const float* __restrict__ XT2, const float* __restrict__ XT3,
    const float* __restrict__ XT4, const short* __restrict__ W5b, const float* __restrict__ scsh,
    float* __restrict__ pmax, float* __restrict__ psum) {
    __shared__ alignas(16) short A[32][520];
    int blk = blockIdx.x;           // 512
    int tid = threadIdx.x, w = tid >> 6, lane = tid & 63;
    int n0g = blk * 32;
    stage_cat_b(A, XT1, XT2, XT3, XT4, n0g, tid);
    __syncthreads();
    int arow = lane & 15, aq = lane >> 4;
    for (int mt = 0; mt < 2; ++mt) {
        bf16x8 af[16];
        #pragma unroll
        for (int ks = 0; ks < 16; ++ks)
            af[ks] = *(const bf16x8*)&A[mt * 16 + arow][ks * 32 + aq * 8];
        for (int t = 0; t < 16; ++t) {
            int nt = w * 16 + t;
            f32x4 acc = {0.f, 0.f, 0.f, 0.f};
            const short* bp = W5b + (size_t)(nt * 16 + arow) * 512 + aq * 8;
            #pragma unroll
            for (int ks = 0; ks < 16; ++ks)
                acc = __builtin_amdgcn_mfma_f32_16x16x32_bf16(af[ks], *(const bf16x8*)(bp + ks * 32), acc, 0, 0, 0);
            int o = nt * 16 + arow;
            float sc = scsh[o], sh = scsh[1024 + o];
            float lmax = -FLT_MAX, lsm = 0.f;
            #pragma unroll
            for (int r = 0; r < 4; ++r) {
                float z = fmaf(sc, acc[r], sh);
                float l = (z > 0.0f) ? z : SLOPEV * z;
                lmax = fmaxf(lmax, l); lsm += l;
            }
            lmax = fmaxf(lmax, __shfl_xor(lmax, 16));
            lmax = fmaxf(lmax, __shfl_xor(lmax, 32));
            lsm += __shfl_xor(lsm, 16); lsm += __shfl_xor(lsm, 32);
            if (lane < 16) {
                pmax[(size_t)(blk * 2 + mt) * 1024 + o] = lmax;
                psum[(size_t)(blk * 2 + mt) * 1024 + o] = lsm;
            }
        }
    }
}

__global__ void final_passC_kernel(const float* __restrict__ pmax, const float* __restrict__ psum,
                                   float* __restrict__ out) {
    int e = blockIdx.x * blockDim.x + threadIdx.x;
    if (e >= BB * 1024) return;
    int b = e >> 10, o = e & 1023;
    float mx = -FLT_MAX, sm = 0;
    for (int j = 0; j < NN / 16; ++j) {
        size_t p = ((size_t)(b * (NN / 16) + j)) * 1024 + o;
        mx = fmaxf(mx, pmax[p]);
        sm += psum[p];
    }
    out[b * 2048 + o] = mx;
    out[b * 2048 + 1024 + o] = sm * (1.0f / NN);
}

// ---------------- launch ----------------

extern "C" void kernel_launch(void* const* d_in, const int* in_sizes, int n_in,
                              void* d_out, int out_size, void* d_ws, size_t ws_size,
                              hipStream_t stream) {
    const float* x  = (const float*)d_in[0];
    const float* W1 = (const float*)d_in[1];
    const float* W2 = (const float*)d_in[2];
    const float* W3 = (const float*)d_in[3];
    const float* W4 = (const float*)d_in[4];
    const float* W5 = (const float*)d_in[5];
    const float* g1 = (const float*)d_in[6];  const float* b1 = (const float*)d_in[7];
    const float* g2 = (const float*)d_in[8];  const float* b2 = (const float*)d_in[9];
    const float* g3 = (const float*)d_in[10]; const float* b3 = (const float*)d_in[11];
    const float* g4 = (const float*)d_in[12]; const float* b4 = (const float*)d_in[13];
    const float* g5 = (const float*)d_in[14]; const float* b5 = (const float*)d_in[15];

    float* ws = (float*)d_ws;
    size_t off = 0;
    float* XT0 = ws + off; off += (size_t)BB * NN * 3;
    float* XT1 = ws + off; off += (size_t)BB * NN * 64;
    float* XT2 = ws + off; off += (size_t)BB * NN * 64;
    float* XT3 = ws + off; off += (size_t)BB * NN * 128;
    float* XT4 = ws + off; off += (size_t)BB * NN * 256;
    float* XC1 = ws + off; off += (size_t)BB * NN * 64;
    float* XC2 = ws + off; off += (size_t)BB * NN * 64;
    float* XC3 = ws + off; off += (size_t)BB * NN * 128;
    float* ymax = ws + off; off += (size_t)BB * NN * 256;
    float* ymin = ws + off; off += (size_t)BB * NN * 256;
    int*   idxb = (int*)(ws + off); off += (size_t)BB * NN * KNN;
    float* xxb = ws + off; off += (size_t)BB * NN;
    float* WaT = ws + off; off += 128 * 256;
    float* WdT = ws + off; off += 128 * 256;
    short* Wa4b = (short*)(ws + off); off += 256 * 128 / 2;
    short* Wd4b = (short*)(ws + off); off += 256 * 128 / 2;
    short* W5b  = (short*)(ws + off); off += 1024 * 512 / 2;
    float* st1 = ws + off; off += NCOPY * 2 * 64;
    float* st2 = ws + off; off += NCOPY * 2 * 64;
    float* st3 = ws + off; off += NCOPY * 2 * 128;
    float* st4 = ws + off; off += NCOPY * 2 * 256;
    float* st5 = ws + off; off += NCOPY * 2 * 1024;
    float* sc1 = ws + off; off += 2 * 64;
    float* sc2 = ws + off; off += 2 * 64;
    float* sc3 = ws + off; off += 2 * 128;
    float* sc4 = ws + off; off += 2 * 256;
    float* sc5 = ws + off; off += 2 * 1024;
    float* T2 = XC1;      // alias: XC1..3 dead after layer-4 knn
    float* pd2 = ymax;    // alias: ymax+ymin = 2 batches of pd (33.5 MB), dead during knn
    float* pmax = ymax;   // reuse (edge buffers dead by final pass B)
    float* psum = ymin;

    hipMemsetAsync(st1, 0, (size_t)NCOPY * 2 * (64 + 64 + 128 + 256 + 1024) * sizeof(float), stream);

    transpose0_kernel<<<(BB * NN * 3 + 255) / 256, 256, 0, stream>>>(x, XT0);

    dim3 dgrid(NN / 64, NN / 64, 2);

    // layer 1: C=3 -> O=64   (x itself is the channel-major XC0)
    wprep_kernel<<<(3 * 64 + 255) / 256, 256, 0, stream>>>(W1, WaT, WdT, 3, 64);
    xx_kernel<3><<<BB * NN / 256, 256, 0, stream>>>(XT0, xxb);
    knn_c3_kernel<<<BB * NN / 4, 256, 0, stream>>>(x, XT0, xxb, idxb);
    edge_passA_kernel<3, 64><<<BB * NN, 256, 0, stream>>>(XT0, idxb, WaT, WdT, ymax, ymin, st1);
    finalize_stats_kernel<<<1, 64, 0, stream>>>(st1, g1, b1, sc1, 64, 1.0f / ((float)BB * NN * KNN));
    edge_passB_kernel<<<BB * NN * 64 / 256, 256, 0, stream>>>(ymax, ymin, sc1, XT1, XC1, 64, BB * NN * 64);

    // layer 2: C=64 -> O=64
    wprep_kernel<<<(64 * 64 + 255) / 256, 256, 0, stream>>>(W2, WaT, WdT, 64, 64);
    xx_kernel<64><<<BB * NN / 256, 256, 0, stream>>>(XT1, xxb);
    for (int p = 0; p < 4; ++p) {
        knn_dist_kernel<64><<<dgrid, 256, 0, stream>>>(XC1, XT1, xxb, pd2, 2 * p);
        knn_sel_kernel<<<2 * NN / 4, 256, 0, stream>>>(pd2, idxb, 2 * p);
    }
    edge_passA_kernel<64, 64><<<BB * NN, 256, 0, stream>>>(XT1, idxb, WaT, WdT, ymax, ymin, st2);
    finalize_stats_kernel<<<1, 64, 0, stream>>>(st2, g2, b2, sc2, 64, 1.0f / ((float)BB * NN * KNN));
    edge_passB_kernel<<<BB * NN * 64 / 256, 256, 0, stream>>>(ymax, ymin, sc2, XT2, XC2, 64, BB * NN * 64);

    // layer 3: C=64 -> O=128
    wprep_kernel<<<(64 * 128 + 255) / 256, 256, 0, stream>>>(W3, WaT, WdT, 64, 128);
    xx_kernel<64><<<BB * NN / 256, 256, 0, stream>>>(XT2, xxb);
    for (int p = 0; p < 4; ++p) {
        knn_dist_kernel<64><<<dgrid, 256, 0, stream>>>(XC2, XT2, xxb, pd2, 2 * p);
        knn_sel_kernel<<<2 * NN / 4, 256, 0, stream>>>(pd2, idxb, 2 * p);
    }
    edge_passA_kernel<64, 128><<<BB * NN, 256, 0, stream>>>(XT2, idxb, WaT, WdT, ymax, ymin, st3);
    finalize_stats_kernel<<<1, 128, 0, stream>>>(st3, g3, b3, sc3, 128, 1.0f / ((float)BB * NN * KNN));
    edge_passB_kernel<<<BB * NN * 128 / 256, 256, 0, stream>>>(ymax, ymin, sc3, XT3, XC3, 128, BB * NN * 128);

    // layer 4: C=128 -> O=256 (bf16 MFMA; output never feeds KNN)
    wprep4b_kernel<<<256 * 128 / 256, 256, 0, stream>>>(W4, Wa4b, Wd4b);
    xx_kernel<128><<<BB * NN / 256, 256, 0, stream>>>(XT3, xxb);
    for (int p = 0; p < 4; ++p) {
        knn_dist_kernel<128><<<dgrid, 256, 0, stream>>>(XC3, XT3, xxb, pd2, 2 * p);
        knn_sel_kernel<<<2 * NN / 4, 256, 0, stream>>>(pd2, idxb, 2 * p);
    }
    t2_mfma_kernel<<<BB * NN / 16, 256, 0, stream>>>(XT3, Wd4b, T2);   // overwrites XC1..3
    edge4_mfma_kernel<<<BB * NN / 4, 256, 0, stream>>>(XT3, idxb, Wa4b, T2, ymax, ymin, st4);
    finalize_stats_kernel<<<1, 256, 0, stream>>>(st4, g4, b4, sc4, 256, 1.0f / ((float)BB * NN * KNN));
    edge_passB_kernel<<<BB * NN * 256 / 256, 256, 0, stream>>>(ymax, ymin, sc4, XT4, nullptr, 256, BB * NN * 256);

    // final: 512 -> 1024 (bf16 MFMA), BN over (B,N), leaky, max+mean over N
    w5b_kernel<<<1024 * 512 / 256, 256, 0, stream>>>(W5, W5b);
    final_mfmaA_kernel<<<BB * NN / 32, 256, 0, stream>>>(XT1, XT2, XT3, XT4, W5b, st5);
    finalize_stats_kernel<<<4, 256, 0, stream>>>(st5, g5, b5, sc5, 1024, 1.0f / ((float)BB * NN));
    final_mfmaB_kernel<<<BB * NN / 32, 256, 0, stream>>>(XT1, XT2, XT3, XT4, W5b, sc5, pmax, psum);
    final_passC_kernel<<<(BB * 1024 + 255) / 256, 256, 0, stream>>>(pmax, psum, (float*)d_out);

    (void)in_sizes; (void)n_in; (void)out_size; (void)ws_size;
}

// Round 7
// 1515.524 us; speedup vs baseline: 2.6357x; 1.2795x over previous
//
#include <hip/hip_runtime.h>
#include <cfloat>

#define BB 8
#define NN 2048
#define KNN 20
#define NCOPY 64
#define EPSV 1e-5f
#define SLOPEV 0.2f

typedef short bf16x8 __attribute__((ext_vector_type(8)));   // 8 bf16 (4 VGPRs)
typedef float f32x4 __attribute__((ext_vector_type(4)));

__device__ __forceinline__ unsigned short f2b(float f) {
    unsigned u = __builtin_bit_cast(unsigned, f);
    unsigned r = (u + 0x7FFFu + ((u >> 16) & 1u)) >> 16;   // RNE
    return (unsigned short)r;
}
__device__ __forceinline__ short4 f2b4(float4 v) {
    short4 r;
    r.x = (short)f2b(v.x); r.y = (short)f2b(v.y);
    r.z = (short)f2b(v.z); r.w = (short)f2b(v.w);
    return r;
}
__device__ __forceinline__ bf16x8 f2b8(float4 a, float4 b) {
    short4 sa = f2b4(a), sb = f2b4(b);
    bf16x8 r;
    r[0] = sa.x; r[1] = sa.y; r[2] = sa.z; r[3] = sa.w;
    r[4] = sb.x; r[5] = sb.y; r[6] = sb.z; r[7] = sb.w;
    return r;
}

// ---------------- small prep kernels ----------------

__global__ void transpose0_kernel(const float* __restrict__ x, float* __restrict__ XT0) {
    int e = blockIdx.x * blockDim.x + threadIdx.x;
    if (e >= BB * NN * 3) return;
    int b = e / (NN * 3); int r = e - b * NN * 3; int n = r / 3; int c = r - n * 3;
    XT0[e] = x[((size_t)b * 3 + c) * NN + n];
}

__global__ void wprep_kernel(const float* __restrict__ W, float* __restrict__ WaT,
                             float* __restrict__ WdT, int C, int O) {
    int e = blockIdx.x * blockDim.x + threadIdx.x;
    if (e >= C * O) return;
    int c = e / O, o = e - c * O;
    float a = W[o * 2 * C + c];
    WaT[e] = a;
    WdT[e] = W[o * 2 * C + C + c] - a;
}

// W4 [256][256] -> Wa bf16 [o=256][c=128], Wd bf16 [o=256][c=128]
__global__ void wprep4b_kernel(const float* __restrict__ W, short* __restrict__ Wab,
                               short* __restrict__ Wdb) {
    int e = blockIdx.x * 256 + threadIdx.x;   // 32768 exact
    int o = e >> 7, c = e & 127;
    float a = W[o * 256 + c];
    Wab[e] = (short)f2b(a);
    Wdb[e] = (short)f2b(W[o * 256 + 128 + c] - a);
}

__global__ void w5b_kernel(const float* __restrict__ W5, short* __restrict__ W5b) {
    int e = blockIdx.x * 256 + threadIdx.x;   // 1024*512 exact, same [o][c] layout
    W5b[e] = (short)f2b(W5[e]);
}

// ---------------- per-point squared norm (matches dot-product partial order) ----

template <int C>
__global__ void xx_kernel(const float* __restrict__ XT, float* __restrict__ xx) {
    int e = blockIdx.x * blockDim.x + threadIdx.x;
    if (e >= BB * NN) return;
    const float* p = &XT[(size_t)e * C];
    float s;
    if constexpr (C % 4 == 0) {
        float s0 = 0, s1 = 0, s2 = 0, s3 = 0;
        for (int c = 0; c < C; c += 4) {
            float4 v = *(const float4*)(p + c);
            s0 += v.x * v.x; s1 += v.y * v.y; s2 += v.z * v.z; s3 += v.w * v.w;
        }
        s = (s0 + s1) + (s2 + s3);
    } else {
        s = p[0] * p[0];
        for (int c = 1; c < C; ++c) s += p[c] * p[c];
    }
    xx[e] = s;
}

// ---------------- KNN: tiled distance GEMM + register selection ----------------
// pd accumulation structure unchanged (verified). Selection v2: per-lane TOP-4
// value/index cache (strict > insert in increasing-m order == lowest-index tie
// within lane), value-only shfl max + index-min reduce (exact lowest-index tie
// across lanes), removal mask + rescan only when a lane's cache empties.

template <int C>
__global__ __launch_bounds__(256) void knn_dist_kernel(
    const float* __restrict__ XC,   // [B][C][N]
    const float* __restrict__ XT,   // [B][N][C]
    const float* __restrict__ xx,   // [B][N]
    float* __restrict__ pd2,        // [2][N][N]
    int b0) {
    constexpr int BK = 16;
    __shared__ float As[BK][68];    // [c][n] (transposed on store)
    __shared__ alignas(16) float Bs[BK][64];   // [c][m]
    int mt = blockIdx.x, nt = blockIdx.y, bz = blockIdx.z;
    int b = b0 + bz;
    int n0 = nt * 64, m0 = mt * 64;
    int tid = threadIdx.x;
    int tn = tid >> 4, tm = tid & 15;
    float P[4][4][4];
    #pragma unroll
    for (int cl = 0; cl < 4; ++cl)
        #pragma unroll
        for (int i = 0; i < 4; ++i)
            #pragma unroll
            for (int j = 0; j < 4; ++j) P[cl][i][j] = 0.f;

    int arow = tid >> 2, acq = tid & 3;
    int brow = tid >> 4, bmq = tid & 15;
    for (int kb = 0; kb < C / BK; ++kb) {
        if (kb) __syncthreads();
        float4 av = *(const float4*)&XT[((size_t)b * NN + n0 + arow) * C + kb * BK + acq * 4];
        As[acq * 4 + 0][arow] = av.x; As[acq * 4 + 1][arow] = av.y;
        As[acq * 4 + 2][arow] = av.z; As[acq * 4 + 3][arow] = av.w;
        *(float4*)&Bs[brow][bmq * 4] =
            *(const float4*)&XC[((size_t)b * C + kb * BK + brow) * NN + m0 + bmq * 4];
        __syncthreads();
        #pragma unroll
        for (int c = 0; c < BK; ++c) {
            float4 a = *(const float4*)&As[c][tn * 4];
            float4 bv = *(const float4*)&Bs[c][tm * 4];
            int cl = c & 3;
            P[cl][0][0] += a.x * bv.x; P[cl][0][1] += a.x * bv.y; P[cl][0][2] += a.x * bv.z; P[cl][0][3] += a.x * bv.w;
            P[cl][1][0] += a.y * bv.x; P[cl][1][1] += a.y * bv.y; P[cl][1][2] += a.y * bv.z; P[cl][1][3] += a.y * bv.w;
            P[cl][2][0] += a.z * bv.x; P[cl][2][1] += a.z * bv.y; P[cl][2][2] += a.z * bv.z; P[cl][2][3] += a.z * bv.w;
            P[cl][3][0] += a.w * bv.x; P[cl][3][1] += a.w * bv.y; P[cl][3][2] += a.w * bv.z; P[cl][3][3] += a.w * bv.w;
        }
    }
    float4 xm = *(const float4*)&xx[(size_t)b * NN + m0 + tm * 4];
    #pragma unroll
    for (int i = 0; i < 4; ++i) {
        float xrn = xx[(size_t)b * NN + n0 + tn * 4 + i];
        float4 pd;
        float in0 = (P[0][i][0] + P[1][i][0]) + (P[2][i][0] + P[3][i][0]);
        float in1 = (P[0][i][1] + P[1][i][1]) + (P[2][i][1] + P[3][i][1]);
        float in2 = (P[0][i][2] + P[1][i][2]) + (P[2][i][2] + P[3][i][2]);
        float in3 = (P[0][i][3] + P[1][i][3]) + (P[2][i][3] + P[3][i][3]);
        pd.x = (2.0f * in0 - xrn) - xm.x;
        pd.y = (2.0f * in1 - xrn) - xm.y;
        pd.z = (2.0f * in2 - xrn) - xm.z;
        pd.w = (2.0f * in3 - xrn) - xm.w;
        *(float4*)&pd2[((size_t)bz * NN + n0 + tn * 4 + i) * NN + m0 + tm * 4] = pd;
    }
}

// strict > keeps earliest-inserted (lowest m) among equal values
#define INS(val, mm) do { \
    float _v = (val); int _m = (mm); \
    bool b1 = _v > v1, b2 = _v > v2, b3 = _v > v3, b4 = _v > v4; \
    i4 = b3 ? i3 : (b4 ? _m : i4);  v4 = b3 ? v3 : (b4 ? _v : v4); \
    i3 = b2 ? i2 : (b3 ? _m : i3);  v3 = b2 ? v2 : (b3 ? _v : v3); \
    i2 = b1 ? i1 : (b2 ? _m : i2);  v2 = b1 ? v1 : (b2 ? _v : v2); \
    i1 = b1 ? _m : i1;              v1 = b1 ? _v : v1; \
} while (0)

__device__ __forceinline__ void sel20_reg(const float4* pv, int lane, int* outp) {
    float v1 = -FLT_MAX, v2 = -FLT_MAX, v3 = -FLT_MAX, v4 = -FLT_MAX;
    int i1 = 0x7FFFFFFF, i2 = 0x7FFFFFFF, i3 = 0x7FFFFFFF, i4 = 0x7FFFFFFF;
    unsigned rm = 0;
    #pragma unroll
    for (int j = 0; j < 8; ++j) {
        int m0 = 4 * lane + 256 * j;
        INS(pv[j].x, m0); INS(pv[j].y, m0 + 1); INS(pv[j].z, m0 + 2); INS(pv[j].w, m0 + 3);
    }
    int depth = 4;
    for (int it = 0; it < KNN; ++it) {
        float bv = v1;
        #pragma unroll
        for (int off = 1; off < 64; off <<= 1) bv = fmaxf(bv, __shfl_xor(bv, off));
        int cand = (v1 == bv) ? i1 : 0x7FFFFFFF;
        int bi = cand;
        #pragma unroll
        for (int off = 1; off < 64; off <<= 1) bi = min(bi, __shfl_xor(bi, off));
        if (lane == 0) outp[it] = bi;
        if (v1 == bv && i1 == bi) {       // unique owner
            rm |= 1u << ((((unsigned)bi >> 6) & 0x1C) | ((unsigned)bi & 3));  // slot 4j+q
            v1 = v2; i1 = i2; v2 = v3; i2 = i3; v3 = v4; i3 = i4;
            v4 = -FLT_MAX; i4 = 0x7FFFFFFF;
            if (--depth == 0) {           // cache exhausted: exact rescan (rare)
                v1 = v2 = v3 = v4 = -FLT_MAX;
                i1 = i2 = i3 = i4 = 0x7FFFFFFF;
                #pragma unroll
                for (int j = 0; j < 8; ++j) {
                    int m0 = 4 * lane + 256 * j;
                    if (!(rm & (1u << (4 * j + 0)))) INS(pv[j].x, m0);
                    if (!(rm & (1u << (4 * j + 1)))) INS(pv[j].y, m0 + 1);
                    if (!(rm & (1u << (4 * j + 2)))) INS(pv[j].z, m0 + 2);
                    if (!(rm & (1u << (4 * j + 3)))) INS(pv[j].w, m0 + 3);
                }
                depth = 4;
            }
        }
    }
}

__global__ __launch_bounds__(256) void knn_sel_kernel(
    const float* __restrict__ pd2, int* __restrict__ idxb, int b0) {
    int tid = threadIdx.x, w = tid >> 6, lane = tid & 63;
    int rg = blockIdx.x * 4 + w;          // 0..4095 (2 batches)
    int bz = rg >> 11, n = rg & (NN - 1);
    const float* row = pd2 + ((size_t)bz * NN + n) * NN;
    float4 pv[8];
    #pragma unroll
    for (int j = 0; j < 8; ++j) pv[j] = *(const float4*)&row[4 * lane + 256 * j];
    int* outp = idxb + ((size_t)(b0 + bz) * NN + n) * KNN;
    sel20_reg(pv, lane, outp);
}

// Layer-1 (C=3) fused: pd computed inline in registers, same selection.
__global__ __launch_bounds__(256) void knn_c3_kernel(
    const float* __restrict__ XC,   // x: [B][3][N]
    const float* __restrict__ XT,   // XT0: [B][N][3]
    const float* __restrict__ xx, int* __restrict__ idxb) {
    int tid = threadIdx.x, w = tid >> 6, lane = tid & 63;
    int rg = blockIdx.x * 4 + w;          // 0..16383
    int b = rg >> 11, n = rg & (NN - 1);
    const float* xt0 = XT + ((size_t)b * NN + n) * 3;
    float s0 = xt0[0], s1 = xt0[1], s2 = xt0[2];
    float xrn = xx[(size_t)b * NN + n];
    float4 pv[8];
    #pragma unroll
    for (int j = 0; j < 8; ++j) {
        int m0 = 4 * lane + 256 * j;
        float4 v0 = *(const float4*)&XC[((size_t)b * 3 + 0) * NN + m0];
        float4 v1 = *(const float4*)&XC[((size_t)b * 3 + 1) * NN + m0];
        float4 v2 = *(const float4*)&XC[((size_t)b * 3 + 2) * NN + m0];
        float4 xm = *(const float4*)&xx[(size_t)b * NN + m0];
        float4 in;
        in.x = v0.x * s0; in.x += v1.x * s1; in.x += v2.x * s2;
        in.y = v0.y * s0; in.y += v1.y * s1; in.y += v2.y * s2;
        in.z = v0.z * s0; in.z += v1.z * s1; in.z += v2.z * s2;
        in.w = v0.w * s0; in.w += v1.w * s1; in.w += v2.w * s2;
        pv[j].x = (2.0f * in.x - xrn) - xm.x;
        pv[j].y = (2.0f * in.y - xrn) - xm.y;
        pv[j].z = (2.0f * in.z - xrn) - xm.z;
        pv[j].w = (2.0f * in.w - xrn) - xm.w;
    }
    int* outp = idxb + ((size_t)b * NN + n) * KNN;
    sel20_reg(pv, lane, outp);
}
#undef INS

// ---------------- EdgeConv pass A (fp32, layers 1-3 only: feeds KNN, must stay exact) ----

template <int C, int O>
__global__ __launch_bounds__(256) void edge_passA_kernel(
    const float* __restrict__ XT, const int* __restrict__ idxb,
    const float* __restrict__ WaT, const float* __restrict__ WdT,
    float* __restrict__ ymaxb, float* __restrict__ yminb, float* __restrict__ stats) {
    constexpr int OT = O / 4;
    constexpr int G = 256 / OT;
    constexpr int KP = (KNN + G - 1) / G;
    constexpr int CP = (C % 4 == 0) ? (C + 4) : C;
    __shared__ alignas(16) float ctr[C];
    __shared__ alignas(16) float nbr[KNN][CP];
    __shared__ alignas(16) float t2[O];
    __shared__ int sidx[KNN];
    __shared__ alignas(16) float red[4][1024];
    int blk = blockIdx.x;
    int b = blk >> 11;            // N = 2048
    int tid = threadIdx.x;
    if (tid < KNN) sidx[tid] = idxb[(size_t)blk * KNN + tid];
    for (int e = tid; e < C; e += 256) ctr[e] = XT[(size_t)blk * C + e];
    __syncthreads();
    if constexpr (C % 4 == 0) {
        for (int e = tid; e < KNN * (C / 4); e += 256) {
            int k = e / (C / 4), q = e - k * (C / 4);
            *(float4*)&nbr[k][q * 4] =
                *(const float4*)&XT[((size_t)b * NN + sidx[k]) * C + q * 4];
        }
    } else {
        for (int e = tid; e < KNN * C; e += 256) {
            int k = e / C, c = e - k * C;
            nbr[k][c] = XT[((size_t)b * NN + sidx[k]) * C + c];
        }
    }
    if (tid < O) {
        float s = 0;
        for (int c = 0; c < C; ++c) s += WdT[c * O + tid] * ctr[c];
        t2[tid] = s;
    }
    __syncthreads();
    int og = tid % OT, kg = tid / OT;
    int o0 = og * 4;
    float acc[KP][4];
    #pragma unroll
    for (int j = 0; j < KP; ++j) { acc[j][0] = 0; acc[j][1] = 0; acc[j][2] = 0; acc[j][3] = 0; }
    if constexpr (C % 4 == 0) {
        for (int c = 0; c < C; c += 4) {
            float4 w0 = *(const float4*)&WaT[(c + 0) * O + o0];
            float4 w1 = *(const float4*)&WaT[(c + 1) * O + o0];
            float4 w2 = *(const float4*)&WaT[(c + 2) * O + o0];
            float4 w3 = *(const float4*)&WaT[(c + 3) * O + o0];
            #pragma unroll
            for (int j = 0; j < KP; ++j) {
                int k = kg + j * G;
                if (k < KNN) {
                    float4 nv = *(const float4*)&nbr[k][c];
                    acc[j][0] += nv.x * w0.x + nv.y * w1.x + nv.z * w2.x + nv.w * w3.x;
                    acc[j][1] += nv.x * w0.y + nv.y * w1.y + nv.z * w2.y + nv.w * w3.y;
                    acc[j][2] += nv.x * w0.z + nv.y * w1.z + nv.z * w2.z + nv.w * w3.z;
                    acc[j][3] += nv.x * w0.w + nv.y * w1.w + nv.z * w2.w + nv.w * w3.w;
                }
            }
        }
    } else {
        for (int c = 0; c < C; ++c) {
            float4 w = *(const float4*)&WaT[c * O + o0];
            #pragma unroll
            for (int j = 0; j < KP; ++j) {
                int k = kg + j * G;
                if (k < KNN) {
                    float nv = nbr[k][c];
                    acc[j][0] += nv * w.x; acc[j][1] += nv * w.y;
                    acc[j][2] += nv * w.z; acc[j][3] += nv * w.w;
                }
            }
        }
    }
    float t2a[4];
    *(float4*)t2a = *(const float4*)&t2[o0];
    float vmax[4], vmin[4], vsum[4], vsq[4];
    #pragma unroll
    for (int q = 0; q < 4; ++q) { vmax[q] = -FLT_MAX; vmin[q] = FLT_MAX; vsum[q] = 0; vsq[q] = 0; }
    #pragma unroll
    for (int j = 0; j < KP; ++j) {
        int k = kg + j * G;
        if (k < KNN) {
            #pragma unroll
            for (int q = 0; q < 4; ++q) {
                float y = acc[j][q] + t2a[q];
                vmax[q] = fmaxf(vmax[q], y); vmin[q] = fminf(vmin[q], y);
                vsum[q] += y; vsq[q] += y * y;
            }
        }
    }
    *(float4*)&red[0][kg * O + o0] = make_float4(vmax[0], vmax[1], vmax[2], vmax[3]);
    *(float4*)&red[1][kg * O + o0] = make_float4(vmin[0], vmin[1], vmin[2], vmin[3]);
    *(float4*)&red[2][kg * O + o0] = make_float4(vsum[0], vsum[1], vsum[2], vsum[3]);
    *(float4*)&red[3][kg * O + o0] = make_float4(vsq[0], vsq[1], vsq[2], vsq[3]);
    __syncthreads();
    if (tid < O) {
        float m1 = -FLT_MAX, m2 = FLT_MAX, s1 = 0, s2 = 0;
        #pragma unroll 4
        for (int g = 0; g < G; ++g) {
            m1 = fmaxf(m1, red[0][g * O + tid]);
            m2 = fminf(m2, red[1][g * O + tid]);
            s1 += red[2][g * O + tid];
            s2 += red[3][g * O + tid];
        }
        ymaxb[(size_t)blk * O + tid] = m1;
        yminb[(size_t)blk * O + tid] = m2;
        float* st = &stats[(size_t)(blk & (NCOPY - 1)) * (2 * O)];
        atomicAdd(&st[tid], s1);
        atomicAdd(&st[O + tid], s2);
    }
}

// ---------------- T2 = XT3 . Wd (bf16 MFMA), all points ----------------

__global__ __launch_bounds__(256) void t2_mfma_kernel(
    const float* __restrict__ XT3, const short* __restrict__ Wdb, float* __restrict__ T2) {
    __shared__ alignas(16) short A[16][136];
    int blk = blockIdx.x;           // BB*NN/16 = 1024
    int tid = threadIdx.x, w = tid >> 6, lane = tid & 63;
    int n0g = blk * 16;
    for (int ch = tid; ch < 512; ch += 256) {
        int r = ch >> 5, c4 = (ch & 31) << 2;
        float4 v = *(const float4*)&XT3[((size_t)n0g + r) * 128 + c4];
        *(short4*)&A[r][c4] = f2b4(v);
    }
    __syncthreads();
    int arow = lane & 15, aq = lane >> 4;
    bf16x8 af[4];
    #pragma unroll
    for (int ks = 0; ks < 4; ++ks)
        af[ks] = *(const bf16x8*)&A[arow][ks * 32 + aq * 8];
    for (int t = 0; t < 4; ++t) {
        int nt = w * 4 + t;
        f32x4 acc = {0.f, 0.f, 0.f, 0.f};
        const short* bp = Wdb + (size_t)(nt * 16 + arow) * 128 + aq * 8;
        #pragma unroll
        for (int ks = 0; ks < 4; ++ks)
            acc = __builtin_amdgcn_mfma_f32_16x16x32_bf16(af[ks], *(const bf16x8*)(bp + ks * 32), acc, 0, 0, 0);
        #pragma unroll
        for (int r = 0; r < 4; ++r)
            T2[((size_t)n0g + aq * 4 + r) * 256 + nt * 16 + arow] = acc[r];
    }
}

// ---------------- EdgeConv layer 4 (bf16 MFMA, no LDS, Wab prefetch) ----------
// Per-lane direct global->reg A-fragment gather (A rows 20..31 hold garbage;
// their C rows are never read). Next-nt Wab frags + t2 prefetched in registers
// to overlap L2 latency with MFMA.

__global__ __launch_bounds__(256) void edge4_mfma_kernel(
    const float* __restrict__ XT, const int* __restrict__ idxb,
    const short* __restrict__ Wab, const float* __restrict__ T2,
    float* __restrict__ ymaxb, float* __restrict__ yminb, float* __restrict__ stats) {
    int blk = blockIdx.x;           // BB*NN/4 = 4096
    int tid = threadIdx.x, w = tid >> 6, lane = tid & 63;
    int p = blk * 4 + w;            // global point id
    int b = p >> 11;
    size_t baseC = (size_t)b * NN;
    const int* idxp = idxb + (size_t)p * KNN;
    int arow = lane & 15, aq = lane >> 4;
    int idx0 = idxp[arow];
    int idx1 = (arow < 4) ? idxp[16 + arow] : idx0;
    const float* r0 = &XT[(baseC + idx0) * 128 + aq * 8];
    const float* r1 = &XT[(baseC + idx1) * 128 + aq * 8];
    bf16x8 af0[4], af1[4];
    #pragma unroll
    for (int ks = 0; ks < 4; ++ks) {
        af0[ks] = f2b8(*(const float4*)(r0 + ks * 32), *(const float4*)(r0 + ks * 32 + 4));
        af1[ks] = f2b8(*(const float4*)(r1 + ks * 32), *(const float4*)(r1 + ks * 32 + 4));
    }
    const float* t2p = T2 + (size_t)p * 256;
    float* st = stats + (size_t)(p & (NCOPY - 1)) * 512;
    const short* bp0 = Wab + (size_t)arow * 128 + aq * 8;
    bf16x8 bfc[4];
    #pragma unroll
    for (int ks = 0; ks < 4; ++ks) bfc[ks] = *(const bf16x8*)(bp0 + ks * 32);
    float t2c = t2p[arow];
    for (int nt = 0; nt < 16; ++nt) {
        bf16x8 bfn[4]; float t2n = 0.f;
        if (nt < 15) {
            const short* bpn = Wab + (size_t)((nt + 1) * 16 + arow) * 128 + aq * 8;
            #pragma unroll
            for (int ks = 0; ks < 4; ++ks) bfn[ks] = *(const bf16x8*)(bpn + ks * 32);
            t2n = t2p[(nt + 1) * 16 + arow];
        }
        f32x4 acc0 = {0.f, 0.f, 0.f, 0.f}, acc1 = {0.f, 0.f, 0.f, 0.f};
        #pragma unroll
        for (int ks = 0; ks < 4; ++ks) {
            acc0 = __builtin_amdgcn_mfma_f32_16x16x32_bf16(af0[ks], bfc[ks], acc0, 0, 0, 0);
            acc1 = __builtin_amdgcn_mfma_f32_16x16x32_bf16(af1[ks], bfc[ks], acc1, 0, 0, 0);
        }
        float lmax = -FLT_MAX, lmin = FLT_MAX, ls = 0.f, lsq = 0.f;
        #pragma unroll
        for (int r = 0; r < 4; ++r) {
            float y = acc0[r] + t2c;
            lmax = fmaxf(lmax, y); lmin = fminf(lmin, y); ls += y; lsq += y * y;
        }
        if (aq == 0) {                  // acc1 rows 16..19 valid only in quad 0
            #pragma unroll
            for (int r = 0; r < 4; ++r) {
                float y = acc1[r] + t2c;
                lmax = fmaxf(lmax, y); lmin = fminf(lmin, y); ls += y; lsq += y * y;
            }
        }
        #pragma unroll
        for (int off = 16; off < 64; off <<= 1) {
            lmax = fmaxf(lmax, __shfl_xor(lmax, off));
            lmin = fminf(lmin, __shfl_xor(lmin, off));
            ls += __shfl_xor(ls, off);
            lsq += __shfl_xor(lsq, off);
        }
        if (lane < 16) {
            ymaxb[(size_t)p * 256 + nt * 16 + lane] = lmax;
            yminb[(size_t)p * 256 + nt * 16 + lane] = lmin;
            atomicAdd(&st[nt * 16 + lane], ls);
            atomicAdd(&st[256 + nt * 16 + lane], lsq);
        }
        #pragma unroll
        for (int ks = 0; ks < 4; ++ks) bfc[ks] = bfn[ks];
        t2c = t2n;
    }
}

// ---------------- BN finalize + edge pass B ----------------

__global__ void finalize_stats_kernel(const float* __restrict__ stats, const float* __restrict__ gg,
                                      const float* __restrict__ bb, float* __restrict__ scsh,
                                      int O, float invM) {
    int o = blockIdx.x * blockDim.x + threadIdx.x;
    if (o >= O) return;
    float s1 = 0, s2 = 0;
    for (int cp = 0; cp < NCOPY; ++cp) {
        s1 += stats[(size_t)cp * 2 * O + o];
        s2 += stats[(size_t)cp * 2 * O + O + o];
    }
    float mean = s1 * invM;
    float var = s2 * invM - mean * mean;
    float scale = gg[o] * rsqrtf(var + EPSV);
    float shift = bb[o] - mean * scale;
    scsh[o] = scale; scsh[O + o] = shift;
}

__global__ void edge_passB_kernel(const float* __restrict__ ymaxb, const float* __restrict__ yminb,
                                  const float* __restrict__ scsh, float* __restrict__ XTout,
                                  float* __restrict__ XCout, int O, int total) {
    int e = blockIdx.x * blockDim.x + threadIdx.x;
    if (e >= total) return;
    int o = e & (O - 1);
    float sc = scsh[o], sh = scsh[O + o];
    float y = (sc >= 0.0f) ? ymaxb[e] : yminb[e];   // monotone-affine max/min trick
    float z = sc * y + sh;
    float r = (z > 0.0f) ? z : SLOPEV * z;
    XTout[e] = r;
    if (XCout) {
        int n = (e / O) & (NN - 1);
        int bb_ = e / (O * NN);
        XCout[((size_t)bb_ * O + o) * NN + n] = r;
    }
}

// ---------------- final 512->1024 (bf16 MFMA) ----------------

__device__ __forceinline__ void stage_cat_b(short (*A)[520], const float* __restrict__ XT1,
                                            const float* __restrict__ XT2, const float* __restrict__ XT3,
                                            const float* __restrict__ XT4, int n0g, int tid) {
    for (int ch = tid; ch < 32 * 16; ch += 256) { int r = ch >> 4, c4 = (ch & 15) << 2;
        *(short4*)&A[r][c4]       = f2b4(*(const float4*)&XT1[((size_t)n0g + r) * 64 + c4]); }
    for (int ch = tid; ch < 32 * 16; ch += 256) { int r = ch >> 4, c4 = (ch & 15) << 2;
        *(short4*)&A[r][64 + c4]  = f2b4(*(const float4*)&XT2[((size_t)n0g + r) * 64 + c4]); }
    for (int ch = tid; ch < 32 * 32; ch += 256) { int r = ch >> 5, c4 = (ch & 31) << 2;
        *(short4*)&A[r][128 + c4] = f2b4(*(const float4*)&XT3[((size_t)n0g + r) * 128 + c4]); }
    for (int ch = tid; ch < 32 * 64; ch += 256) { int r = ch >> 6, c4 = (ch & 63) << 2;
        *(short4*)&A[r][256 + c4] = f2b4(*(const float4*)&XT4[((size_t)n0g + r) * 256 + c4]); }
}

__global__ __launch_bounds__(256) void final_mfmaA_kernel(
    const float* __restrict__ XT1, const float* __restrict__ XT2, const float* __restrict__ XT3,
    const float* __restrict__ XT4, const short* __restrict__ W5b, float* __restrict__ stats) {
    __shared__ alignas(16) short A[32][520];
    int blk = blockIdx.x;           // BB*NN/32 = 512
    int tid = threadIdx.x, w = tid >> 6, lane = tid & 63;
    int n0g = blk * 32;
    stage_cat_b(A, XT1, XT2, XT3, XT4, n0g, tid);
    __syncthreads();
    int arow = lane & 15, aq = lane >> 4;
    float* st = stats + (size_t)(blk & (NCOPY - 1)) * 2048;
    for (int mt = 0; mt < 2; ++mt) {
        bf16x8 af[16];
        #pragma unroll
        for (int ks = 0; ks < 16; ++ks)
            af[ks] = *(const bf16x8*)&A[mt * 16 + arow][ks * 32 + aq * 8];
        for (int t = 0; t < 16; ++t) {
            int nt = w * 16 + t;
            f32x4 acc = {0.f, 0.f, 0.f, 0.f};
            const short* bp = W5b + (size_t)(nt * 16 + arow) * 512 + aq * 8;
            #pragma unroll
            for (int ks = 0; ks < 16; ++ks)
                acc = __builtin_amdgcn_mfma_f32_16x16x32_bf16(af[ks], *(const bf16x8*)(bp + ks * 32), acc, 0, 0, 0);
            float ls = (acc[0] + acc[1]) + (acc[2] + acc[3]);
            float lsq = (acc[0] * acc[0] + acc[1] * acc[1]) + (acc[2] * acc[2] + acc[3] * acc[3]);
            ls += __shfl_xor(ls, 16); ls += __shfl_xor(ls, 32);
            lsq += __shfl_xor(lsq, 16); lsq += __shfl_xor(lsq, 32);
            if (lane < 16) {
                atomicAdd(&st[nt * 16 + lane], ls);
                atomicAdd(&st[1024 + nt * 16 + lane], lsq);
            }
        }
    }
}

__global__ __launch_bounds__(256) void final_mfmaB_kernel(
    const float* __restrict__ XT1, const float* __restrict__ XT2, const float* __restrict__ XT3,
    const float* __restrict__ XT4, const short* __restrict__ W5b, const float* __restrict__ scsh,
    float* __restrict__ pmax, float* __restrict__ psum) {
    __shared__ alignas(16) short A[32][520];
    int blk = blockIdx.x;           // 512
    int tid = threadIdx.x, w = tid >> 6, lane = tid & 63;
    int n0g = blk * 32;
    stage_cat_b(A, XT1, XT2, XT3, XT4, n0g, tid);
    __syncthreads();
    int arow = lane & 15, aq = lane >> 4;
    for (int mt = 0; mt < 2; ++mt) {
        bf16x8 af[16];
        #pragma unroll
        for (int ks = 0; ks < 16; ++ks)
            af[ks] = *(const bf16x8*)&A[mt * 16 + arow][ks * 32 + aq * 8];
        for (int t = 0; t < 16; ++t) {
            int nt = w * 16 + t;
            f32x4 acc = {0.f, 0.f, 0.f, 0.f};
            const short* bp = W5b + (size_t)(nt * 16 + arow) * 512 + aq * 8;
            #pragma unroll
            for (int ks = 0; ks < 16; ++ks)
                acc = __builtin_amdgcn_mfma_f32_16x16x32_bf16(af[ks], *(const bf16x8*)(bp + ks * 32), acc, 0, 0, 0);
            int o = nt * 16 + arow;
            float sc = scsh[o], sh = scsh[1024 + o];
            float lmax = -FLT_MAX, lsm = 0.f;
            #pragma unroll
            for (int r = 0; r < 4; ++r) {
                float z = fmaf(sc, acc[r], sh);
                float l = (z > 0.0f) ? z : SLOPEV * z;
                lmax = fmaxf(lmax, l); lsm += l;
            }
            lmax = fmaxf(lmax, __shfl_xor(lmax, 16));
            lmax = fmaxf(lmax, __shfl_xor(lmax, 32));
            lsm += __shfl_xor(lsm, 16); lsm += __shfl_xor(lsm, 32);
            if (lane < 16) {
                pmax[(size_t)(blk * 2 + mt) * 1024 + o] = lmax;
                psum[(size_t)(blk * 2 + mt) * 1024 + o] = lsm;
            }
        }
    }
}

__global__ void final_passC_kernel(const float* __restrict__ pmax, const float* __restrict__ psum,
                                   float* __restrict__ out) {
    int e = blockIdx.x * blockDim.x + threadIdx.x;
    if (e >= BB * 1024) return;
    int b = e >> 10, o = e & 1023;
    float mx = -FLT_MAX, sm = 0;
    for (int j = 0; j < NN / 16; ++j) {
        size_t p = ((size_t)(b * (NN / 16) + j)) * 1024 + o;
        mx = fmaxf(mx, pmax[p]);
        sm += psum[p];
    }
    out[b * 2048 + o] = mx;
    out[b * 2048 + 1024 + o] = sm * (1.0f / NN);
}

// ---------------- launch ----------------

extern "C" void kernel_launch(void* const* d_in, const int* in_sizes, int n_in,
                              void* d_out, int out_size, void* d_ws, size_t ws_size,
                              hipStream_t stream) {
    const float* x  = (const float*)d_in[0];
    const float* W1 = (const float*)d_in[1];
    const float* W2 = (const float*)d_in[2];
    const float* W3 = (const float*)d_in[3];
    const float* W4 = (const float*)d_in[4];
    const float* W5 = (const float*)d_in[5];
    const float* g1 = (const float*)d_in[6];  const float* b1 = (const float*)d_in[7];
    const float* g2 = (const float*)d_in[8];  const float* b2 = (const float*)d_in[9];
    const float* g3 = (const float*)d_in[10]; const float* b3 = (const float*)d_in[11];
    const float* g4 = (const float*)d_in[12]; const float* b4 = (const float*)d_in[13];
    const float* g5 = (const float*)d_in[14]; const float* b5 = (const float*)d_in[15];

    float* ws = (float*)d_ws;
    size_t off = 0;
    float* XT0 = ws + off; off += (size_t)BB * NN * 3;
    float* XT1 = ws + off; off += (size_t)BB * NN * 64;
    float* XT2 = ws + off; off += (size_t)BB * NN * 64;
    float* XT3 = ws + off; off += (size_t)BB * NN * 128;
    float* XT4 = ws + off; off += (size_t)BB * NN * 256;
    float* XC1 = ws + off; off += (size_t)BB * NN * 64;
    float* XC2 = ws + off; off += (size_t)BB * NN * 64;
    float* XC3 = ws + off; off += (size_t)BB * NN * 128;
    float* ymax = ws + off; off += (size_t)BB * NN * 256;
    float* ymin = ws + off; off += (size_t)BB * NN * 256;
    int*   idxb = (int*)(ws + off); off += (size_t)BB * NN * KNN;
    float* xxb = ws + off; off += (size_t)BB * NN;
    float* WaT = ws + off; off += 128 * 256;
    float* WdT = ws + off; off += 128 * 256;
    short* Wa4b = (short*)(ws + off); off += 256 * 128 / 2;
    short* Wd4b = (short*)(ws + off); off += 256 * 128 / 2;
    short* W5b  = (short*)(ws + off); off += 1024 * 512 / 2;
    float* st1 = ws + off; off += NCOPY * 2 * 64;
    float* st2 = ws + off; off += NCOPY * 2 * 64;
    float* st3 = ws + off; off += NCOPY * 2 * 128;
    float* st4 = ws + off; off += NCOPY * 2 * 256;
    float* st5 = ws + off; off += NCOPY * 2 * 1024;
    float* sc1 = ws + off; off += 2 * 64;
    float* sc2 = ws + off; off += 2 * 64;
    float* sc3 = ws + off; off += 2 * 128;
    float* sc4 = ws + off; off += 2 * 256;
    float* sc5 = ws + off; off += 2 * 1024;
    float* T2 = XC1;      // alias: XC1..3 dead after layer-4 knn
    float* pd2 = ymax;    // alias: ymax+ymin = 2 batches of pd (33.5 MB), dead during knn
    float* pmax = ymax;   // reuse (edge buffers dead by final pass B)
    float* psum = ymin;

    hipMemsetAsync(st1, 0, (size_t)NCOPY * 2 * (64 + 64 + 128 + 256 + 1024) * sizeof(float), stream);

    transpose0_kernel<<<(BB * NN * 3 + 255) / 256, 256, 0, stream>>>(x, XT0);

    dim3 dgrid(NN / 64, NN / 64, 2);

    // layer 1: C=3 -> O=64   (x itself is the channel-major XC0)
    wprep_kernel<<<(3 * 64 + 255) / 256, 256, 0, stream>>>(W1, WaT, WdT, 3, 64);
    xx_kernel<3><<<BB * NN / 256, 256, 0, stream>>>(XT0, xxb);
    knn_c3_kernel<<<BB * NN / 4, 256, 0, stream>>>(x, XT0, xxb, idxb);
    edge_passA_kernel<3, 64><<<BB * NN, 256, 0, stream>>>(XT0, idxb, WaT, WdT, ymax, ymin, st1);
    finalize_stats_kernel<<<1, 64, 0, stream>>>(st1, g1, b1, sc1, 64, 1.0f / ((float)BB * NN * KNN));
    edge_passB_kernel<<<BB * NN * 64 / 256, 256, 0, stream>>>(ymax, ymin, sc1, XT1, XC1, 64, BB * NN * 64);

    // layer 2: C=64 -> O=64
    wprep_kernel<<<(64 * 64 + 255) / 256, 256, 0, stream>>>(W2, WaT, WdT, 64, 64);
    xx_kernel<64><<<BB * NN / 256, 256, 0, stream>>>(XT1, xxb);
    for (int p = 0; p < 4; ++p) {
        knn_dist_kernel<64><<<dgrid, 256, 0, stream>>>(XC1, XT1, xxb, pd2, 2 * p);
        knn_sel_kernel<<<2 * NN / 4, 256, 0, stream>>>(pd2, idxb, 2 * p);
    }
    edge_passA_kernel<64, 64><<<BB * NN, 256, 0, stream>>>(XT1, idxb, WaT, WdT, ymax, ymin, st2);
    finalize_stats_kernel<<<1, 64, 0, stream>>>(st2, g2, b2, sc2, 64, 1.0f / ((float)BB * NN * KNN));
    edge_passB_kernel<<<BB * NN * 64 / 256, 256, 0, stream>>>(ymax, ymin, sc2, XT2, XC2, 64, BB * NN * 64);

    // layer 3: C=64 -> O=128
    wprep_kernel<<<(64 * 128 + 255) / 256, 256, 0, stream>>>(W3, WaT, WdT, 64, 128);
    xx_kernel<64><<<BB * NN / 256, 256, 0, stream>>>(XT2, xxb);
    for (int p = 0; p < 4; ++p) {
        knn_dist_kernel<64><<<dgrid, 256, 0, stream>>>(XC2, XT2, xxb, pd2, 2 * p);
        knn_sel_kernel<<<2 * NN / 4, 256, 0, stream>>>(pd2, idxb, 2 * p);
    }
    edge_passA_kernel<64, 128><<<BB * NN, 256, 0, stream>>>(XT2, idxb, WaT, WdT, ymax, ymin, st3);
    finalize_stats_kernel<<<1, 128, 0, stream>>>(st3, g3, b3, sc3, 128, 1.0f / ((float)BB * NN * KNN));
    edge_passB_kernel<<<BB * NN * 128 / 256, 256, 0, stream>>>(ymax, ymin, sc3, XT3, XC3, 128, BB * NN * 128);

    // layer 4: C=128 -> O=256 (bf16 MFMA; output never feeds KNN)
    wprep4b_kernel<<<256 * 128 / 256, 256, 0, stream>>>(W4, Wa4b, Wd4b);
    xx_kernel<128><<<BB * NN / 256, 256, 0, stream>>>(XT3, xxb);
    for (int p = 0; p < 4; ++p) {
        knn_dist_kernel<128><<<dgrid, 256, 0, stream>>>(XC3, XT3, xxb, pd2, 2 * p);
        knn_sel_kernel<<<2 * NN / 4, 256, 0, stream>>>(pd2, idxb, 2 * p);
    }
    t2_mfma_kernel<<<BB * NN / 16, 256, 0, stream>>>(XT3, Wd4b, T2);   // overwrites XC1..3
    edge4_mfma_kernel<<<BB * NN / 4, 256, 0, stream>>>(XT3, idxb, Wa4b, T2, ymax, ymin, st4);
    finalize_stats_kernel<<<1, 256, 0, stream>>>(st4, g4, b4, sc4, 256, 1.0f / ((float)BB * NN * KNN));
    edge_passB_kernel<<<BB * NN * 256 / 256, 256, 0, stream>>>(ymax, ymin, sc4, XT4, nullptr, 256, BB * NN * 256);

    // final: 512 -> 1024 (bf16 MFMA), BN over (B,N), leaky, max+mean over N
    w5b_kernel<<<1024 * 512 / 256, 256, 0, stream>>>(W5, W5b);
    final_mfmaA_kernel<<<BB * NN / 32, 256, 0, stream>>>(XT1, XT2, XT3, XT4, W5b, st5);
    finalize_stats_kernel<<<4, 256, 0, stream>>>(st5, g5, b5, sc5, 1024, 1.0f / ((float)BB * NN));
    final_mfmaB_kernel<<<BB * NN / 32, 256, 0, stream>>>(XT1, XT2, XT3, XT4, W5b, sc5, pmax, psum);
    final_passC_kernel<<<(BB * 1024 + 255) / 256, 256, 0, stream>>>(pmax, psum, (float*)d_out);

    (void)in_sizes; (void)n_in; (void)out_size; (void)ws_size;
}

// Round 9
// 1400.038 us; speedup vs baseline: 2.8531x; 1.0825x over previous
//
#include <hip/hip_runtime.h>
#include <cfloat>

#define BB 8
#define NN 2048
#define KNN 20
#define EPSV 1e-5f
#define SLOPEV 0.2f

typedef short bf16x8 __attribute__((ext_vector_type(8)));   // 8 bf16 (4 VGPRs)
typedef float f32x4 __attribute__((ext_vector_type(4)));

__device__ __forceinline__ unsigned short f2b(float f) {
    unsigned u = __builtin_bit_cast(unsigned, f);
    unsigned r = (u + 0x7FFFu + ((u >> 16) & 1u)) >> 16;   // RNE
    return (unsigned short)r;
}
__device__ __forceinline__ short4 f2b4(float4 v) {
    short4 r;
    r.x = (short)f2b(v.x); r.y = (short)f2b(v.y);
    r.z = (short)f2b(v.z); r.w = (short)f2b(v.w);
    return r;
}

// ---------------- small prep kernels ----------------

__global__ void transpose0_kernel(const float* __restrict__ x, float* __restrict__ XT0) {
    int e = blockIdx.x * blockDim.x + threadIdx.x;
    if (e >= BB * NN * 3) return;
    int b = e / (NN * 3); int r = e - b * NN * 3; int n = r / 3; int c = r - n * 3;
    XT0[e] = x[((size_t)b * 3 + c) * NN + n];
}

__global__ void wprep_kernel(const float* __restrict__ W, float* __restrict__ WaT,
                             float* __restrict__ WdT, int C, int O) {
    int e = blockIdx.x * blockDim.x + threadIdx.x;
    if (e >= C * O) return;
    int c = e / O, o = e - c * O;
    float a = W[o * 2 * C + c];
    WaT[e] = a;
    WdT[e] = W[o * 2 * C + C + c] - a;
}

// W4 [256][256] -> Wa bf16 [o=256][c=128], Wd bf16 [o=256][c=128]
__global__ void wprep4b_kernel(const float* __restrict__ W, short* __restrict__ Wab,
                               short* __restrict__ Wdb) {
    int e = blockIdx.x * 256 + threadIdx.x;   // 32768 exact
    int o = e >> 7, c = e & 127;
    float a = W[o * 256 + c];
    Wab[e] = (short)f2b(a);
    Wdb[e] = (short)f2b(W[o * 256 + 128 + c] - a);
}

__global__ void w5b_kernel(const float* __restrict__ W5, short* __restrict__ W5b) {
    int e = blockIdx.x * 256 + threadIdx.x;   // 1024*512 exact, same [o][c] layout
    W5b[e] = (short)f2b(W5[e]);
}

// ---------------- per-point squared norm (matches dot-product partial order) ----

template <int C>
__global__ void xx_kernel(const float* __restrict__ XT, float* __restrict__ xx) {
    int e = blockIdx.x * blockDim.x + threadIdx.x;
    if (e >= BB * NN) return;
    const float* p = &XT[(size_t)e * C];
    float s;
    if constexpr (C % 4 == 0) {
        float s0 = 0, s1 = 0, s2 = 0, s3 = 0;
        for (int c = 0; c < C; c += 4) {
            float4 v = *(const float4*)(p + c);
            s0 += v.x * v.x; s1 += v.y * v.y; s2 += v.z * v.z; s3 += v.w * v.w;
        }
        s = (s0 + s1) + (s2 + s3);
    } else {
        s = p[0] * p[0];
        for (int c = 1; c < C; ++c) s += p[c] * p[c];
    }
    xx[e] = s;
}

// ---------------- KNN: tiled distance GEMM + register selection ----------------

template <int C>
__global__ __launch_bounds__(256) void knn_dist_kernel(
    const float* __restrict__ XC,   // [B][C][N]
    const float* __restrict__ XT,   // [B][N][C]
    const float* __restrict__ xx,   // [B][N]
    float* __restrict__ pd2,        // [2][N][N]
    int b0) {
    constexpr int BK = 16;
    __shared__ float As[BK][68];    // [c][n] (transposed on store)
    __shared__ alignas(16) float Bs[BK][64];   // [c][m]
    int mt = blockIdx.x, nt = blockIdx.y, bz = blockIdx.z;
    int b = b0 + bz;
    int n0 = nt * 64, m0 = mt * 64;
    int tid = threadIdx.x;
    int tn = tid >> 4, tm = tid & 15;
    float P[4][4][4];
    #pragma unroll
    for (int cl = 0; cl < 4; ++cl)
        #pragma unroll
        for (int i = 0; i < 4; ++i)
            #pragma unroll
            for (int j = 0; j < 4; ++j) P[cl][i][j] = 0.f;

    int arow = tid >> 2, acq = tid & 3;
    int brow = tid >> 4, bmq = tid & 15;
    for (int kb = 0; kb < C / BK; ++kb) {
        if (kb) __syncthreads();
        float4 av = *(const float4*)&XT[((size_t)b * NN + n0 + arow) * C + kb * BK + acq * 4];
        As[acq * 4 + 0][arow] = av.x; As[acq * 4 + 1][arow] = av.y;
        As[acq * 4 + 2][arow] = av.z; As[acq * 4 + 3][arow] = av.w;
        *(float4*)&Bs[brow][bmq * 4] =
            *(const float4*)&XC[((size_t)b * C + kb * BK + brow) * NN + m0 + bmq * 4];
        __syncthreads();
        #pragma unroll
        for (int c = 0; c < BK; ++c) {
            float4 a = *(const float4*)&As[c][tn * 4];
            float4 bv = *(const float4*)&Bs[c][tm * 4];
            int cl = c & 3;
            P[cl][0][0] += a.x * bv.x; P[cl][0][1] += a.x * bv.y; P[cl][0][2] += a.x * bv.z; P[cl][0][3] += a.x * bv.w;
            P[cl][1][0] += a.y * bv.x; P[cl][1][1] += a.y * bv.y; P[cl][1][2] += a.y * bv.z; P[cl][1][3] += a.y * bv.w;
            P[cl][2][0] += a.z * bv.x; P[cl][2][1] += a.z * bv.y; P[cl][2][2] += a.z * bv.z; P[cl][2][3] += a.z * bv.w;
            P[cl][3][0] += a.w * bv.x; P[cl][3][1] += a.w * bv.y; P[cl][3][2] += a.w * bv.z; P[cl][3][3] += a.w * bv.w;
        }
    }
    float4 xm = *(const float4*)&xx[(size_t)b * NN + m0 + tm * 4];
    #pragma unroll
    for (int i = 0; i < 4; ++i) {
        float xrn = xx[(size_t)b * NN + n0 + tn * 4 + i];
        float4 pd;
        float in0 = (P[0][i][0] + P[1][i][0]) + (P[2][i][0] + P[3][i][0]);
        float in1 = (P[0][i][1] + P[1][i][1]) + (P[2][i][1] + P[3][i][1]);
        float in2 = (P[0][i][2] + P[1][i][2]) + (P[2][i][2] + P[3][i][2]);
        float in3 = (P[0][i][3] + P[1][i][3]) + (P[2][i][3] + P[3][i][3]);
        pd.x = (2.0f * in0 - xrn) - xm.x;
        pd.y = (2.0f * in1 - xrn) - xm.y;
        pd.z = (2.0f * in2 - xrn) - xm.z;
        pd.w = (2.0f * in3 - xrn) - xm.w;
        *(float4*)&pd2[((size_t)bz * NN + n0 + tn * 4 + i) * NN + m0 + tm * 4] = pd;
    }
}

// strict > keeps earliest-inserted (lowest m) among equal values
#define INS(val, mm) do { \
    float _v = (val); int _m = (mm); \
    bool b1 = _v > v1, b2 = _v > v2, b3 = _v > v3, b4 = _v > v4; \
    i4 = b3 ? i3 : (b4 ? _m : i4);  v4 = b3 ? v3 : (b4 ? _v : v4); \
    i3 = b2 ? i2 : (b3 ? _m : i3);  v3 = b2 ? v2 : (b3 ? _v : v3); \
    i2 = b1 ? i1 : (b2 ? _m : i2);  v2 = b1 ? v1 : (b2 ? _v : v2); \
    i1 = b1 ? _m : i1;              v1 = b1 ? _v : v1; \
} while (0)

__device__ __forceinline__ void sel20_reg(const float4* pv, int lane, int* outp) {
    float v1 = -FLT_MAX, v2 = -FLT_MAX, v3 = -FLT_MAX, v4 = -FLT_MAX;
    int i1 = 0x7FFFFFFF, i2 = 0x7FFFFFFF, i3 = 0x7FFFFFFF, i4 = 0x7FFFFFFF;
    unsigned rm = 0;
    #pragma unroll
    for (int j = 0; j < 8; ++j) {
        int m0 = 4 * lane + 256 * j;
        INS(pv[j].x, m0); INS(pv[j].y, m0 + 1); INS(pv[j].z, m0 + 2); INS(pv[j].w, m0 + 3);
    }
    int depth = 4;
    for (int it = 0; it < KNN; ++it) {
        float bv = v1;
        #pragma unroll
        for (int off = 1; off < 64; off <<= 1) bv = fmaxf(bv, __shfl_xor(bv, off));
        int cand = (v1 == bv) ? i1 : 0x7FFFFFFF;
        int bi = cand;
        #pragma unroll
        for (int off = 1; off < 64; off <<= 1) bi = min(bi, __shfl_xor(bi, off));
        if (lane == 0) outp[it] = bi;
        if (v1 == bv && i1 == bi) {       // unique owner
            rm |= 1u << ((((unsigned)bi >> 6) & 0x1C) | ((unsigned)bi & 3));  // slot 4j+q
            v1 = v2; i1 = i2; v2 = v3; i2 = i3; v3 = v4; i3 = i4;
            v4 = -FLT_MAX; i4 = 0x7FFFFFFF;
            if (--depth == 0) {           // cache exhausted: exact rescan (rare)
                v1 = v2 = v3 = v4 = -FLT_MAX;
                i1 = i2 = i3 = i4 = 0x7FFFFFFF;
                #pragma unroll
                for (int j = 0; j < 8; ++j) {
                    int m0 = 4 * lane + 256 * j;
                    if (!(rm & (1u << (4 * j + 0)))) INS(pv[j].x, m0);
                    if (!(rm & (1u << (4 * j + 1)))) INS(pv[j].y, m0 + 1);
                    if (!(rm & (1u << (4 * j + 2)))) INS(pv[j].z, m0 + 2);
                    if (!(rm & (1u << (4 * j + 3)))) INS(pv[j].w, m0 + 3);
                }
                depth = 4;
            }
        }
    }
}

__global__ __launch_bounds__(256) void knn_sel_kernel(
    const float* __restrict__ pd2, int* __restrict__ idxb, int b0) {
    int tid = threadIdx.x, w = tid >> 6, lane = tid & 63;
    int rg = blockIdx.x * 4 + w;          // 0..4095 (2 batches)
    int bz = rg >> 11, n = rg & (NN - 1);
    const float* row = pd2 + ((size_t)bz * NN + n) * NN;
    float4 pv[8];
    #pragma unroll
    for (int j = 0; j < 8; ++j) pv[j] = *(const float4*)&row[4 * lane + 256 * j];
    int* outp = idxb + ((size_t)(b0 + bz) * NN + n) * KNN;
    sel20_reg(pv, lane, outp);
}

// Layer-1 (C=3) fused: pd computed inline in registers, same selection.
__global__ __launch_bounds__(256) void knn_c3_kernel(
    const float* __restrict__ XC,   // x: [B][3][N]
    const float* __restrict__ XT,   // XT0: [B][N][3]
    const float* __restrict__ xx, int* __restrict__ idxb) {
    int tid = threadIdx.x, w = tid >> 6, lane = tid & 63;
    int rg = blockIdx.x * 4 + w;          // 0..16383
    int b = rg >> 11, n = rg & (NN - 1);
    const float* xt0 = XT + ((size_t)b * NN + n) * 3;
    float s0 = xt0[0], s1 = xt0[1], s2 = xt0[2];
    float xrn = xx[(size_t)b * NN + n];
    float4 pv[8];
    #pragma unroll
    for (int j = 0; j < 8; ++j) {
        int m0 = 4 * lane + 256 * j;
        float4 v0 = *(const float4*)&XC[((size_t)b * 3 + 0) * NN + m0];
        float4 v1 = *(const float4*)&XC[((size_t)b * 3 + 1) * NN + m0];
        float4 v2 = *(const float4*)&XC[((size_t)b * 3 + 2) * NN + m0];
        float4 xm = *(const float4*)&xx[(size_t)b * NN + m0];
        float4 in;
        in.x = v0.x * s0; in.x += v1.x * s1; in.x += v2.x * s2;
        in.y = v0.y * s0; in.y += v1.y * s1; in.y += v2.y * s2;
        in.z = v0.z * s0; in.z += v1.z * s1; in.z += v2.z * s2;
        in.w = v0.w * s0; in.w += v1.w * s1; in.w += v2.w * s2;
        pv[j].x = (2.0f * in.x - xrn) - xm.x;
        pv[j].y = (2.0f * in.y - xrn) - xm.y;
        pv[j].z = (2.0f * in.z - xrn) - xm.z;
        pv[j].w = (2.0f * in.w - xrn) - xm.w;
    }
    int* outp = idxb + ((size_t)b * NN + n) * KNN;
    sel20_reg(pv, lane, outp);
}
#undef INS

// ---------------- dense T1/T2 precompute (fp32, layers 1-3) ----------------
// T1 = X.Wa^T with the EXACT c-quad accumulation expression of the original
// edge_passA acc; T2 = X.Wd^T with the EXACT scalar ascending chain of the
// original t2 — keeps XT1..3 bit-identical (they feed KNN).

template <int C, int O>
__global__ __launch_bounds__(256) void t1t2_gemm_kernel(
    const float* __restrict__ XT, const float* __restrict__ WaT,
    const float* __restrict__ WdT, float* __restrict__ T1, float* __restrict__ T2) {
    constexpr int CP = (C < 4) ? 4 : C;
    __shared__ alignas(16) float xt[64][CP];
    int p0 = blockIdx.x * 64;
    int tid = threadIdx.x;
    if constexpr (C % 4 == 0) {
        for (int e = tid; e < 64 * (C / 4); e += 256) {
            int r = e / (C / 4), q = e - r * (C / 4);
            *(float4*)&xt[r][q * 4] = *(const float4*)&XT[((size_t)p0 + r) * C + q * 4];
        }
    } else {
        for (int e = tid; e < 64 * C; e += 256) {
            int r = e / C, c = e - r * C;
            xt[r][c] = XT[((size_t)p0 + r) * C + c];
        }
    }
    __syncthreads();
    {
        constexpr int OQ = O / 4;
        constexpr int PS = 256 / OQ;
        constexpr int PPT = 64 / PS;
        int oq = tid % OQ, ps = tid / OQ;
        int o0 = oq * 4;
        float acc[PPT][4];
        #pragma unroll
        for (int t = 0; t < PPT; ++t) { acc[t][0] = 0; acc[t][1] = 0; acc[t][2] = 0; acc[t][3] = 0; }
        if constexpr (C % 4 == 0) {
            for (int c = 0; c < C; c += 4) {
                float4 w0 = *(const float4*)&WaT[(c + 0) * O + o0];
                float4 w1 = *(const float4*)&WaT[(c + 1) * O + o0];
                float4 w2 = *(const float4*)&WaT[(c + 2) * O + o0];
                float4 w3 = *(const float4*)&WaT[(c + 3) * O + o0];
                #pragma unroll
                for (int t = 0; t < PPT; ++t) {
                    float4 nv = *(const float4*)&xt[ps + t * PS][c];
                    acc[t][0] += nv.x * w0.x + nv.y * w1.x + nv.z * w2.x + nv.w * w3.x;
                    acc[t][1] += nv.x * w0.y + nv.y * w1.y + nv.z * w2.y + nv.w * w3.y;
                    acc[t][2] += nv.x * w0.z + nv.y * w1.z + nv.z * w2.z + nv.w * w3.z;
                    acc[t][3] += nv.x * w0.w + nv.y * w1.w + nv.z * w2.w + nv.w * w3.w;
                }
            }
        } else {
            for (int c = 0; c < C; ++c) {
                float4 w = *(const float4*)&WaT[c * O + o0];
                #pragma unroll
                for (int t = 0; t < PPT; ++t) {
                    float nv = xt[ps + t * PS][c];
                    acc[t][0] += nv * w.x; acc[t][1] += nv * w.y;
                    acc[t][2] += nv * w.z; acc[t][3] += nv * w.w;
                }
            }
        }
        #pragma unroll
        for (int t = 0; t < PPT; ++t)
            *(float4*)&T1[((size_t)p0 + ps + t * PS) * O + o0] =
                make_float4(acc[t][0], acc[t][1], acc[t][2], acc[t][3]);
    }
    {
        constexpr int PS2 = 256 / O;
        constexpr int PPT2 = 64 / PS2;
        int o = tid % O, ps = tid / O;
        float s[PPT2];
        #pragma unroll
        for (int t = 0; t < PPT2; ++t) s[t] = 0.f;
        for (int c = 0; c < C; ++c) {
            float w = WdT[c * O + o];
            #pragma unroll
            for (int t = 0; t < PPT2; ++t) s[t] += w * xt[ps + t * PS2][c];
        }
        #pragma unroll
        for (int t = 0; t < PPT2; ++t) T2[((size_t)p0 + ps + t * PS2) * O + o] = s[t];
    }
}

// ---------------- edge gather-reduce (DETERMINISTIC stats) --------
// y[k,o] = T1[idx_k][o] + T2[n][o]; max/min per point; block-partial sum/sumsq
// accumulated in registers (g ascending) + fixed-order LDS tree, stored
// NON-atomically to stP[blk] — bitwise-reproducible across runs.

template <int O, int G>
__global__ __launch_bounds__(256) void edge_reduce_kernel(
    const float* __restrict__ T1, const float* __restrict__ T2,
    const int* __restrict__ idxb,
    float* __restrict__ ymaxb, float* __restrict__ yminb, float* __restrict__ stP) {
    constexpr int OQ = O / 4;
    constexpr int PTS = 256 / OQ;
    __shared__ int sidx[PTS][KNN];
    __shared__ alignas(16) float red[2][PTS][O];   // 2*PTS*O = 2048 floats
    int blk = blockIdx.x, tid = threadIdx.x;
    int oq = tid % OQ, ps = tid / OQ;
    int o0 = oq * 4;
    float4 as = make_float4(0, 0, 0, 0), aq = make_float4(0, 0, 0, 0);
    for (int g = 0; g < G; ++g) {
        int pbase = (blk * G + g) * PTS;
        if (g) __syncthreads();
        for (int e = tid; e < PTS * KNN; e += 256)
            sidx[e / KNN][e % KNN] = idxb[(size_t)(pbase + e / KNN) * KNN + (e % KNN)];
        __syncthreads();
        int p = pbase + ps;
        int b = p >> 11;
        float4 t2v = *(const float4*)&T2[(size_t)p * O + o0];
        float4 vmax = make_float4(-FLT_MAX, -FLT_MAX, -FLT_MAX, -FLT_MAX);
        float4 vmin = make_float4(FLT_MAX, FLT_MAX, FLT_MAX, FLT_MAX);
        float4 vs = make_float4(0, 0, 0, 0), vq = make_float4(0, 0, 0, 0);
        #pragma unroll 4
        for (int k = 0; k < KNN; ++k) {
            int r = (b << 11) + sidx[ps][k];
            float4 t1v = *(const float4*)&T1[(size_t)r * O + o0];
            float yx = t1v.x + t2v.x, yy = t1v.y + t2v.y;
            float yz = t1v.z + t2v.z, yw = t1v.w + t2v.w;
            vmax.x = fmaxf(vmax.x, yx); vmax.y = fmaxf(vmax.y, yy);
            vmax.z = fmaxf(vmax.z, yz); vmax.w = fmaxf(vmax.w, yw);
            vmin.x = fminf(vmin.x, yx); vmin.y = fminf(vmin.y, yy);
            vmin.z = fminf(vmin.z, yz); vmin.w = fminf(vmin.w, yw);
            vs.x += yx; vs.y += yy; vs.z += yz; vs.w += yw;
            vq.x += yx * yx; vq.y += yy * yy; vq.z += yz * yz; vq.w += yw * yw;
        }
        *(float4*)&ymaxb[(size_t)p * O + o0] = vmax;
        *(float4*)&yminb[(size_t)p * O + o0] = vmin;
        as.x += vs.x; as.y += vs.y; as.z += vs.z; as.w += vs.w;
        aq.x += vq.x; aq.y += vq.y; aq.z += vq.z; aq.w += vq.w;
    }
    __syncthreads();
    *(float4*)&red[0][ps][o0] = as;
    *(float4*)&red[1][ps][o0] = aq;
    __syncthreads();
    for (int e = tid; e < 2 * O; e += 256) {
        int pl = e / O, oo = e - pl * O;
        float s = red[pl][0][oo];
        #pragma unroll 4
        for (int j = 1; j < PTS; ++j) s += red[pl][j][oo];
        stP[(size_t)blk * 2 * O + e] = s;
    }
}

// ---------------- T = XT3 . W (bf16 MFMA), all points; used for T1_4 and T2_4 ----

__global__ __launch_bounds__(256) void t2_mfma_kernel(
    const float* __restrict__ XT3, const short* __restrict__ Wdb, float* __restrict__ T2) {
    __shared__ alignas(16) short A[16][136];
    int blk = blockIdx.x;           // BB*NN/16 = 1024
    int tid = threadIdx.x, w = tid >> 6, lane = tid & 63;
    int n0g = blk * 16;
    for (int ch = tid; ch < 512; ch += 256) {
        int r = ch >> 5, c4 = (ch & 31) << 2;
        float4 v = *(const float4*)&XT3[((size_t)n0g + r) * 128 + c4];
        *(short4*)&A[r][c4] = f2b4(v);
    }
    __syncthreads();
    int arow = lane & 15, aq = lane >> 4;
    bf16x8 af[4];
    #pragma unroll
    for (int ks = 0; ks < 4; ++ks)
        af[ks] = *(const bf16x8*)&A[arow][ks * 32 + aq * 8];
    for (int t = 0; t < 4; ++t) {
        int nt = w * 4 + t;
        f32x4 acc = {0.f, 0.f, 0.f, 0.f};
        const short* bp = Wdb + (size_t)(nt * 16 + arow) * 128 + aq * 8;
        #pragma unroll
        for (int ks = 0; ks < 4; ++ks)
            acc = __builtin_amdgcn_mfma_f32_16x16x32_bf16(af[ks], *(const bf16x8*)(bp + ks * 32), acc, 0, 0, 0);
        #pragma unroll
        for (int r = 0; r < 4; ++r)
            T2[((size_t)n0g + aq * 4 + r) * 256 + nt * 16 + arow] = acc[r];
    }
}

// ---------------- BN finalize (fixed-order over per-block partials) ----------

__global__ void finalize_stats_kernel(const float* __restrict__ stP, const float* __restrict__ gg,
                                      const float* __restrict__ bb, float* __restrict__ scsh,
                                      int O, int nblk, float invM) {
    int o = blockIdx.x * blockDim.x + threadIdx.x;
    if (o >= O) return;
    float sa[8] = {0, 0, 0, 0, 0, 0, 0, 0}, qa[8] = {0, 0, 0, 0, 0, 0, 0, 0};
    int cp = 0;
    for (; cp + 8 <= nblk; cp += 8) {
        #pragma unroll
        for (int j = 0; j < 8; ++j) {
            sa[j] += stP[(size_t)(cp + j) * 2 * O + o];
            qa[j] += stP[(size_t)(cp + j) * 2 * O + O + o];
        }
    }
    for (; cp < nblk; ++cp) {
        sa[0] += stP[(size_t)cp * 2 * O + o];
        qa[0] += stP[(size_t)cp * 2 * O + O + o];
    }
    float s1 = ((sa[0] + sa[1]) + (sa[2] + sa[3])) + ((sa[4] + sa[5]) + (sa[6] + sa[7]));
    float s2 = ((qa[0] + qa[1]) + (qa[2] + qa[3])) + ((qa[4] + qa[5]) + (qa[6] + qa[7]));
    float mean = s1 * invM;
    float var = s2 * invM - mean * mean;
    float scale = gg[o] * rsqrtf(var + EPSV);
    float shift = bb[o] - mean * scale;
    scsh[o] = scale; scsh[O + o] = shift;
}

__global__ void edge_passB_kernel(const float* __restrict__ ymaxb, const float* __restrict__ yminb,
                                  const float* __restrict__ scsh, float* __restrict__ XTout,
                                  float* __restrict__ XCout, int O, int total) {
    int e = blockIdx.x * blockDim.x + threadIdx.x;
    if (e >= total) return;
    int o = e & (O - 1);
    float sc = scsh[o], sh = scsh[O + o];
    float y = (sc >= 0.0f) ? ymaxb[e] : yminb[e];   // monotone-affine max/min trick
    float z = sc * y + sh;
    float r = (z > 0.0f) ? z : SLOPEV * z;
    XTout[e] = r;
    if (XCout) {
        int n = (e / O) & (NN - 1);
        int bb_ = e / (O * NN);
        XCout[((size_t)bb_ * O + o) * NN + n] = r;
    }
}

// ---------------- final 512->1024 (bf16 MFMA) ----------------

__device__ __forceinline__ void stage_cat_b(short (*A)[520], const float* __restrict__ XT1,
                                            const float* __restrict__ XT2, const float* __restrict__ XT3,
                                            const float* __restrict__ XT4, int n0g, int tid) {
    for (int ch = tid; ch < 32 * 16; ch += 256) { int r = ch >> 4, c4 = (ch & 15) << 2;
        *(short4*)&A[r][c4]       = f2b4(*(const float4*)&XT1[((size_t)n0g + r) * 64 + c4]); }
    for (int ch = tid; ch < 32 * 16; ch += 256) { int r = ch >> 4, c4 = (ch & 15) << 2;
        *(short4*)&A[r][64 + c4]  = f2b4(*(const float4*)&XT2[((size_t)n0g + r) * 64 + c4]); }
    for (int ch = tid; ch < 32 * 32; ch += 256) { int r = ch >> 5, c4 = (ch & 31) << 2;
        *(short4*)&A[r][128 + c4] = f2b4(*(const float4*)&XT3[((size_t)n0g + r) * 128 + c4]); }
    for (int ch = tid; ch < 32 * 64; ch += 256) { int r = ch >> 6, c4 = (ch & 63) << 2;
        *(short4*)&A[r][256 + c4] = f2b4(*(const float4*)&XT4[((size_t)n0g + r) * 256 + c4]); }
}

// Pass A: block-partial BN stats (sum/sumsq), NON-atomic: each (w,t,lane<16)
// owns output o for both mt iterations (mt0 store, mt1 add) — deterministic.
__global__ __launch_bounds__(256) void final_mfmaA_kernel(
    const float* __restrict__ XT1, const float* __restrict__ XT2, const float* __restrict__ XT3,
    const float* __restrict__ XT4, const short* __restrict__ W5b, float* __restrict__ stP5) {
    __shared__ alignas(16) short A[32][520];
    int blk = blockIdx.x;           // BB*NN/32 = 512
    int tid = threadIdx.x, w = tid >> 6, lane = tid & 63;
    int n0g = blk * 32;
    stage_cat_b(A, XT1, XT2, XT3, XT4, n0g, tid);
    __syncthreads();
    int arow = lane & 15, aq = lane >> 4;
    float* bp5 = stP5 + (size_t)blk * 2048;
    for (int mt = 0; mt < 2; ++mt) {
        bf16x8 af[16];
        #pragma unroll
        for (int ks = 0; ks < 16; ++ks)
            af[ks] = *(const bf16x8*)&A[mt * 16 + arow][ks * 32 + aq * 8];
        for (int t = 0; t < 16; ++t) {
            int nt = w * 16 + t;
            f32x4 acc = {0.f, 0.f, 0.f, 0.f};
            const short* bp = W5b + (size_t)(nt * 16 + arow) * 512 + aq * 8;
            #pragma unroll
            for (int ks = 0; ks < 16; ++ks)
                acc = __builtin_amdgcn_mfma_f32_16x16x32_bf16(af[ks], *(const bf16x8*)(bp + ks * 32), acc, 0, 0, 0);
            float ls = (acc[0] + acc[1]) + (acc[2] + acc[3]);
            float lsq = (acc[0] * acc[0] + acc[1] * acc[1]) + (acc[2] * acc[2] + acc[3] * acc[3]);
            ls += __shfl_xor(ls, 16); ls += __shfl_xor(ls, 32);
            lsq += __shfl_xor(lsq, 16); lsq += __shfl_xor(lsq, 32);
            if (lane < 16) {
                int o = nt * 16 + lane;
                if (mt == 0) { bp5[o] = ls; bp5[1024 + o] = lsq; }
                else         { bp5[o] += ls; bp5[1024 + o] += lsq; }
            }
        }
    }
}

__global__ __launch_bounds__(256) void final_mfmaB_kernel(
    const float* __restrict__ XT1, const float* __restrict__ XT2, const float* __restrict__ XT3,
    const float* __restrict__ XT4, const short* __restrict__ W5b, const float* __restrict__ scsh,
    float* __restrict__ pmax, float* __restrict__ psum) {
    __shared__ alignas(16) short A[32][520];
    int blk = blockIdx.x;           // 512
    int tid = threadIdx.x, w = tid >> 6, lane = tid & 63;
    int n0g = blk * 32;
    stage_cat_b(A, XT1, XT2, XT3, XT4, n0g, tid);
    __syncthreads();
    int arow = lane & 15, aq = lane >> 4;
    for (int mt = 0; mt < 2; ++mt) {
        bf16x8 af[16];
        #pragma unroll
        for (int ks = 0; ks < 16; ++ks)
            af[ks] = *(const bf16x8*)&A[mt * 16 + arow][ks * 32 + aq * 8];
        for (int t = 0; t < 16; ++t) {
            int nt = w * 16 + t;
            f32x4 acc = {0.f, 0.f, 0.f, 0.f};
            const short* bp = W5b + (size_t)(nt * 16 + arow) * 512 + aq * 8;
            #pragma unroll
            for (int ks = 0; ks < 16; ++ks)
                acc = __builtin_amdgcn_mfma_f32_16x16x32_bf16(af[ks], *(const bf16x8*)(bp + ks * 32), acc, 0, 0, 0);
            int o = nt * 16 + arow;
            float sc = scsh[o], sh = scsh[1024 + o];
            float lmax = -FLT_MAX, lsm = 0.f;
            #pragma unroll
            for (int r = 0; r < 4; ++r) {
                float z = fmaf(sc, acc[r], sh);
                float l = (z > 0.0f) ? z : SLOPEV * z;
                lmax = fmaxf(lmax, l); lsm += l;
            }
            lmax = fmaxf(lmax, __shfl_xor(lmax, 16));
            lmax = fmaxf(lmax, __shfl_xor(lmax, 32));
            lsm += __shfl_xor(lsm, 16); lsm += __shfl_xor(lsm, 32);
            if (lane < 16) {
                pmax[(size_t)(blk * 2 + mt) * 1024 + o] = lmax;
                psum[(size_t)(blk * 2 + mt) * 1024 + o] = lsm;
            }
        }
    }
}

__global__ void final_passC_kernel(const float* __restrict__ pmax, const float* __restrict__ psum,
                                   float* __restrict__ out) {
    int e = blockIdx.x * blockDim.x + threadIdx.x;
    if (e >= BB * 1024) return;
    int b = e >> 10, o = e & 1023;
    float mx = -FLT_MAX, sm = 0;
    for (int j = 0; j < NN / 16; ++j) {
        size_t p = ((size_t)(b * (NN / 16) + j)) * 1024 + o;
        mx = fmaxf(mx, pmax[p]);
        sm += psum[p];
    }
    out[b * 2048 + o] = mx;
    out[b * 2048 + 1024 + o] = sm * (1.0f / NN);
}

// ---------------- launch ----------------

extern "C" void kernel_launch(void* const* d_in, const int* in_sizes, int n_in,
                              void* d_out, int out_size, void* d_ws, size_t ws_size,
                              hipStream_t stream) {
    const float* x  = (const float*)d_in[0];
    const float* W1 = (const float*)d_in[1];
    const float* W2 = (const float*)d_in[2];
    const float* W3 = (const float*)d_in[3];
    const float* W4 = (const float*)d_in[4];
    const float* W5 = (const float*)d_in[5];
    const float* g1 = (const float*)d_in[6];  const float* b1 = (const float*)d_in[7];
    const float* g2 = (const float*)d_in[8];  const float* b2 = (const float*)d_in[9];
    const float* g3 = (const float*)d_in[10]; const float* b3 = (const float*)d_in[11];
    const float* g4 = (const float*)d_in[12]; const float* b4 = (const float*)d_in[13];
    const float* g5 = (const float*)d_in[14]; const float* b5 = (const float*)d_in[15];

    float* ws = (float*)d_ws;
    size_t off = 0;
    float* XT0 = ws + off; off += (size_t)BB * NN * 3;
    float* XT1 = ws + off; off += (size_t)BB * NN * 64;
    float* XT2 = ws + off; off += (size_t)BB * NN * 64;
    float* XT3 = ws + off; off += (size_t)BB * NN * 128;
    float* XT4 = ws + off; off += (size_t)BB * NN * 256;
    float* XC1 = ws + off; off += (size_t)BB * NN * 64;
    float* XC2 = ws + off; off += (size_t)BB * NN * 64;
    float* XC3 = ws + off; off += (size_t)BB * NN * 128;
    float* ymax = ws + off; off += (size_t)BB * NN * 256;
    float* ymin = ws + off; off += (size_t)BB * NN * 256;
    int*   idxb = (int*)(ws + off); off += (size_t)BB * NN * KNN;
    float* xxb = ws + off; off += (size_t)BB * NN;
    float* WaT = ws + off; off += 128 * 256;
    float* WdT = ws + off; off += 128 * 256;
    short* Wa4b = (short*)(ws + off); off += 256 * 128 / 2;
    short* Wd4b = (short*)(ws + off); off += 256 * 128 / 2;
    short* W5b  = (short*)(ws + off); off += 1024 * 512 / 2;
    float* stP = ws + off; off += 2048 * 256;          // per-block stat partials (max 524288)
    float* sc1 = ws + off; off += 2 * 64;
    float* sc2 = ws + off; off += 2 * 64;
    float* sc3 = ws + off; off += 2 * 128;
    float* sc4 = ws + off; off += 2 * 256;
    float* sc5 = ws + off; off += 2 * 1024;
    // aliases (lifetime-disjoint):
    float* T1f = XT4;                                  // layers 1-3 T1 (<=8MB)
    float* T2f = XT4 + (size_t)BB * NN * 128;          // layers 1-3 T2 (<=8MB)
    float* T1_4 = XT4;                                 // layer-4 T1 (16MB), consumed before passB writes XT4
    float* T2_4 = XC1;                                 // layer-4 T2 (16MB = XC1..3), dead after layer-4 knn
    float* pd2 = ymax;                                 // 2-batch pd tile (33.5MB = ymax+ymin)
    float* stP5 = ymax;                                // final-layer stat partials (1M floats), ymax dead then
    float* pmax = ymax;                                // final partials (after finalize consumed stP5)
    float* psum = ymin;

    transpose0_kernel<<<(BB * NN * 3 + 255) / 256, 256, 0, stream>>>(x, XT0);

    dim3 dgrid(NN / 64, NN / 64, 2);

    // layer 1: C=3 -> O=64   (x itself is the channel-major XC0)
    wprep_kernel<<<(3 * 64 + 255) / 256, 256, 0, stream>>>(W1, WaT, WdT, 3, 64);
    xx_kernel<3><<<BB * NN / 256, 256, 0, stream>>>(XT0, xxb);
    knn_c3_kernel<<<BB * NN / 4, 256, 0, stream>>>(x, XT0, xxb, idxb);
    t1t2_gemm_kernel<3, 64><<<BB * NN / 64, 256, 0, stream>>>(XT0, WaT, WdT, T1f, T2f);
    edge_reduce_kernel<64, 1><<<BB * NN / 16, 256, 0, stream>>>(T1f, T2f, idxb, ymax, ymin, stP);
    finalize_stats_kernel<<<1, 64, 0, stream>>>(stP, g1, b1, sc1, 64, BB * NN / 16, 1.0f / ((float)BB * NN * KNN));
    edge_passB_kernel<<<BB * NN * 64 / 256, 256, 0, stream>>>(ymax, ymin, sc1, XT1, XC1, 64, BB * NN * 64);

    // layer 2: C=64 -> O=64
    wprep_kernel<<<(64 * 64 + 255) / 256, 256, 0, stream>>>(W2, WaT, WdT, 64, 64);
    xx_kernel<64><<<BB * NN / 256, 256, 0, stream>>>(XT1, xxb);
    for (int p = 0; p < 4; ++p) {
        knn_dist_kernel<64><<<dgrid, 256, 0, stream>>>(XC1, XT1, xxb, pd2, 2 * p);
        knn_sel_kernel<<<2 * NN / 4, 256, 0, stream>>>(pd2, idxb, 2 * p);
    }
    t1t2_gemm_kernel<64, 64><<<BB * NN / 64, 256, 0, stream>>>(XT1, WaT, WdT, T1f, T2f);
    edge_reduce_kernel<64, 1><<<BB * NN / 16, 256, 0, stream>>>(T1f, T2f, idxb, ymax, ymin, stP);
    finalize_stats_kernel<<<1, 64, 0, stream>>>(stP, g2, b2, sc2, 64, BB * NN / 16, 1.0f / ((float)BB * NN * KNN));
    edge_passB_kernel<<<BB * NN * 64 / 256, 256, 0, stream>>>(ymax, ymin, sc2, XT2, XC2, 64, BB * NN * 64);

    // layer 3: C=64 -> O=128
    wprep_kernel<<<(64 * 128 + 255) / 256, 256, 0, stream>>>(W3, WaT, WdT, 64, 128);
    xx_kernel<64><<<BB * NN / 256, 256, 0, stream>>>(XT2, xxb);
    for (int p = 0; p < 4; ++p) {
        knn_dist_kernel<64><<<dgrid, 256, 0, stream>>>(XC2, XT2, xxb, pd2, 2 * p);
        knn_sel_kernel<<<2 * NN / 4, 256, 0, stream>>>(pd2, idxb, 2 * p);
    }
    t1t2_gemm_kernel<64, 128><<<BB * NN / 64, 256, 0, stream>>>(XT2, WaT, WdT, T1f, T2f);
    edge_reduce_kernel<128, 1><<<BB * NN / 8, 256, 0, stream>>>(T1f, T2f, idxb, ymax, ymin, stP);
    finalize_stats_kernel<<<1, 128, 0, stream>>>(stP, g3, b3, sc3, 128, BB * NN / 8, 1.0f / ((float)BB * NN * KNN));
    edge_passB_kernel<<<BB * NN * 128 / 256, 256, 0, stream>>>(ymax, ymin, sc3, XT3, XC3, 128, BB * NN * 128);

    // layer 4: C=128 -> O=256 (bf16 MFMA dense T1/T2; output never feeds KNN)
    wprep4b_kernel<<<256 * 128 / 256, 256, 0, stream>>>(W4, Wa4b, Wd4b);
    xx_kernel<128><<<BB * NN / 256, 256, 0, stream>>>(XT3, xxb);
    for (int p = 0; p < 4; ++p) {
        knn_dist_kernel<128><<<dgrid, 256, 0, stream>>>(XC3, XT3, xxb, pd2, 2 * p);
        knn_sel_kernel<<<2 * NN / 4, 256, 0, stream>>>(pd2, idxb, 2 * p);
    }
    t2_mfma_kernel<<<BB * NN / 16, 256, 0, stream>>>(XT3, Wd4b, T2_4);   // overwrites XC1..3
    t2_mfma_kernel<<<BB * NN / 16, 256, 0, stream>>>(XT3, Wa4b, T1_4);   // into XT4 region
    edge_reduce_kernel<256, 4><<<BB * NN / 16, 256, 0, stream>>>(T1_4, T2_4, idxb, ymax, ymin, stP);
    finalize_stats_kernel<<<1, 256, 0, stream>>>(stP, g4, b4, sc4, 256, BB * NN / 16, 1.0f / ((float)BB * NN * KNN));
    edge_passB_kernel<<<BB * NN * 256 / 256, 256, 0, stream>>>(ymax, ymin, sc4, XT4, nullptr, 256, BB * NN * 256);

    // final: 512 -> 1024 (bf16 MFMA), BN over (B,N), leaky, max+mean over N
    w5b_kernel<<<1024 * 512 / 256, 256, 0, stream>>>(W5, W5b);
    final_mfmaA_kernel<<<BB * NN / 32, 256, 0, stream>>>(XT1, XT2, XT3, XT4, W5b, stP5);
    finalize_stats_kernel<<<4, 256, 0, stream>>>(stP5, g5, b5, sc5, 1024, BB * NN / 32, 1.0f / ((float)BB * NN));
    final_mfmaB_kernel<<<BB * NN / 32, 256, 0, stream>>>(XT1, XT2, XT3, XT4, W5b, sc5, pmax, psum);
    final_passC_kernel<<<(BB * 1024 + 255) / 256, 256, 0, stream>>>(pmax, psum, (float*)d_out);

    (void)in_sizes; (void)n_in; (void)out_size; (void)ws_size;
}